// Round 7
// baseline (2674.526 us; speedup 1.0000x reference)
//
#include <hip/hip_runtime.h>

// CPCGNN: LSTM(2048 x 128 steps, F=16, H=256) -> GATv2 x2 (16-node graphs) ->
// mean pool -> CPC loss. Inputs/outputs FLOAT32; MFMA paths use bf16 copies.
//
// Round 7: LSTM = 256 WGs (64 groups x 4 members, 2 graphs/group). Each WG
// holds a 128 KB gate-column slice of W_hh in LDS for ALL 128 steps (XOR
// bank swizzle). Per step: 72 MFMA/wave vs 16 KB h-exchange through a
// double-buffered global buffer with agent-scope release/acquire flags.
// Members XCD-colocated via bid swizzle. No W streaming at all.

typedef __bf16 bf16;
typedef bf16 bf16x4 __attribute__((ext_vector_type(4)));
typedef bf16 bf16x8 __attribute__((ext_vector_type(8)));
typedef float f32x4 __attribute__((ext_vector_type(4)));

__device__ __forceinline__ float fast_sigmoid(float x) {
    return __builtin_amdgcn_rcpf(1.0f + __expf(-x));
}
__device__ __forceinline__ float fast_tanh(float x) {
    return 2.0f * __builtin_amdgcn_rcpf(1.0f + __expf(-2.0f * x)) - 1.0f;
}
__device__ __forceinline__ bf16x8 zero8() {
    bf16x8 z;
#pragma unroll
    for (int i = 0; i < 8; ++i) z[i] = (bf16)0.0f;
    return z;
}
__device__ __forceinline__ bf16x8 load8_bf(const float* p) {
    float4 a = *(const float4*)p;
    float4 b = *(const float4*)(p + 4);
    bf16x8 r;
    r[0] = (bf16)a.x; r[1] = (bf16)a.y; r[2] = (bf16)a.z; r[3] = (bf16)a.w;
    r[4] = (bf16)b.x; r[5] = (bf16)b.y; r[6] = (bf16)b.z; r[7] = (bf16)b.w;
    return r;
}

// ---------------------------------------------------------------------------
// 0. Weight f32 -> bf16 (all plain row-major) + zero the 256 lstm sync flags.
// ---------------------------------------------------------------------------
__global__ __launch_bounds__(256, 1) void cvt6(
    const float* __restrict__ s0, const float* __restrict__ s1,
    const float* __restrict__ s2, const float* __restrict__ s3,
    const float* __restrict__ s4, const float* __restrict__ s5,
    bf16* __restrict__ d0, bf16* __restrict__ d1, bf16* __restrict__ d2,
    bf16* __restrict__ d3, bf16* __restrict__ d4, bf16* __restrict__ d5,
    int* __restrict__ flags)
{
    if (blockIdx.x == 0 && threadIdx.x < 256) flags[threadIdx.x] = 0;
    const int n0 = 16384, n1 = 262144, n2 = 524288, n3 = 524288, n4 = 65536;
    int loc = (blockIdx.x * 256 + threadIdx.x) * 4;
    const float* s; bf16* d;
    if (loc < n0)              { s = s0; d = d0; }
    else if ((loc -= n0) < n1) { s = s1; d = d1; }
    else if ((loc -= n1) < n2) { s = s2; d = d2; }
    else if ((loc -= n2) < n3) { s = s3; d = d3; }
    else if ((loc -= n3) < n4) { s = s4; d = d4; }
    else                       { loc -= n4; s = s5; d = d5; }
    float4 v = *(const float4*)(s + loc);
    bf16x4 o;
    o[0] = (bf16)v.x; o[1] = (bf16)v.y; o[2] = (bf16)v.z; o[3] = (bf16)v.w;
    *(bf16x4*)(d + loc) = o;
}

// ---------------------------------------------------------------------------
// 1. LSTM, LDS-resident W. bid -> xcd=bid&7, slot=bid>>3, member m=slot&3,
//    group p = xcd*8 + (slot>>2). Group p owns graphs {2p, 2p+1}; member m
//    owns gate-cols j in [64m, 64m+64). Wave w owns j-subslice [64m+16w,+16),
//    all 4 gates. W slice (256 rows x 256 k bf16 = 128 KB) staged once into
//    LDS with XOR swizzle. Per step/wave: 32 W ds_read_b128 (shared by the 2
//    graphs), 16 h ds_reads, 72 MFMA, gates, h-exchange via hx + flags.
// ---------------------------------------------------------------------------
__global__ __launch_bounds__(256, 1) void lstm_kernel(
    const float* __restrict__ agent_obs,  // (128,128,16,16) f32
    const bf16* __restrict__ W_ih,        // (1024,16) bf16
    const bf16* __restrict__ W_hh,        // (1024,256) bf16 row-major
    const float* __restrict__ b_ih,
    const float* __restrict__ b_hh,
    bf16* __restrict__ hn,                // (2048,256) bf16
    bf16* __restrict__ hx,                // (64,2,2,16,256) bf16
    int*  __restrict__ flags)             // (64,4)
{
    __shared__ bf16 Wlds[65536];          // 128 KB: [256 rows][256 k], XOR swz
    __shared__ bf16 hlds[2][16][264];     // 16.9 KB: [graph][agent][k+pad]
    const int tid  = threadIdx.x;
    const int lane = tid & 63;
    const int w    = tid >> 6;            // wave 0..3
    const int col  = lane & 15;
    const int grp  = lane >> 4;
    const int bid  = blockIdx.x;
    const int m    = (bid >> 3) & 3;                  // member 0..3
    const int p    = (bid & 7) * 8 + (bid >> 5);      // group 0..63
    char* WL = (char*)Wlds;
    char* HL = (char*)&hlds[0][0][0];

    // ---- stage W slice: 4 contiguous 32 KB blocks (rows G*256+64m .. +64)
#pragma unroll
    for (int G = 0; G < 4; ++G) {
        const bf16* gsrc = W_hh + ((size_t)(G * 256 + 64 * m)) * 256;
#pragma unroll
        for (int i = 0; i < 8; ++i) {
            int e = (i * 256 + tid) * 8;  // elem in 16384-elem block
            bf16x8 v = *(const bf16x8*)(gsrc + e);
            int lr = e >> 8, k = e & 255;
            int byte = ((G * 64 + lr) * 512 + k * 2) ^ ((lr & 7) << 4);
            *(bf16x8*)(WL + byte) = v;
        }
    }

    // per-lane invariants
    const int j = 64 * m + 16 * w + col;  // global h-col this lane produces
    float bias[4];
    bf16x8 wih[4];
#pragma unroll
    for (int G = 0; G < 4; ++G) {
        int n = G * 256 + j;
        bias[G] = b_ih[n] + b_hh[n];
        wih[G] = (grp < 2) ? *(const bf16x8*)&W_ih[n * 16 + grp * 8] : zero8();
    }
    f32x4 c[2];
    c[0] = (f32x4){0.f, 0.f, 0.f, 0.f};
    c[1] = (f32x4){0.f, 0.f, 0.f, 0.f};

    const float* xb0 = agent_obs + (size_t)(2 * p + 0) * 32768;
    const float* xb1 = agent_obs + (size_t)(2 * p + 1) * 32768;
    int* flg = flags + p * 4;
    bf16* hxp = hx + (size_t)p * 16384;   // 2 bufs x 8192 elems

    __syncthreads();                      // Wlds ready

    for (int s = 0; s < 128; ++s) {
        bf16x8 ax0 = (grp < 2) ? load8_bf(xb0 + s * 256 + col * 16 + grp * 8) : zero8();
        bf16x8 ax1 = (grp < 2) ? load8_bf(xb1 + s * 256 + col * 16 + grp * 8) : zero8();
        f32x4 acc[2][4];
#pragma unroll
        for (int G = 0; G < 4; ++G) {
            float bs_ = bias[G];
            acc[0][G] = (f32x4){bs_, bs_, bs_, bs_};
            acc[1][G] = (f32x4){bs_, bs_, bs_, bs_};
        }
        if (s > 0) {
#pragma unroll
            for (int kc = 0; kc < 8; ++kc) {
                bf16x8 ah0 = *(const bf16x8*)(HL + col * 528 + kc * 64 + grp * 16);
                bf16x8 ah1 = *(const bf16x8*)(HL + 8448 + col * 528 + kc * 64 + grp * 16);
#pragma unroll
                for (int G = 0; G < 4; ++G) {
                    int byte = ((G * 64 + 16 * w + col) * 512 + kc * 64 + grp * 16)
                               ^ ((col & 7) << 4);
                    bf16x8 bw = *(const bf16x8*)(WL + byte);
                    acc[0][G] = __builtin_amdgcn_mfma_f32_16x16x32_bf16(ah0, bw, acc[0][G], 0, 0, 0);
                    acc[1][G] = __builtin_amdgcn_mfma_f32_16x16x32_bf16(ah1, bw, acc[1][G], 0, 0, 0);
                }
            }
        }
#pragma unroll
        for (int G = 0; G < 4; ++G) {
            acc[0][G] = __builtin_amdgcn_mfma_f32_16x16x32_bf16(ax0, wih[G], acc[0][G], 0, 0, 0);
            acc[1][G] = __builtin_amdgcn_mfma_f32_16x16x32_bf16(ax1, wih[G], acc[1][G], 0, 0, 0);
        }
        const int bufw = (s + 1) & 1;
        bf16* hxw = hxp + bufw * 8192;
#pragma unroll
        for (int gma = 0; gma < 2; ++gma) {
#pragma unroll
            for (int r = 0; r < 4; ++r) {
                float iv = fast_sigmoid(acc[gma][0][r]);
                float fv = fast_sigmoid(acc[gma][1][r]);
                float gv = fast_tanh(acc[gma][2][r]);
                float ov = fast_sigmoid(acc[gma][3][r]);
                float cn = fv * c[gma][r] + iv * gv;
                c[gma][r] = cn;
                float hv = ov * fast_tanh(cn);
                int row = grp * 4 + r;
                if (s == 127)
                    hn[((size_t)(2 * p + gma) * 16 + row) * 256 + j] = (bf16)hv;
                else
                    hxw[gma * 4096 + row * 256 + j] = (bf16)hv;
            }
        }
        if (s == 127) break;

        __syncthreads();                  // drain all waves' h stores
        if (tid == 0) {
            __hip_atomic_store(&flg[m], s + 1, __ATOMIC_RELEASE,
                               __HIP_MEMORY_SCOPE_AGENT);
            int it = 0;
            for (;;) {
                int f0 = __hip_atomic_load(&flg[0], __ATOMIC_ACQUIRE, __HIP_MEMORY_SCOPE_AGENT);
                int f1 = __hip_atomic_load(&flg[1], __ATOMIC_ACQUIRE, __HIP_MEMORY_SCOPE_AGENT);
                int f2 = __hip_atomic_load(&flg[2], __ATOMIC_ACQUIRE, __HIP_MEMORY_SCOPE_AGENT);
                int f3 = __hip_atomic_load(&flg[3], __ATOMIC_ACQUIRE, __HIP_MEMORY_SCOPE_AGENT);
                if (f0 > s && f1 > s && f2 > s && f3 > s) break;
                __builtin_amdgcn_s_sleep(1);
                if (++it > (1 << 20)) break;   // safety valve: no hard hang
            }
        }
        __syncthreads();
        // stage h_{s+1} (full 2x16x256) into padded hlds
#pragma unroll
        for (int i = 0; i < 4; ++i) {
            int e = (i * 256 + tid) * 8;  // 0..8191
            bf16x8 v = *(const bf16x8*)(hxw + e);
            int gma = e >> 12, rem = e & 4095;
            int row = rem >> 8, k = rem & 255;
            *(bf16x8*)(HL + gma * 8448 + row * 528 + k * 2) = v;
        }
        __syncthreads();
    }
}

// ---------------------------------------------------------------------------
// 2. GEMM: C[M,N] = A[M,256] @ W[N,256]^T + bias. A,W,C bf16; bias f32.
// ---------------------------------------------------------------------------
__global__ __launch_bounds__(256, 1) void gemm_bias(
    const bf16* __restrict__ A, const bf16* __restrict__ W,
    const float* __restrict__ bias, bf16* __restrict__ C, int M, int N)
{
    const int tid = threadIdx.x, lane = tid & 63, wv = tid >> 6;
    const int col = lane & 15, grp = lane >> 4;
    const int n = blockIdx.x * 64 + wv * 16 + col;
    const int bm = blockIdx.y * 64;
    float bs = bias[n];
    f32x4 acc[4];
#pragma unroll
    for (int mt = 0; mt < 4; ++mt) acc[mt] = (f32x4){bs, bs, bs, bs};
#pragma unroll
    for (int kc = 0; kc < 8; ++kc) {
        bf16x8 bw = *(const bf16x8*)&W[(size_t)n * 256 + kc * 32 + grp * 8];
#pragma unroll
        for (int mt = 0; mt < 4; ++mt) {
            bf16x8 aa = *(const bf16x8*)
                &A[(size_t)(bm + mt * 16 + col) * 256 + kc * 32 + grp * 8];
            acc[mt] = __builtin_amdgcn_mfma_f32_16x16x32_bf16(aa, bw, acc[mt], 0, 0, 0);
        }
    }
#pragma unroll
    for (int mt = 0; mt < 4; ++mt)
#pragma unroll
        for (int r = 0; r < 4; ++r)
            C[(size_t)(bm + mt * 16 + grp * 4 + r) * N + n] = (bf16)acc[mt][r];
}

// ---------------------------------------------------------------------------
// 3. GATv2 layer 1: scores + edge softmax (no self) + head-mean aggregation.
// ---------------------------------------------------------------------------
__global__ __launch_bounds__(256, 1) void gat1_kernel(
    const bf16* __restrict__ src,    // (2048, 2048) = (b*16+n, h*256+f)
    const bf16* __restrict__ dst,
    const float* __restrict__ attn,  // (8,256) f32
    bf16* __restrict__ r1)           // (2048, 256)
{
    __shared__ float sal[2048];      // (i*16+j)*8+h
    const int tid = threadIdx.x, b = blockIdx.x;
    const bf16* sb = src + (size_t)b * 32768;
    const bf16* db = dst + (size_t)b * 32768;

    for (int ii = 0; ii < 8; ++ii) {
        int trip = tid + ii * 256;            // i*128 + j*8 + h
        int i = trip >> 7, j = (trip >> 3) & 15, h = trip & 7;
        const bf16* ps = sb + j * 2048 + h * 256;
        const bf16* pd = db + i * 2048 + h * 256;
        const float* pa = attn + h * 256;
        float acc = 0.0f;
        for (int f8 = 0; f8 < 32; ++f8) {
            bf16x8 vs = *(const bf16x8*)(ps + f8 * 8);
            bf16x8 vd = *(const bf16x8*)(pd + f8 * 8);
            float4 a0 = *(const float4*)(pa + f8 * 8);
            float4 a1 = *(const float4*)(pa + f8 * 8 + 4);
            float av[8] = {a0.x, a0.y, a0.z, a0.w, a1.x, a1.y, a1.z, a1.w};
#pragma unroll
            for (int e = 0; e < 8; ++e) {
                float v = (float)vs[e] + (float)vd[e];
                v = v > 0.0f ? v : 0.2f * v;
                acc += v * av[e];
            }
        }
        sal[trip] = acc;
    }
    __syncthreads();
    if (tid < 128) {                          // softmax over j != i
        int i = tid >> 3, h = tid & 7;
        float m = -1e30f;
#pragma unroll
        for (int j = 0; j < 16; ++j)
            if (j != i) m = fmaxf(m, sal[(i * 16 + j) * 8 + h]);
        float ex[16], den = 0.0f;
#pragma unroll
        for (int j = 0; j < 16; ++j) {
            ex[j] = (j == i) ? 0.0f : __expf(sal[(i * 16 + j) * 8 + h] - m);
            den += ex[j];
        }
        float rd = 1.0f / den;
#pragma unroll
        for (int j = 0; j < 16; ++j) sal[(i * 16 + j) * 8 + h] = ex[j] * rd;
    }
    __syncthreads();
    {
        int i = tid >> 4, fb = tid & 15;
        for (int it = 0; it < 16; ++it) {
            int f = fb + it * 16;
            float acc = 0.0f;
            for (int j = 0; j < 16; ++j) {
                const bf16* ps = sb + j * 2048 + f;
#pragma unroll
                for (int h = 0; h < 8; ++h)
                    acc += sal[(i * 16 + j) * 8 + h] * (float)ps[h * 256];
            }
            r1[((size_t)b * 16 + i) * 256 + f] = (bf16)(acc * 0.125f);
        }
    }
}

// ---------------------------------------------------------------------------
// 4. GATv2 layer 2 (1 head) fused with node-mean + d_out row writes.
// ---------------------------------------------------------------------------
__global__ __launch_bounds__(256, 1) void gat2_kernel(
    const bf16* __restrict__ src2,   // (2048,256)
    const bf16* __restrict__ dst2,
    const float* __restrict__ attn2, // (256) f32
    const float* __restrict__ hideout,   // (128,2) f32
    const float* __restrict__ timestep,  // (128,1) f32
    float* __restrict__ out,             // (128,259)+loss f32
    float* __restrict__ ac_ws)           // (128,256) f32
{
    __shared__ float sal[256];
    __shared__ float wj[16];
    const int tid = threadIdx.x, b = blockIdx.x;
    const bf16* sb = src2 + (size_t)b * 4096;
    const bf16* db = dst2 + (size_t)b * 4096;
    {
        int i = tid >> 4, j = tid & 15;
        const bf16* ps = sb + j * 256;
        const bf16* pd = db + i * 256;
        float acc = 0.0f;
        for (int g8 = 0; g8 < 32; ++g8) {
            bf16x8 vs = *(const bf16x8*)(ps + g8 * 8);
            bf16x8 vd = *(const bf16x8*)(pd + g8 * 8);
            float4 a0 = *(const float4*)(attn2 + g8 * 8);
            float4 a1 = *(const float4*)(attn2 + g8 * 8 + 4);
            float av[8] = {a0.x, a0.y, a0.z, a0.w, a1.x, a1.y, a1.z, a1.w};
#pragma unroll
            for (int e = 0; e < 8; ++e) {
                float v = (float)vs[e] + (float)vd[e];
                v = v > 0.0f ? v : 0.2f * v;
                acc += v * av[e];
            }
        }
        sal[tid] = acc;
    }
    __syncthreads();
    if (tid < 16) {
        int i = tid;
        float m = -1e30f;
#pragma unroll
        for (int j = 0; j < 16; ++j)
            if (j != i) m = fmaxf(m, sal[i * 16 + j]);
        float ex[16], den = 0.0f;
#pragma unroll
        for (int j = 0; j < 16; ++j) {
            ex[j] = (j == i) ? 0.0f : __expf(sal[i * 16 + j] - m);
            den += ex[j];
        }
        float rd = 1.0f / den;
#pragma unroll
        for (int j = 0; j < 16; ++j) sal[i * 16 + j] = ex[j] * rd;
    }
    __syncthreads();
    if (tid < 16) {
        float a = 0.0f;
#pragma unroll
        for (int i = 0; i < 16; ++i) a += sal[i * 16 + tid];
        wj[tid] = a * (1.0f / 16.0f);
    }
    __syncthreads();
    {
        int g = tid;
        float acc = 0.0f;
#pragma unroll
        for (int j = 0; j < 16; ++j) acc += wj[j] * (float)sb[j * 256 + g];
        ac_ws[b * 256 + g] = acc;
        out[(size_t)b * 259 + g] = acc;
    }
    if (tid < 2) out[(size_t)b * 259 + 256 + tid] = hideout[b * 2 + tid];
    if (tid == 0) out[(size_t)b * 259 + 258] = timestep[b];
}

// ---------------------------------------------------------------------------
// 5. CPC: one WG per t. pred/proj -> l2norm -> logits -> log-softmax diag.
// ---------------------------------------------------------------------------
__global__ __launch_bounds__(256, 1) void cpc_kernel(
    const float* __restrict__ ac,      // (128,256) f32
    const float* __restrict__ future,  // (128,12,2) f32
    const float* __restrict__ Wk,      // (12,16,256) f32
    const float* __restrict__ bk,      // (12,16) f32
    const float* __restrict__ Wl,      // (16,2) f32
    const float* __restrict__ bl,      // (16) f32
    float* __restrict__ loss_part)     // (12) f32
{
    __shared__ float pred[128][17];
    __shared__ float proj[128][17];
    __shared__ float red[4];
    const int tid = threadIdx.x, t = blockIdx.x;

    for (int ii = 0; ii < 8; ++ii) {
        int idx = tid + ii * 256;
        int b = idx >> 4, l = idx & 15;
        const float* wrow = Wk + ((size_t)t * 16 + l) * 256;
        const float* arow = ac + b * 256;
        float acc = bk[t * 16 + l];
        for (int g = 0; g < 256; g += 4) {
            float4 w = *(const float4*)(wrow + g);
            float4 a = *(const float4*)(arow + g);
            acc += w.x * a.x + w.y * a.y + w.z * a.z + w.w * a.w;
        }
        pred[b][l] = acc;
        float f0 = future[(b * 12 + t) * 2 + 0];
        float f1 = future[(b * 12 + t) * 2 + 1];
        proj[b][l] = f0 * Wl[l * 2 + 0] + f1 * Wl[l * 2 + 1] + bl[l];
    }
    __syncthreads();
    {
        float* row = (tid < 128) ? pred[tid] : proj[tid - 128];
        float ss = 0.0f;
#pragma unroll
        for (int l = 0; l < 16; ++l) ss += row[l] * row[l];
        float inv = 1.0f / fmaxf(sqrtf(ss), 1e-12f);
#pragma unroll
        for (int l = 0; l < 16; ++l) row[l] *= inv;
    }
    __syncthreads();
    float lsbb = 0.0f;
    if (tid < 128) {
        int b = tid;
        float tf[16];
#pragma unroll
        for (int l = 0; l < 16; ++l) tf[l] = proj[b][l];
        float mx = -1e30f, dbb = 0.0f;
        for (int cc = 0; cc < 128; ++cc) {
            float d = 0.0f;
#pragma unroll
            for (int l = 0; l < 16; ++l) d += tf[l] * pred[cc][l];
            mx = fmaxf(mx, d);
            if (cc == b) dbb = d;
        }
        float den = 0.0f;
        for (int cc = 0; cc < 128; ++cc) {
            float d = 0.0f;
#pragma unroll
            for (int l = 0; l < 16; ++l) d += tf[l] * pred[cc][l];
            den += __expf(d - mx);
        }
        lsbb = dbb - mx - __logf(den);
    }
#pragma unroll
    for (int o = 32; o > 0; o >>= 1) lsbb += __shfl_down(lsbb, o);
    if ((tid & 63) == 0) red[tid >> 6] = lsbb;
    __syncthreads();
    if (tid == 0) loss_part[t] = red[0] + red[1] + red[2] + red[3];
}

__global__ void final_kernel(const float* __restrict__ loss_part,
                             float* __restrict__ out)
{
    if (threadIdx.x == 0) {
        float s = 0.0f;
        for (int t = 0; t < 12; ++t) s += loss_part[t];
        out[33152] = -s / 1536.0f;
    }
}

// ---------------------------------------------------------------------------
extern "C" void kernel_launch(void* const* d_in, const int* in_sizes, int n_in,
                              void* d_out, int out_size, void* d_ws, size_t ws_size,
                              hipStream_t stream)
{
    const float* agent_obs = (const float*)d_in[0];
    const float* future    = (const float*)d_in[1];
    const float* hideout   = (const float*)d_in[2];
    const float* timestep  = (const float*)d_in[3];
    // d_in[4] = num_agents (int, ==16)
    const float* W_ih  = (const float*)d_in[5];
    const float* W_hh  = (const float*)d_in[6];
    const float* b_ih  = (const float*)d_in[7];
    const float* b_hh  = (const float*)d_in[8];
    const float* Wsrc1 = (const float*)d_in[9];
    const float* bsrc1 = (const float*)d_in[10];
    const float* Wdst1 = (const float*)d_in[11];
    const float* bdst1 = (const float*)d_in[12];
    const float* attn1 = (const float*)d_in[13];
    const float* Wsrc2 = (const float*)d_in[14];
    const float* bsrc2 = (const float*)d_in[15];
    const float* Wdst2 = (const float*)d_in[16];
    const float* bdst2 = (const float*)d_in[17];
    const float* attn2 = (const float*)d_in[18];
    const float* Wk    = (const float*)d_in[19];
    const float* bk    = (const float*)d_in[20];
    const float* Wl    = (const float*)d_in[21];
    const float* bl    = (const float*)d_in[22];
    float* out = (float*)d_out;

    char* ws = (char*)d_ws;
    const size_t KB = 1024;
    bf16*  wihb  = (bf16*)(ws);                  // 32 KB  (1024x16)
    bf16*  whhb  = (bf16*)(ws + 32 * KB);        // 512 KB (1024x256) row-major
    bf16*  ws1b  = (bf16*)(ws + 544 * KB);       // 1 MB   (2048x256)
    bf16*  wd1b  = (bf16*)(ws + 1568 * KB);      // 1 MB
    bf16*  ws2b  = (bf16*)(ws + 2592 * KB);      // 128 KB (256x256)
    bf16*  wd2b  = (bf16*)(ws + 2720 * KB);      // 128 KB
    bf16*  hn    = (bf16*)(ws + 2848 * KB);      // 1 MB   (2048x256)
    bf16*  src1  = (bf16*)(ws + 3872 * KB);      // 8 MB   (2048x2048)
    bf16*  dst1  = (bf16*)(ws + 12064 * KB);     // 8 MB
    bf16*  r1    = (bf16*)(ws + 20256 * KB);     // 1 MB   (2048x256)
    bf16*  src2  = (bf16*)(ws + 21280 * KB);     // 1 MB
    bf16*  dst2  = (bf16*)(ws + 22304 * KB);     // 1 MB
    float* acf   = (float*)(ws + 23328 * KB);    // 128 KB (128x256 f32)
    float* lossp = (float*)(ws + 23456 * KB);    // 48 B
    // lstm-only scratch, OVERLAPS src1 region (src1 written after lstm ends):
    int*   flags = (int*)(ws + 3872 * KB);       // 1 KB   (64x4)
    bf16*  hx    = (bf16*)(ws + 3876 * KB);      // 2 MB   (64x2x2x16x256)

    cvt6<<<1424, 256, 0, stream>>>(W_ih, W_hh, Wsrc1, Wdst1, Wsrc2, Wdst2,
                                   wihb, whhb, ws1b, wd1b, ws2b, wd2b, flags);
    lstm_kernel<<<256, 256, 0, stream>>>(agent_obs, wihb, whhb, b_ih, b_hh,
                                         hn, hx, flags);
    gemm_bias<<<dim3(32, 32), 256, 0, stream>>>(hn, ws1b, bsrc1, src1, 2048, 2048);
    gemm_bias<<<dim3(32, 32), 256, 0, stream>>>(hn, wd1b, bdst1, dst1, 2048, 2048);
    gat1_kernel<<<128, 256, 0, stream>>>(src1, dst1, attn1, r1);
    gemm_bias<<<dim3(4, 32), 256, 0, stream>>>(r1, ws2b, bsrc2, src2, 2048, 256);
    gemm_bias<<<dim3(4, 32), 256, 0, stream>>>(r1, wd2b, bdst2, dst2, 2048, 256);
    gat2_kernel<<<128, 256, 0, stream>>>(src2, dst2, attn2, hideout, timestep, out, acf);
    cpc_kernel<<<12, 256, 0, stream>>>(acf, future, Wk, bk, Wl, bl, lossp);
    final_kernel<<<1, 64, 0, stream>>>(lossp, out);
}

// Round 8
// 1499.873 us; speedup vs baseline: 1.7832x; 1.7832x over previous
//
#include <hip/hip_runtime.h>

// CPCGNN: LSTM(2048 x 128 steps, F=16, H=256) -> GATv2 x2 (16-node graphs) ->
// mean pool -> CPC loss. Inputs/outputs FLOAT32; MFMA paths use bf16 copies.
//
// Round 8: round-6 LSTM structure (1024 thr / 16 waves / 1 barrier/step,
// W_hh streamed global->VGPR from chunk-major layout) + two changes:
//  * per-WG kc-phase rotation ((bid>>3)&7) to break L2 same-line camping
//    across the 128 lockstep WGs (all sweeping the same 512 KB of W).
//  * non-temporal W loads (bypass the 32 KB L1 this stream can never hit).

typedef __bf16 bf16;
typedef bf16 bf16x4 __attribute__((ext_vector_type(4)));
typedef bf16 bf16x8 __attribute__((ext_vector_type(8)));
typedef float f32x4 __attribute__((ext_vector_type(4)));

__device__ __forceinline__ float fast_sigmoid(float x) {
    return __builtin_amdgcn_rcpf(1.0f + __expf(-x));
}
__device__ __forceinline__ float fast_tanh(float x) {
    return 2.0f * __builtin_amdgcn_rcpf(1.0f + __expf(-2.0f * x)) - 1.0f;
}
__device__ __forceinline__ bf16x8 zero8() {
    bf16x8 z;
#pragma unroll
    for (int i = 0; i < 8; ++i) z[i] = (bf16)0.0f;
    return z;
}
__device__ __forceinline__ bf16x8 load8_bf(const float* p) {
    float4 a = *(const float4*)p;
    float4 b = *(const float4*)(p + 4);
    bf16x8 r;
    r[0] = (bf16)a.x; r[1] = (bf16)a.y; r[2] = (bf16)a.z; r[3] = (bf16)a.w;
    r[4] = (bf16)b.x; r[5] = (bf16)b.y; r[6] = (bf16)b.z; r[7] = (bf16)b.w;
    return r;
}
__device__ __forceinline__ bf16x8 ldnt8(const bf16* p) {
    return __builtin_nontemporal_load((const bf16x8*)p);
}

// ---------------------------------------------------------------------------
// 0. Weight f32 -> bf16. W_hh chunk-major: chunk ic = (k>>5)*2 + (n>>9) holds
//    rows (n&511) x k-slice (k&31), layout whh2[16][512][32].
// ---------------------------------------------------------------------------
__global__ __launch_bounds__(256, 1) void cvt6(
    const float* __restrict__ s0, const float* __restrict__ s1,
    const float* __restrict__ s2, const float* __restrict__ s3,
    const float* __restrict__ s4, const float* __restrict__ s5,
    bf16* __restrict__ d0, bf16* __restrict__ d1, bf16* __restrict__ d2,
    bf16* __restrict__ d3, bf16* __restrict__ d4, bf16* __restrict__ d5)
{
    const int n0 = 16384, n1 = 262144, n2 = 524288, n3 = 524288, n4 = 65536;
    int loc = (blockIdx.x * 256 + threadIdx.x) * 4;
    const float* s; bf16* d; int dst;
    if (loc < n0)              { s = s0; d = d0; dst = loc; }
    else if ((loc -= n0) < n1) {
        s = s1; d = d1;
        int n = loc >> 8, k = loc & 255;
        dst = ((((k >> 5) << 1) | (n >> 9)) << 14) + ((n & 511) << 5) + (k & 31);
    }
    else if ((loc -= n1) < n2) { s = s2; d = d2; dst = loc; }
    else if ((loc -= n2) < n3) { s = s3; d = d3; dst = loc; }
    else if ((loc -= n3) < n4) { s = s4; d = d4; dst = loc; }
    else                       { loc -= n4; s = s5; d = d5; dst = loc; }
    float4 v = *(const float4*)(s + loc);
    bf16x4 o;
    o[0] = (bf16)v.x; o[1] = (bf16)v.y; o[2] = (bf16)v.z; o[3] = (bf16)v.w;
    *(bf16x4*)(d + dst) = o;
}

// ---------------------------------------------------------------------------
// 1. LSTM. WG b = graph b (16 rows). 16 waves; wave w owns tau=w: gate-cols
//    n = G*256 + w*16 + col for G=0..3. Per step per wave: 32 nt 16B W loads
//    (kc order rotated per WG to spread L2 line pressure), 36 MFMA, gates,
//    1 barrier. K-accumulation order is commutative -> rotation is safe.
// ---------------------------------------------------------------------------
__global__ __launch_bounds__(1024)
__attribute__((amdgpu_waves_per_eu(4, 4)))
void lstm_kernel(
    const float* __restrict__ agent_obs,  // (128,128,16,16) f32
    const bf16* __restrict__ W_ih,        // (1024,16) bf16
    const bf16* __restrict__ whh2,        // (16,512,32) bf16 chunk-major
    const float* __restrict__ b_ih,
    const float* __restrict__ b_hh,
    bf16* __restrict__ hn)                // (2048,256) bf16
{
    __shared__ bf16 hbuf[2][16][264];     // +8 pad; double-buffered h
    const int tid  = threadIdx.x;
    const int lane = tid & 63;
    const int w    = tid >> 6;            // wave id = tau
    const int col  = lane & 15;           // A-row (agent) / B-col (within tau)
    const int grp  = lane >> 4;           // k-group
    const int b    = blockIdx.x;
    const int phase = (b >> 3) & 7;       // per-XCD kc-phase spreading

    for (int i = tid; i < 2 * 16 * 264; i += 1024) (&hbuf[0][0][0])[i] = (bf16)0.0f;

    // per-lane invariants
    float bias[4];
    bf16x8 wih[4];
    const bf16* wp[4];                    // &whh2[chunk(G,kc=0)][r512][grp*8]
#pragma unroll
    for (int G = 0; G < 4; ++G) {
        int n = G * 256 + w * 16 + col;
        bias[G] = b_ih[n] + b_hh[n];
        wih[G] = (grp < 2) ? *(const bf16x8*)&W_ih[n * 16 + grp * 8] : zero8();
        wp[G] = whh2 + (G >> 1) * 16384 + (n & 511) * 32 + grp * 8;
    }
    f32x4 c = (f32x4){0.0f, 0.0f, 0.0f, 0.0f};

    const float* xb = agent_obs + (size_t)b * 32768;

    __syncthreads();

    for (int s = 0; s < 128; ++s) {
        const int pr = s & 1, pw = pr ^ 1;
        // issue x load early; consumed only after the K loop (latency hidden)
        bf16x8 ax = (grp < 2) ? load8_bf(xb + s * 256 + col * 16 + grp * 8)
                              : zero8();
        f32x4 acc[4];
#pragma unroll
        for (int G = 0; G < 4; ++G) {
            float bs_ = bias[G];
            acc[G] = (f32x4){bs_, bs_, bs_, bs_};
        }
        // recurrent K loop, kc order rotated by per-WG phase
#pragma unroll 4
        for (int t = 0; t < 8; ++t) {
            const int kc = (t + phase) & 7;
            bf16x8 bw0 = ldnt8(wp[0] + kc * 32768);
            bf16x8 bw1 = ldnt8(wp[1] + kc * 32768);
            bf16x8 bw2 = ldnt8(wp[2] + kc * 32768);
            bf16x8 bw3 = ldnt8(wp[3] + kc * 32768);
            bf16x8 ah = *(const bf16x8*)&hbuf[pr][col][kc * 32 + grp * 8];
            acc[0] = __builtin_amdgcn_mfma_f32_16x16x32_bf16(ah, bw0, acc[0], 0, 0, 0);
            acc[1] = __builtin_amdgcn_mfma_f32_16x16x32_bf16(ah, bw1, acc[1], 0, 0, 0);
            acc[2] = __builtin_amdgcn_mfma_f32_16x16x32_bf16(ah, bw2, acc[2], 0, 0, 0);
            acc[3] = __builtin_amdgcn_mfma_f32_16x16x32_bf16(ah, bw3, acc[3], 0, 0, 0);
        }
        // input contribution (ax long since arrived)
#pragma unroll
        for (int G = 0; G < 4; ++G)
            acc[G] = __builtin_amdgcn_mfma_f32_16x16x32_bf16(ax, wih[G], acc[G], 0, 0, 0);
        // gates: lane holds rows m=grp*4+r, col j=w*16+col
#pragma unroll
        for (int r = 0; r < 4; ++r) {
            float iv = fast_sigmoid(acc[0][r]);
            float fv = fast_sigmoid(acc[1][r]);
            float gv = fast_tanh(acc[2][r]);
            float ov = fast_sigmoid(acc[3][r]);
            float cn = fv * c[r] + iv * gv;
            c[r] = cn;
            float hv = ov * fast_tanh(cn);
            int m = grp * 4 + r, j = w * 16 + col;
            if (s == 127) hn[((size_t)b * 16 + m) * 256 + j] = (bf16)hv;
            else          hbuf[pw][m][j] = (bf16)hv;
        }
        __syncthreads();
    }
}

// ---------------------------------------------------------------------------
// 2. GEMM: C[M,N] = A[M,256] @ W[N,256]^T + bias. A,W,C bf16; bias f32.
// ---------------------------------------------------------------------------
__global__ __launch_bounds__(256, 1) void gemm_bias(
    const bf16* __restrict__ A, const bf16* __restrict__ W,
    const float* __restrict__ bias, bf16* __restrict__ C, int M, int N)
{
    const int tid = threadIdx.x, lane = tid & 63, wv = tid >> 6;
    const int col = lane & 15, grp = lane >> 4;
    const int n = blockIdx.x * 64 + wv * 16 + col;
    const int bm = blockIdx.y * 64;
    float bs = bias[n];
    f32x4 acc[4];
#pragma unroll
    for (int mt = 0; mt < 4; ++mt) acc[mt] = (f32x4){bs, bs, bs, bs};
#pragma unroll
    for (int kc = 0; kc < 8; ++kc) {
        bf16x8 bw = *(const bf16x8*)&W[(size_t)n * 256 + kc * 32 + grp * 8];
#pragma unroll
        for (int mt = 0; mt < 4; ++mt) {
            bf16x8 aa = *(const bf16x8*)
                &A[(size_t)(bm + mt * 16 + col) * 256 + kc * 32 + grp * 8];
            acc[mt] = __builtin_amdgcn_mfma_f32_16x16x32_bf16(aa, bw, acc[mt], 0, 0, 0);
        }
    }
#pragma unroll
    for (int mt = 0; mt < 4; ++mt)
#pragma unroll
        for (int r = 0; r < 4; ++r)
            C[(size_t)(bm + mt * 16 + grp * 4 + r) * N + n] = (bf16)acc[mt][r];
}

// ---------------------------------------------------------------------------
// 3. GATv2 layer 1: scores + edge softmax (no self) + head-mean aggregation.
// ---------------------------------------------------------------------------
__global__ __launch_bounds__(256, 1) void gat1_kernel(
    const bf16* __restrict__ src,    // (2048, 2048) = (b*16+n, h*256+f)
    const bf16* __restrict__ dst,
    const float* __restrict__ attn,  // (8,256) f32
    bf16* __restrict__ r1)           // (2048, 256)
{
    __shared__ float sal[2048];      // (i*16+j)*8+h
    const int tid = threadIdx.x, b = blockIdx.x;
    const bf16* sb = src + (size_t)b * 32768;
    const bf16* db = dst + (size_t)b * 32768;

    for (int ii = 0; ii < 8; ++ii) {
        int trip = tid + ii * 256;            // i*128 + j*8 + h
        int i = trip >> 7, j = (trip >> 3) & 15, h = trip & 7;
        const bf16* ps = sb + j * 2048 + h * 256;
        const bf16* pd = db + i * 2048 + h * 256;
        const float* pa = attn + h * 256;
        float acc = 0.0f;
        for (int f8 = 0; f8 < 32; ++f8) {
            bf16x8 vs = *(const bf16x8*)(ps + f8 * 8);
            bf16x8 vd = *(const bf16x8*)(pd + f8 * 8);
            float4 a0 = *(const float4*)(pa + f8 * 8);
            float4 a1 = *(const float4*)(pa + f8 * 8 + 4);
            float av[8] = {a0.x, a0.y, a0.z, a0.w, a1.x, a1.y, a1.z, a1.w};
#pragma unroll
            for (int e = 0; e < 8; ++e) {
                float v = (float)vs[e] + (float)vd[e];
                v = v > 0.0f ? v : 0.2f * v;
                acc += v * av[e];
            }
        }
        sal[trip] = acc;
    }
    __syncthreads();
    if (tid < 128) {                          // softmax over j != i
        int i = tid >> 3, h = tid & 7;
        float m = -1e30f;
#pragma unroll
        for (int j = 0; j < 16; ++j)
            if (j != i) m = fmaxf(m, sal[(i * 16 + j) * 8 + h]);
        float ex[16], den = 0.0f;
#pragma unroll
        for (int j = 0; j < 16; ++j) {
            ex[j] = (j == i) ? 0.0f : __expf(sal[(i * 16 + j) * 8 + h] - m);
            den += ex[j];
        }
        float rd = 1.0f / den;
#pragma unroll
        for (int j = 0; j < 16; ++j) sal[(i * 16 + j) * 8 + h] = ex[j] * rd;
    }
    __syncthreads();
    {
        int i = tid >> 4, fb = tid & 15;
        for (int it = 0; it < 16; ++it) {
            int f = fb + it * 16;
            float acc = 0.0f;
            for (int j = 0; j < 16; ++j) {
                const bf16* ps = sb + j * 2048 + f;
#pragma unroll
                for (int h = 0; h < 8; ++h)
                    acc += sal[(i * 16 + j) * 8 + h] * (float)ps[h * 256];
            }
            r1[((size_t)b * 16 + i) * 256 + f] = (bf16)(acc * 0.125f);
        }
    }
}

// ---------------------------------------------------------------------------
// 4. GATv2 layer 2 (1 head) fused with node-mean + d_out row writes.
// ---------------------------------------------------------------------------
__global__ __launch_bounds__(256, 1) void gat2_kernel(
    const bf16* __restrict__ src2,   // (2048,256)
    const bf16* __restrict__ dst2,
    const float* __restrict__ attn2, // (256) f32
    const float* __restrict__ hideout,   // (128,2) f32
    const float* __restrict__ timestep,  // (128,1) f32
    float* __restrict__ out,             // (128,259)+loss f32
    float* __restrict__ ac_ws)           // (128,256) f32
{
    __shared__ float sal[256];
    __shared__ float wj[16];
    const int tid = threadIdx.x, b = blockIdx.x;
    const bf16* sb = src2 + (size_t)b * 4096;
    const bf16* db = dst2 + (size_t)b * 4096;
    {
        int i = tid >> 4, j = tid & 15;
        const bf16* ps = sb + j * 256;
        const bf16* pd = db + i * 256;
        float acc = 0.0f;
        for (int g8 = 0; g8 < 32; ++g8) {
            bf16x8 vs = *(const bf16x8*)(ps + g8 * 8);
            bf16x8 vd = *(const bf16x8*)(pd + g8 * 8);
            float4 a0 = *(const float4*)(attn2 + g8 * 8);
            float4 a1 = *(const float4*)(attn2 + g8 * 8 + 4);
            float av[8] = {a0.x, a0.y, a0.z, a0.w, a1.x, a1.y, a1.z, a1.w};
#pragma unroll
            for (int e = 0; e < 8; ++e) {
                float v = (float)vs[e] + (float)vd[e];
                v = v > 0.0f ? v : 0.2f * v;
                acc += v * av[e];
            }
        }
        sal[tid] = acc;
    }
    __syncthreads();
    if (tid < 16) {
        int i = tid;
        float m = -1e30f;
#pragma unroll
        for (int j = 0; j < 16; ++j)
            if (j != i) m = fmaxf(m, sal[i * 16 + j]);
        float ex[16], den = 0.0f;
#pragma unroll
        for (int j = 0; j < 16; ++j) {
            ex[j] = (j == i) ? 0.0f : __expf(sal[i * 16 + j] - m);
            den += ex[j];
        }
        float rd = 1.0f / den;
#pragma unroll
        for (int j = 0; j < 16; ++j) sal[i * 16 + j] = ex[j] * rd;
    }
    __syncthreads();
    if (tid < 16) {
        float a = 0.0f;
#pragma unroll
        for (int i = 0; i < 16; ++i) a += sal[i * 16 + tid];
        wj[tid] = a * (1.0f / 16.0f);
    }
    __syncthreads();
    {
        int g = tid;
        float acc = 0.0f;
#pragma unroll
        for (int j = 0; j < 16; ++j) acc += wj[j] * (float)sb[j * 256 + g];
        ac_ws[b * 256 + g] = acc;
        out[(size_t)b * 259 + g] = acc;
    }
    if (tid < 2) out[(size_t)b * 259 + 256 + tid] = hideout[b * 2 + tid];
    if (tid == 0) out[(size_t)b * 259 + 258] = timestep[b];
}

// ---------------------------------------------------------------------------
// 5. CPC: one WG per t. pred/proj -> l2norm -> logits -> log-softmax diag.
// ---------------------------------------------------------------------------
__global__ __launch_bounds__(256, 1) void cpc_kernel(
    const float* __restrict__ ac,      // (128,256) f32
    const float* __restrict__ future,  // (128,12,2) f32
    const float* __restrict__ Wk,      // (12,16,256) f32
    const float* __restrict__ bk,      // (12,16) f32
    const float* __restrict__ Wl,      // (16,2) f32
    const float* __restrict__ bl,      // (16) f32
    float* __restrict__ loss_part)     // (12) f32
{
    __shared__ float pred[128][17];
    __shared__ float proj[128][17];
    __shared__ float red[4];
    const int tid = threadIdx.x, t = blockIdx.x;

    for (int ii = 0; ii < 8; ++ii) {
        int idx = tid + ii * 256;
        int b = idx >> 4, l = idx & 15;
        const float* wrow = Wk + ((size_t)t * 16 + l) * 256;
        const float* arow = ac + b * 256;
        float acc = bk[t * 16 + l];
        for (int g = 0; g < 256; g += 4) {
            float4 w = *(const float4*)(wrow + g);
            float4 a = *(const float4*)(arow + g);
            acc += w.x * a.x + w.y * a.y + w.z * a.z + w.w * a.w;
        }
        pred[b][l] = acc;
        float f0 = future[(b * 12 + t) * 2 + 0];
        float f1 = future[(b * 12 + t) * 2 + 1];
        proj[b][l] = f0 * Wl[l * 2 + 0] + f1 * Wl[l * 2 + 1] + bl[l];
    }
    __syncthreads();
    {
        float* row = (tid < 128) ? pred[tid] : proj[tid - 128];
        float ss = 0.0f;
#pragma unroll
        for (int l = 0; l < 16; ++l) ss += row[l] * row[l];
        float inv = 1.0f / fmaxf(sqrtf(ss), 1e-12f);
#pragma unroll
        for (int l = 0; l < 16; ++l) row[l] *= inv;
    }
    __syncthreads();
    float lsbb = 0.0f;
    if (tid < 128) {
        int b = tid;
        float tf[16];
#pragma unroll
        for (int l = 0; l < 16; ++l) tf[l] = proj[b][l];
        float mx = -1e30f, dbb = 0.0f;
        for (int cc = 0; cc < 128; ++cc) {
            float d = 0.0f;
#pragma unroll
            for (int l = 0; l < 16; ++l) d += tf[l] * pred[cc][l];
            mx = fmaxf(mx, d);
            if (cc == b) dbb = d;
        }
        float den = 0.0f;
        for (int cc = 0; cc < 128; ++cc) {
            float d = 0.0f;
#pragma unroll
            for (int l = 0; l < 16; ++l) d += tf[l] * pred[cc][l];
            den += __expf(d - mx);
        }
        lsbb = dbb - mx - __logf(den);
    }
#pragma unroll
    for (int o = 32; o > 0; o >>= 1) lsbb += __shfl_down(lsbb, o);
    if ((tid & 63) == 0) red[tid >> 6] = lsbb;
    __syncthreads();
    if (tid == 0) loss_part[t] = red[0] + red[1] + red[2] + red[3];
}

__global__ void final_kernel(const float* __restrict__ loss_part,
                             float* __restrict__ out)
{
    if (threadIdx.x == 0) {
        float s = 0.0f;
        for (int t = 0; t < 12; ++t) s += loss_part[t];
        out[33152] = -s / 1536.0f;
    }
}

// ---------------------------------------------------------------------------
extern "C" void kernel_launch(void* const* d_in, const int* in_sizes, int n_in,
                              void* d_out, int out_size, void* d_ws, size_t ws_size,
                              hipStream_t stream)
{
    const float* agent_obs = (const float*)d_in[0];
    const float* future    = (const float*)d_in[1];
    const float* hideout   = (const float*)d_in[2];
    const float* timestep  = (const float*)d_in[3];
    // d_in[4] = num_agents (int, ==16)
    const float* W_ih  = (const float*)d_in[5];
    const float* W_hh  = (const float*)d_in[6];
    const float* b_ih  = (const float*)d_in[7];
    const float* b_hh  = (const float*)d_in[8];
    const float* Wsrc1 = (const float*)d_in[9];
    const float* bsrc1 = (const float*)d_in[10];
    const float* Wdst1 = (const float*)d_in[11];
    const float* bdst1 = (const float*)d_in[12];
    const float* attn1 = (const float*)d_in[13];
    const float* Wsrc2 = (const float*)d_in[14];
    const float* bsrc2 = (const float*)d_in[15];
    const float* Wdst2 = (const float*)d_in[16];
    const float* bdst2 = (const float*)d_in[17];
    const float* attn2 = (const float*)d_in[18];
    const float* Wk    = (const float*)d_in[19];
    const float* bk    = (const float*)d_in[20];
    const float* Wl    = (const float*)d_in[21];
    const float* bl    = (const float*)d_in[22];
    float* out = (float*)d_out;

    char* ws = (char*)d_ws;
    const size_t KB = 1024;
    bf16*  wihb  = (bf16*)(ws);                  // 32 KB  (1024x16)
    bf16*  whh2  = (bf16*)(ws + 32 * KB);        // 512 KB (16,512,32) chunked
    bf16*  ws1b  = (bf16*)(ws + 544 * KB);       // 1 MB   (2048x256)
    bf16*  wd1b  = (bf16*)(ws + 1568 * KB);      // 1 MB
    bf16*  ws2b  = (bf16*)(ws + 2592 * KB);      // 128 KB (256x256)
    bf16*  wd2b  = (bf16*)(ws + 2720 * KB);      // 128 KB
    bf16*  hn    = (bf16*)(ws + 2848 * KB);      // 1 MB   (2048x256)
    bf16*  src1  = (bf16*)(ws + 3872 * KB);      // 8 MB   (2048x2048)
    bf16*  dst1  = (bf16*)(ws + 12064 * KB);     // 8 MB
    bf16*  r1    = (bf16*)(ws + 20256 * KB);     // 1 MB   (2048x256)
    bf16*  src2  = (bf16*)(ws + 21280 * KB);     // 1 MB
    bf16*  dst2  = (bf16*)(ws + 22304 * KB);     // 1 MB
    float* acf   = (float*)(ws + 23328 * KB);    // 128 KB (128x256 f32)
    float* lossp = (float*)(ws + 23456 * KB);    // 48 B

    cvt6<<<1424, 256, 0, stream>>>(W_ih, W_hh, Wsrc1, Wdst1, Wsrc2, Wdst2,
                                   wihb, whh2, ws1b, wd1b, ws2b, wd2b);
    lstm_kernel<<<128, 1024, 0, stream>>>(agent_obs, wihb, whh2, b_ih, b_hh, hn);
    gemm_bias<<<dim3(32, 32), 256, 0, stream>>>(hn, ws1b, bsrc1, src1, 2048, 2048);
    gemm_bias<<<dim3(32, 32), 256, 0, stream>>>(hn, wd1b, bdst1, dst1, 2048, 2048);
    gat1_kernel<<<128, 256, 0, stream>>>(src1, dst1, attn1, r1);
    gemm_bias<<<dim3(4, 32), 256, 0, stream>>>(r1, ws2b, bsrc2, src2, 2048, 256);
    gemm_bias<<<dim3(4, 32), 256, 0, stream>>>(r1, wd2b, bdst2, dst2, 2048, 256);
    gat2_kernel<<<128, 256, 0, stream>>>(src2, dst2, attn2, hideout, timestep, out, acf);
    cpc_kernel<<<12, 256, 0, stream>>>(acf, future, Wk, bk, Wl, bl, lossp);
    final_kernel<<<1, 64, 0, stream>>>(lossp, out);
}

// Round 9
// 1350.315 us; speedup vs baseline: 1.9807x; 1.1108x over previous
//
#include <hip/hip_runtime.h>

// CPCGNN: LSTM(2048 x 128 steps, F=16, H=256) -> GATv2 x2 (16-node graphs) ->
// mean pool -> CPC loss. Inputs/outputs FLOAT32; MFMA paths use bf16 copies.
//
// Round 9: LSTM = 128 WGs x 1024 threads (16 waves). W_hh streamed per step
// through a 4 x 32KB LDS ring via global_load_lds (16B), 3-chunk lookahead,
// counted vmcnt(6) (never drained), raw s_barrier per chunk. W source layout
// pre-swizzled in cvt6 so linear gload_lds fill == bank-conflict-free image
// (2-way only). h double-buffered in LDS. No cross-WG sync.

typedef __bf16 bf16;
typedef bf16 bf16x4 __attribute__((ext_vector_type(4)));
typedef bf16 bf16x8 __attribute__((ext_vector_type(8)));
typedef float f32x4 __attribute__((ext_vector_type(4)));

__device__ __forceinline__ float fast_sigmoid(float x) {
    return __builtin_amdgcn_rcpf(1.0f + __expf(-x));
}
__device__ __forceinline__ float fast_tanh(float x) {
    return 2.0f * __builtin_amdgcn_rcpf(1.0f + __expf(-2.0f * x)) - 1.0f;
}
__device__ __forceinline__ bf16x8 zero8() {
    bf16x8 z;
#pragma unroll
    for (int i = 0; i < 8; ++i) z[i] = (bf16)0.0f;
    return z;
}
__device__ __forceinline__ bf16x8 load8_bf(const float* p) {
    float4 a = *(const float4*)p;
    float4 b = *(const float4*)(p + 4);
    bf16x8 r;
    r[0] = (bf16)a.x; r[1] = (bf16)a.y; r[2] = (bf16)a.z; r[3] = (bf16)a.w;
    r[4] = (bf16)b.x; r[5] = (bf16)b.y; r[6] = (bf16)b.z; r[7] = (bf16)b.w;
    return r;
}

// ---------------------------------------------------------------------------
// 0. Weight f32 -> bf16. W_hh -> whh3, chunk-major + bank-swizzled:
//    chunk ic = (k>>5)*2 + (n>>9) holds rows r=n&511 x k-slice; within chunk,
//    16B-slot index slot16 = r*4 + (grp ^ ((r>>1)&3)), grp = (k>>3)&3.
//    A linear 32KB copy of a chunk into LDS reproduces this swizzled image.
// ---------------------------------------------------------------------------
__global__ __launch_bounds__(256, 1) void cvt6(
    const float* __restrict__ s0, const float* __restrict__ s1,
    const float* __restrict__ s2, const float* __restrict__ s3,
    const float* __restrict__ s4, const float* __restrict__ s5,
    bf16* __restrict__ d0, bf16* __restrict__ d1, bf16* __restrict__ d2,
    bf16* __restrict__ d3, bf16* __restrict__ d4, bf16* __restrict__ d5)
{
    const int n0 = 16384, n1 = 262144, n2 = 524288, n3 = 524288, n4 = 65536;
    int loc = (blockIdx.x * 256 + threadIdx.x) * 4;
    const float* s; bf16* d; int dst;
    if (loc < n0)              { s = s0; d = d0; dst = loc; }
    else if ((loc -= n0) < n1) {
        s = s1; d = d1;
        int n = loc >> 8, k = loc & 255;
        int ic = ((k >> 5) << 1) | (n >> 9);
        int r = n & 511, grp = (k >> 3) & 3;
        int slot16 = r * 4 + (grp ^ ((r >> 1) & 3));
        dst = ic * 16384 + slot16 * 8 + (k & 7);
    }
    else if ((loc -= n1) < n2) { s = s2; d = d2; dst = loc; }
    else if ((loc -= n2) < n3) { s = s3; d = d3; dst = loc; }
    else if ((loc -= n3) < n4) { s = s4; d = d4; dst = loc; }
    else                       { loc -= n4; s = s5; d = d5; dst = loc; }
    float4 v = *(const float4*)(s + loc);
    bf16x4 o;
    o[0] = (bf16)v.x; o[1] = (bf16)v.y; o[2] = (bf16)v.z; o[3] = (bf16)v.w;
    *(bf16x4*)(d + dst) = o;
}

// ---------------------------------------------------------------------------
// 1. LSTM. WG b = graph b. 16 waves; wave w owns tau=w (gate-cols
//    n = G*256 + w*16 + col, G=0..3). Per step: 16 chunk-iters
//    {lgkmcnt(0); s_barrier; stage(ic+3); vmcnt(6); ds_read W + MFMA}.
//    Chunk (kc,gh) = 512 rows x 32 k = 32KB, ring slot ic&3.
// ---------------------------------------------------------------------------
__global__ __launch_bounds__(1024) void lstm_kernel(
    const float* __restrict__ agent_obs,  // (128,128,16,16) f32
    const bf16* __restrict__ W_ih,        // (1024,16) bf16
    const bf16* __restrict__ whh3,        // (16,16384) bf16 chunked+swizzled
    const float* __restrict__ b_ih,
    const float* __restrict__ b_hh,
    bf16* __restrict__ hn)                // (2048,256) bf16
{
    __shared__ bf16 wring[4][16384];      // 128 KB ring
    __shared__ bf16 hbuf[2][16][264];     // 16.9 KB double-buffered h
    const int tid  = threadIdx.x;
    const int lane = tid & 63;
    const int w    = tid >> 6;            // wave id = tau
    const int col  = lane & 15;           // A-row (agent) / B-col (within tau)
    const int grp  = lane >> 4;           // k-group
    const int b    = blockIdx.x;

    for (int i = tid; i < 2 * 16 * 264; i += 1024) (&hbuf[0][0][0])[i] = (bf16)0.0f;

    // per-lane invariants
    float bias[4];
    bf16x8 wih[4];
    int slot16g[4];                       // swizzled 16B-slot per gate
#pragma unroll
    for (int G = 0; G < 4; ++G) {
        int n = G * 256 + w * 16 + col;
        bias[G] = b_ih[n] + b_hh[n];
        wih[G] = (grp < 2) ? *(const bf16x8*)&W_ih[n * 16 + grp * 8] : zero8();
        int r = (G & 1) * 256 + w * 16 + col;
        slot16g[G] = r * 4 + (grp ^ ((r >> 1) & 3));
    }
    f32x4 c = (f32x4){0.0f, 0.0f, 0.0f, 0.0f};
    const float* xb = agent_obs + (size_t)b * 32768;

    // stage one 32KB chunk: per wave 2 x (64 lanes x 16B); LDS base uniform
    auto stage = [&](int chunkid, int sl) {
        const bf16* gs = whh3 + (size_t)chunkid * 16384 + w * 512 + lane * 8;
        bf16* ls = &wring[sl][w * 512];
        __builtin_amdgcn_global_load_lds((const void*)gs, (void*)ls, 16, 0, 0);
        __builtin_amdgcn_global_load_lds((const void*)(gs + 8192),
                                         (void*)(ls + 8192), 16, 0, 0);
    };

    stage(0, 0);
    stage(1, 1);
    stage(2, 2);
    __syncthreads();                      // hbuf zeros + (over-)sync

    for (int s = 0; s < 128; ++s) {
        const int pr = s & 1, pw = pr ^ 1;
        bf16x8 ax = (grp < 2) ? load8_bf(xb + s * 256 + col * 16 + grp * 8)
                              : zero8();
        f32x4 acc[4];
#pragma unroll
        for (int G = 0; G < 4; ++G) {
            float bs_ = bias[G];
            acc[G] = (f32x4){bs_, bs_, bs_, bs_};
        }
        bf16x8 ah = zero8();
#pragma unroll
        for (int ic = 0; ic < 16; ++ic) {
            const int kc = ic >> 1, gh = ic & 1, sl = ic & 3;
            asm volatile("s_waitcnt lgkmcnt(0)" ::: "memory");
            __builtin_amdgcn_s_barrier();
            stage((ic + 3) & 15, (ic + 3) & 3);
            asm volatile("s_waitcnt vmcnt(6)" ::: "memory");
            if (gh == 0)
                ah = *(const bf16x8*)&hbuf[pr][col][kc * 32 + grp * 8];
#pragma unroll
            for (int gl = 0; gl < 2; ++gl) {
                const int G = gh * 2 + gl;
                bf16x8 bw = *(const bf16x8*)&wring[sl][slot16g[G] * 8];
                acc[G] = __builtin_amdgcn_mfma_f32_16x16x32_bf16(
                    ah, bw, acc[G], 0, 0, 0);
            }
        }
        // input contribution
#pragma unroll
        for (int G = 0; G < 4; ++G)
            acc[G] = __builtin_amdgcn_mfma_f32_16x16x32_bf16(ax, wih[G], acc[G], 0, 0, 0);
        // gates: lane holds rows m=grp*4+r, col j=w*16+col
#pragma unroll
        for (int r = 0; r < 4; ++r) {
            float iv = fast_sigmoid(acc[0][r]);
            float fv = fast_sigmoid(acc[1][r]);
            float gv = fast_tanh(acc[2][r]);
            float ov = fast_sigmoid(acc[3][r]);
            float cn = fv * c[r] + iv * gv;
            c[r] = cn;
            float hv = ov * fast_tanh(cn);
            int m = grp * 4 + r, j = w * 16 + col;
            if (s == 127) hn[((size_t)b * 16 + m) * 256 + j] = (bf16)hv;
            else          hbuf[pw][m][j] = (bf16)hv;
        }
    }
}

// ---------------------------------------------------------------------------
// 2. GEMM: C[M,N] = A[M,256] @ W[N,256]^T + bias. A,W,C bf16; bias f32.
// ---------------------------------------------------------------------------
__global__ __launch_bounds__(256, 1) void gemm_bias(
    const bf16* __restrict__ A, const bf16* __restrict__ W,
    const float* __restrict__ bias, bf16* __restrict__ C, int M, int N)
{
    const int tid = threadIdx.x, lane = tid & 63, wv = tid >> 6;
    const int col = lane & 15, grp = lane >> 4;
    const int n = blockIdx.x * 64 + wv * 16 + col;
    const int bm = blockIdx.y * 64;
    float bs = bias[n];
    f32x4 acc[4];
#pragma unroll
    for (int mt = 0; mt < 4; ++mt) acc[mt] = (f32x4){bs, bs, bs, bs};
#pragma unroll
    for (int kc = 0; kc < 8; ++kc) {
        bf16x8 bw = *(const bf16x8*)&W[(size_t)n * 256 + kc * 32 + grp * 8];
#pragma unroll
        for (int mt = 0; mt < 4; ++mt) {
            bf16x8 aa = *(const bf16x8*)
                &A[(size_t)(bm + mt * 16 + col) * 256 + kc * 32 + grp * 8];
            acc[mt] = __builtin_amdgcn_mfma_f32_16x16x32_bf16(aa, bw, acc[mt], 0, 0, 0);
        }
    }
#pragma unroll
    for (int mt = 0; mt < 4; ++mt)
#pragma unroll
        for (int r = 0; r < 4; ++r)
            C[(size_t)(bm + mt * 16 + grp * 4 + r) * N + n] = (bf16)acc[mt][r];
}

// ---------------------------------------------------------------------------
// 3. GATv2 layer 1: scores + edge softmax (no self) + head-mean aggregation.
// ---------------------------------------------------------------------------
__global__ __launch_bounds__(256, 1) void gat1_kernel(
    const bf16* __restrict__ src,    // (2048, 2048) = (b*16+n, h*256+f)
    const bf16* __restrict__ dst,
    const float* __restrict__ attn,  // (8,256) f32
    bf16* __restrict__ r1)           // (2048, 256)
{
    __shared__ float sal[2048];      // (i*16+j)*8+h
    const int tid = threadIdx.x, b = blockIdx.x;
    const bf16* sb = src + (size_t)b * 32768;
    const bf16* db = dst + (size_t)b * 32768;

    for (int ii = 0; ii < 8; ++ii) {
        int trip = tid + ii * 256;            // i*128 + j*8 + h
        int i = trip >> 7, j = (trip >> 3) & 15, h = trip & 7;
        const bf16* ps = sb + j * 2048 + h * 256;
        const bf16* pd = db + i * 2048 + h * 256;
        const float* pa = attn + h * 256;
        float acc = 0.0f;
        for (int f8 = 0; f8 < 32; ++f8) {
            bf16x8 vs = *(const bf16x8*)(ps + f8 * 8);
            bf16x8 vd = *(const bf16x8*)(pd + f8 * 8);
            float4 a0 = *(const float4*)(pa + f8 * 8);
            float4 a1 = *(const float4*)(pa + f8 * 8 + 4);
            float av[8] = {a0.x, a0.y, a0.z, a0.w, a1.x, a1.y, a1.z, a1.w};
#pragma unroll
            for (int e = 0; e < 8; ++e) {
                float v = (float)vs[e] + (float)vd[e];
                v = v > 0.0f ? v : 0.2f * v;
                acc += v * av[e];
            }
        }
        sal[trip] = acc;
    }
    __syncthreads();
    if (tid < 128) {                          // softmax over j != i
        int i = tid >> 3, h = tid & 7;
        float m = -1e30f;
#pragma unroll
        for (int j = 0; j < 16; ++j)
            if (j != i) m = fmaxf(m, sal[(i * 16 + j) * 8 + h]);
        float ex[16], den = 0.0f;
#pragma unroll
        for (int j = 0; j < 16; ++j) {
            ex[j] = (j == i) ? 0.0f : __expf(sal[(i * 16 + j) * 8 + h] - m);
            den += ex[j];
        }
        float rd = 1.0f / den;
#pragma unroll
        for (int j = 0; j < 16; ++j) sal[(i * 16 + j) * 8 + h] = ex[j] * rd;
    }
    __syncthreads();
    {
        int i = tid >> 4, fb = tid & 15;
        for (int it = 0; it < 16; ++it) {
            int f = fb + it * 16;
            float acc = 0.0f;
            for (int j = 0; j < 16; ++j) {
                const bf16* ps = sb + j * 2048 + f;
#pragma unroll
                for (int h = 0; h < 8; ++h)
                    acc += sal[(i * 16 + j) * 8 + h] * (float)ps[h * 256];
            }
            r1[((size_t)b * 16 + i) * 256 + f] = (bf16)(acc * 0.125f);
        }
    }
}

// ---------------------------------------------------------------------------
// 4. GATv2 layer 2 (1 head) fused with node-mean + d_out row writes.
// ---------------------------------------------------------------------------
__global__ __launch_bounds__(256, 1) void gat2_kernel(
    const bf16* __restrict__ src2,   // (2048,256)
    const bf16* __restrict__ dst2,
    const float* __restrict__ attn2, // (256) f32
    const float* __restrict__ hideout,   // (128,2) f32
    const float* __restrict__ timestep,  // (128,1) f32
    float* __restrict__ out,             // (128,259)+loss f32
    float* __restrict__ ac_ws)           // (128,256) f32
{
    __shared__ float sal[256];
    __shared__ float wj[16];
    const int tid = threadIdx.x, b = blockIdx.x;
    const bf16* sb = src2 + (size_t)b * 4096;
    const bf16* db = dst2 + (size_t)b * 4096;
    {
        int i = tid >> 4, j = tid & 15;
        const bf16* ps = sb + j * 256;
        const bf16* pd = db + i * 256;
        float acc = 0.0f;
        for (int g8 = 0; g8 < 32; ++g8) {
            bf16x8 vs = *(const bf16x8*)(ps + g8 * 8);
            bf16x8 vd = *(const bf16x8*)(pd + g8 * 8);
            float4 a0 = *(const float4*)(attn2 + g8 * 8);
            float4 a1 = *(const float4*)(attn2 + g8 * 8 + 4);
            float av[8] = {a0.x, a0.y, a0.z, a0.w, a1.x, a1.y, a1.z, a1.w};
#pragma unroll
            for (int e = 0; e < 8; ++e) {
                float v = (float)vs[e] + (float)vd[e];
                v = v > 0.0f ? v : 0.2f * v;
                acc += v * av[e];
            }
        }
        sal[tid] = acc;
    }
    __syncthreads();
    if (tid < 16) {
        int i = tid;
        float m = -1e30f;
#pragma unroll
        for (int j = 0; j < 16; ++j)
            if (j != i) m = fmaxf(m, sal[i * 16 + j]);
        float ex[16], den = 0.0f;
#pragma unroll
        for (int j = 0; j < 16; ++j) {
            ex[j] = (j == i) ? 0.0f : __expf(sal[i * 16 + j] - m);
            den += ex[j];
        }
        float rd = 1.0f / den;
#pragma unroll
        for (int j = 0; j < 16; ++j) sal[i * 16 + j] = ex[j] * rd;
    }
    __syncthreads();
    if (tid < 16) {
        float a = 0.0f;
#pragma unroll
        for (int i = 0; i < 16; ++i) a += sal[i * 16 + tid];
        wj[tid] = a * (1.0f / 16.0f);
    }
    __syncthreads();
    {
        int g = tid;
        float acc = 0.0f;
#pragma unroll
        for (int j = 0; j < 16; ++j) acc += wj[j] * (float)sb[j * 256 + g];
        ac_ws[b * 256 + g] = acc;
        out[(size_t)b * 259 + g] = acc;
    }
    if (tid < 2) out[(size_t)b * 259 + 256 + tid] = hideout[b * 2 + tid];
    if (tid == 0) out[(size_t)b * 259 + 258] = timestep[b];
}

// ---------------------------------------------------------------------------
// 5. CPC: one WG per t. pred/proj -> l2norm -> logits -> log-softmax diag.
// ---------------------------------------------------------------------------
__global__ __launch_bounds__(256, 1) void cpc_kernel(
    const float* __restrict__ ac,      // (128,256) f32
    const float* __restrict__ future,  // (128,12,2) f32
    const float* __restrict__ Wk,      // (12,16,256) f32
    const float* __restrict__ bk,      // (12,16) f32
    const float* __restrict__ Wl,      // (16,2) f32
    const float* __restrict__ bl,      // (16) f32
    float* __restrict__ loss_part)     // (12) f32
{
    __shared__ float pred[128][17];
    __shared__ float proj[128][17];
    __shared__ float red[4];
    const int tid = threadIdx.x, t = blockIdx.x;

    for (int ii = 0; ii < 8; ++ii) {
        int idx = tid + ii * 256;
        int b = idx >> 4, l = idx & 15;
        const float* wrow = Wk + ((size_t)t * 16 + l) * 256;
        const float* arow = ac + b * 256;
        float acc = bk[t * 16 + l];
        for (int g = 0; g < 256; g += 4) {
            float4 w = *(const float4*)(wrow + g);
            float4 a = *(const float4*)(arow + g);
            acc += w.x * a.x + w.y * a.y + w.z * a.z + w.w * a.w;
        }
        pred[b][l] = acc;
        float f0 = future[(b * 12 + t) * 2 + 0];
        float f1 = future[(b * 12 + t) * 2 + 1];
        proj[b][l] = f0 * Wl[l * 2 + 0] + f1 * Wl[l * 2 + 1] + bl[l];
    }
    __syncthreads();
    {
        float* row = (tid < 128) ? pred[tid] : proj[tid - 128];
        float ss = 0.0f;
#pragma unroll
        for (int l = 0; l < 16; ++l) ss += row[l] * row[l];
        float inv = 1.0f / fmaxf(sqrtf(ss), 1e-12f);
#pragma unroll
        for (int l = 0; l < 16; ++l) row[l] *= inv;
    }
    __syncthreads();
    float lsbb = 0.0f;
    if (tid < 128) {
        int b = tid;
        float tf[16];
#pragma unroll
        for (int l = 0; l < 16; ++l) tf[l] = proj[b][l];
        float mx = -1e30f, dbb = 0.0f;
        for (int cc = 0; cc < 128; ++cc) {
            float d = 0.0f;
#pragma unroll
            for (int l = 0; l < 16; ++l) d += tf[l] * pred[cc][l];
            mx = fmaxf(mx, d);
            if (cc == b) dbb = d;
        }
        float den = 0.0f;
        for (int cc = 0; cc < 128; ++cc) {
            float d = 0.0f;
#pragma unroll
            for (int l = 0; l < 16; ++l) d += tf[l] * pred[cc][l];
            den += __expf(d - mx);
        }
        lsbb = dbb - mx - __logf(den);
    }
#pragma unroll
    for (int o = 32; o > 0; o >>= 1) lsbb += __shfl_down(lsbb, o);
    if ((tid & 63) == 0) red[tid >> 6] = lsbb;
    __syncthreads();
    if (tid == 0) loss_part[t] = red[0] + red[1] + red[2] + red[3];
}

__global__ void final_kernel(const float* __restrict__ loss_part,
                             float* __restrict__ out)
{
    if (threadIdx.x == 0) {
        float s = 0.0f;
        for (int t = 0; t < 12; ++t) s += loss_part[t];
        out[33152] = -s / 1536.0f;
    }
}

// ---------------------------------------------------------------------------
extern "C" void kernel_launch(void* const* d_in, const int* in_sizes, int n_in,
                              void* d_out, int out_size, void* d_ws, size_t ws_size,
                              hipStream_t stream)
{
    const float* agent_obs = (const float*)d_in[0];
    const float* future    = (const float*)d_in[1];
    const float* hideout   = (const float*)d_in[2];
    const float* timestep  = (const float*)d_in[3];
    // d_in[4] = num_agents (int, ==16)
    const float* W_ih  = (const float*)d_in[5];
    const float* W_hh  = (const float*)d_in[6];
    const float* b_ih  = (const float*)d_in[7];
    const float* b_hh  = (const float*)d_in[8];
    const float* Wsrc1 = (const float*)d_in[9];
    const float* bsrc1 = (const float*)d_in[10];
    const float* Wdst1 = (const float*)d_in[11];
    const float* bdst1 = (const float*)d_in[12];
    const float* attn1 = (const float*)d_in[13];
    const float* Wsrc2 = (const float*)d_in[14];
    const float* bsrc2 = (const float*)d_in[15];
    const float* Wdst2 = (const float*)d_in[16];
    const float* bdst2 = (const float*)d_in[17];
    const float* attn2 = (const float*)d_in[18];
    const float* Wk    = (const float*)d_in[19];
    const float* bk    = (const float*)d_in[20];
    const float* Wl    = (const float*)d_in[21];
    const float* bl    = (const float*)d_in[22];
    float* out = (float*)d_out;

    char* ws = (char*)d_ws;
    const size_t KB = 1024;
    bf16*  wihb  = (bf16*)(ws);                  // 32 KB  (1024x16)
    bf16*  whh3  = (bf16*)(ws + 32 * KB);        // 512 KB (16,16384) swizzled
    bf16*  ws1b  = (bf16*)(ws + 544 * KB);       // 1 MB   (2048x256)
    bf16*  wd1b  = (bf16*)(ws + 1568 * KB);      // 1 MB
    bf16*  ws2b  = (bf16*)(ws + 2592 * KB);      // 128 KB (256x256)
    bf16*  wd2b  = (bf16*)(ws + 2720 * KB);      // 128 KB
    bf16*  hn    = (bf16*)(ws + 2848 * KB);      // 1 MB   (2048x256)
    bf16*  src1  = (bf16*)(ws + 3872 * KB);      // 8 MB   (2048x2048)
    bf16*  dst1  = (bf16*)(ws + 12064 * KB);     // 8 MB
    bf16*  r1    = (bf16*)(ws + 20256 * KB);     // 1 MB   (2048x256)
    bf16*  src2  = (bf16*)(ws + 21280 * KB);     // 1 MB
    bf16*  dst2  = (bf16*)(ws + 22304 * KB);     // 1 MB
    float* acf   = (float*)(ws + 23328 * KB);    // 128 KB (128x256 f32)
    float* lossp = (float*)(ws + 23456 * KB);    // 48 B

    cvt6<<<1424, 256, 0, stream>>>(W_ih, W_hh, Wsrc1, Wdst1, Wsrc2, Wdst2,
                                   wihb, whh3, ws1b, wd1b, ws2b, wd2b);
    lstm_kernel<<<128, 1024, 0, stream>>>(agent_obs, wihb, whh3, b_ih, b_hh, hn);
    gemm_bias<<<dim3(32, 32), 256, 0, stream>>>(hn, ws1b, bsrc1, src1, 2048, 2048);
    gemm_bias<<<dim3(32, 32), 256, 0, stream>>>(hn, wd1b, bdst1, dst1, 2048, 2048);
    gat1_kernel<<<128, 256, 0, stream>>>(src1, dst1, attn1, r1);
    gemm_bias<<<dim3(4, 32), 256, 0, stream>>>(r1, ws2b, bsrc2, src2, 2048, 256);
    gemm_bias<<<dim3(4, 32), 256, 0, stream>>>(r1, wd2b, bdst2, dst2, 2048, 256);
    gat2_kernel<<<128, 256, 0, stream>>>(src2, dst2, attn2, hideout, timestep, out, acf);
    cpc_kernel<<<12, 256, 0, stream>>>(acf, future, Wk, bk, Wl, bl, lossp);
    final_kernel<<<1, 64, 0, stream>>>(lossp, out);
}

// Round 10
// 1301.282 us; speedup vs baseline: 2.0553x; 1.0377x over previous
//
#include <hip/hip_runtime.h>

// CPCGNN: LSTM(2048 x 128 steps, F=16, H=256) -> GATv2 x2 (16-node graphs) ->
// mean pool -> CPC loss. Inputs/outputs FLOAT32; MFMA paths use bf16 copies.
//
// Round 10: LSTM = 128 WGs x 1024 threads. W streamed via PER-WAVE private
// global_load_lds pipelines (each wave stages exactly the 2KB slice it
// consumes): 4-slot ring x 16 waves, 3-chunk lookahead, own-wave vmcnt(6) and
// lgkmcnt(0) only — NO barriers in the chunk loop. One lgkmcnt-only s_barrier
// per step for the h exchange (W stream never drained). Lane-linear W layout
// (cvt6) makes every ds_read_b128 conflict-free.

typedef __bf16 bf16;
typedef bf16 bf16x4 __attribute__((ext_vector_type(4)));
typedef bf16 bf16x8 __attribute__((ext_vector_type(8)));
typedef float f32x4 __attribute__((ext_vector_type(4)));

__device__ __forceinline__ float fast_sigmoid(float x) {
    return __builtin_amdgcn_rcpf(1.0f + __expf(-x));
}
__device__ __forceinline__ float fast_tanh(float x) {
    return 2.0f * __builtin_amdgcn_rcpf(1.0f + __expf(-2.0f * x)) - 1.0f;
}
__device__ __forceinline__ bf16x8 zero8() {
    bf16x8 z;
#pragma unroll
    for (int i = 0; i < 8; ++i) z[i] = (bf16)0.0f;
    return z;
}
__device__ __forceinline__ bf16x8 load8_bf(const float* p) {
    float4 a = *(const float4*)p;
    float4 b = *(const float4*)(p + 4);
    bf16x8 r;
    r[0] = (bf16)a.x; r[1] = (bf16)a.y; r[2] = (bf16)a.z; r[3] = (bf16)a.w;
    r[4] = (bf16)b.x; r[5] = (bf16)b.y; r[6] = (bf16)b.z; r[7] = (bf16)b.w;
    return r;
}

// ---------------------------------------------------------------------------
// 0. Weight f32 -> bf16. W_hh -> whh4: per-(chunk, wave) 1024-elem slices,
//    lane-linear within slice so ds_read_b128 at lane*16B == B-fragment:
//    src (n,k): G=n>>8, w=(n>>4)&15, col=n&15, kc=k>>5, grp=(k>>3)&3, k8=k&7
//    dst = (kc*2+(G>>1))*16384 + w*1024 + (G&1)*512 + grp*128 + col*8 + k8.
// ---------------------------------------------------------------------------
__global__ __launch_bounds__(256, 1) void cvt6(
    const float* __restrict__ s0, const float* __restrict__ s1,
    const float* __restrict__ s2, const float* __restrict__ s3,
    const float* __restrict__ s4, const float* __restrict__ s5,
    bf16* __restrict__ d0, bf16* __restrict__ d1, bf16* __restrict__ d2,
    bf16* __restrict__ d3, bf16* __restrict__ d4, bf16* __restrict__ d5)
{
    const int n0 = 16384, n1 = 262144, n2 = 524288, n3 = 524288, n4 = 65536;
    int loc = (blockIdx.x * 256 + threadIdx.x) * 4;
    const float* s; bf16* d; int dst;
    if (loc < n0)              { s = s0; d = d0; dst = loc; }
    else if ((loc -= n0) < n1) {
        s = s1; d = d1;
        int n = loc >> 8, k = loc & 255;
        int G = n >> 8, w_ = (n >> 4) & 15, col = n & 15;
        int kc = k >> 5, grp = (k >> 3) & 3, k8 = k & 7;
        dst = (kc * 2 + (G >> 1)) * 16384 + w_ * 1024 + (G & 1) * 512
              + grp * 128 + col * 8 + k8;
    }
    else if ((loc -= n1) < n2) { s = s2; d = d2; dst = loc; }
    else if ((loc -= n2) < n3) { s = s3; d = d3; dst = loc; }
    else if ((loc -= n3) < n4) { s = s4; d = d4; dst = loc; }
    else                       { loc -= n4; s = s5; d = d5; dst = loc; }
    float4 v = *(const float4*)(s + loc);
    bf16x4 o;
    o[0] = (bf16)v.x; o[1] = (bf16)v.y; o[2] = (bf16)v.z; o[3] = (bf16)v.w;
    *(bf16x4*)(d + dst) = o;
}

// ---------------------------------------------------------------------------
// 1. LSTM. WG b = graph b. Wave w owns tau=w (gate-cols n = G*256+w*16+col).
//    Continuous chunk stream cc = s*16+ic; wave stages its own slice of
//    chunk cc+3 each iter, waits own vmcnt(6), ds_read_b128 + 2 MFMA.
//    No chunk barriers; one lgkmcnt-only barrier per step for hbuf.
// ---------------------------------------------------------------------------
__global__ __launch_bounds__(1024)
__attribute__((amdgpu_waves_per_eu(4, 4)))
void lstm_kernel(
    const float* __restrict__ agent_obs,  // (128,128,16,16) f32
    const bf16* __restrict__ W_ih,        // (1024,16) bf16
    const bf16* __restrict__ whh4,        // (16,16,1024) bf16 per-wave slices
    const float* __restrict__ b_ih,
    const float* __restrict__ b_hh,
    bf16* __restrict__ hn)                // (2048,256) bf16
{
    __shared__ bf16 wring[4][16][1024];   // 128 KB: [slot][wave][slice]
    __shared__ bf16 hbuf[2][16][264];     // 16.9 KB double-buffered h
    const int tid  = threadIdx.x;
    const int lane = tid & 63;
    const int w    = tid >> 6;            // wave id = tau
    const int col  = lane & 15;
    const int grp  = lane >> 4;
    const int b    = blockIdx.x;

    for (int i = tid; i < 16 * 264; i += 1024) (&hbuf[0][0][0])[i] = (bf16)0.0f;

    float bias[4];
    bf16x8 wih[4];
#pragma unroll
    for (int G = 0; G < 4; ++G) {
        int n = G * 256 + w * 16 + col;
        bias[G] = b_ih[n] + b_hh[n];
        wih[G] = (grp < 2) ? *(const bf16x8*)&W_ih[n * 16 + grp * 8] : zero8();
    }
    f32x4 c = (f32x4){0.0f, 0.0f, 0.0f, 0.0f};
    const float* xb = agent_obs + (size_t)b * 32768;
    const bf16* wsrc = whh4 + w * 1024 + lane * 8;   // + (cc&15)*16384

    // stage this wave's 2KB slice of chunk cc into ring slot cc&3
    auto stage = [&](int cc) {
        const bf16* gs = wsrc + (size_t)(cc & 15) * 16384;
        bf16* ls = &wring[cc & 3][w][0];
        __builtin_amdgcn_global_load_lds((const void*)gs, (void*)ls, 16, 0, 0);
        __builtin_amdgcn_global_load_lds((const void*)(gs + 512),
                                         (void*)(ls + 512), 16, 0, 0);
    };

    __syncthreads();                      // hbuf zeros visible
    stage(0); stage(1); stage(2);

    for (int s = 0; s < 128; ++s) {
        const int pr = s & 1, pw = pr ^ 1;
        bf16x8 ax = (grp < 2) ? load8_bf(xb + s * 256 + col * 16 + grp * 8)
                              : zero8();
        f32x4 acc[4];
#pragma unroll
        for (int G = 0; G < 4; ++G) {
            float bs_ = bias[G];
            acc[G] = (f32x4){bs_, bs_, bs_, bs_};
        }
        bf16x8 ah = zero8();
#pragma unroll
        for (int ic = 0; ic < 16; ++ic) {
            const int cc = s * 16 + ic;
            const int kc = ic >> 1, gh = ic & 1, sl = ic & 3;
            // own-wave: prior ds_reads done before overwriting slot (cc+3)&3
            asm volatile("s_waitcnt lgkmcnt(0)" ::: "memory");
            stage(cc + 3);
            asm volatile("s_waitcnt vmcnt(6)" ::: "memory");  // slice cc ready
            if (gh == 0)
                ah = *(const bf16x8*)&hbuf[pr][col][kc * 32 + grp * 8];
#pragma unroll
            for (int gl = 0; gl < 2; ++gl) {
                bf16x8 bw = *(const bf16x8*)&wring[sl][w][gl * 512 + lane * 8];
                acc[gh * 2 + gl] = __builtin_amdgcn_mfma_f32_16x16x32_bf16(
                    ah, bw, acc[gh * 2 + gl], 0, 0, 0);
            }
        }
        // input contribution
#pragma unroll
        for (int G = 0; G < 4; ++G)
            acc[G] = __builtin_amdgcn_mfma_f32_16x16x32_bf16(ax, wih[G], acc[G], 0, 0, 0);
        // gates: lane holds rows m=grp*4+r, col j=w*16+col
#pragma unroll
        for (int r = 0; r < 4; ++r) {
            float iv = fast_sigmoid(acc[0][r]);
            float fv = fast_sigmoid(acc[1][r]);
            float gv = fast_tanh(acc[2][r]);
            float ov = fast_sigmoid(acc[3][r]);
            float cn = fv * c[r] + iv * gv;
            c[r] = cn;
            float hv = ov * fast_tanh(cn);
            int m = grp * 4 + r, j = w * 16 + col;
            if (s == 127) hn[((size_t)b * 16 + m) * 256 + j] = (bf16)hv;
            else          hbuf[pw][m][j] = (bf16)hv;
        }
        // h exchange: drain LDS writes only — W vmcnt stream keeps flowing
        asm volatile("s_waitcnt lgkmcnt(0)" ::: "memory");
        __builtin_amdgcn_s_barrier();
    }
}

// ---------------------------------------------------------------------------
// 2. GEMM: C[M,N] = A[M,256] @ W[N,256]^T + bias. A,W,C bf16; bias f32.
// ---------------------------------------------------------------------------
__global__ __launch_bounds__(256, 1) void gemm_bias(
    const bf16* __restrict__ A, const bf16* __restrict__ W,
    const float* __restrict__ bias, bf16* __restrict__ C, int M, int N)
{
    const int tid = threadIdx.x, lane = tid & 63, wv = tid >> 6;
    const int col = lane & 15, grp = lane >> 4;
    const int n = blockIdx.x * 64 + wv * 16 + col;
    const int bm = blockIdx.y * 64;
    float bs = bias[n];
    f32x4 acc[4];
#pragma unroll
    for (int mt = 0; mt < 4; ++mt) acc[mt] = (f32x4){bs, bs, bs, bs};
#pragma unroll
    for (int kc = 0; kc < 8; ++kc) {
        bf16x8 bw = *(const bf16x8*)&W[(size_t)n * 256 + kc * 32 + grp * 8];
#pragma unroll
        for (int mt = 0; mt < 4; ++mt) {
            bf16x8 aa = *(const bf16x8*)
                &A[(size_t)(bm + mt * 16 + col) * 256 + kc * 32 + grp * 8];
            acc[mt] = __builtin_amdgcn_mfma_f32_16x16x32_bf16(aa, bw, acc[mt], 0, 0, 0);
        }
    }
#pragma unroll
    for (int mt = 0; mt < 4; ++mt)
#pragma unroll
        for (int r = 0; r < 4; ++r)
            C[(size_t)(bm + mt * 16 + grp * 4 + r) * N + n] = (bf16)acc[mt][r];
}

// ---------------------------------------------------------------------------
// 3. GATv2 layer 1: scores + edge softmax (no self) + head-mean aggregation.
// ---------------------------------------------------------------------------
__global__ __launch_bounds__(256, 1) void gat1_kernel(
    const bf16* __restrict__ src,    // (2048, 2048) = (b*16+n, h*256+f)
    const bf16* __restrict__ dst,
    const float* __restrict__ attn,  // (8,256) f32
    bf16* __restrict__ r1)           // (2048, 256)
{
    __shared__ float sal[2048];      // (i*16+j)*8+h
    const int tid = threadIdx.x, b = blockIdx.x;
    const bf16* sb = src + (size_t)b * 32768;
    const bf16* db = dst + (size_t)b * 32768;

    for (int ii = 0; ii < 8; ++ii) {
        int trip = tid + ii * 256;            // i*128 + j*8 + h
        int i = trip >> 7, j = (trip >> 3) & 15, h = trip & 7;
        const bf16* ps = sb + j * 2048 + h * 256;
        const bf16* pd = db + i * 2048 + h * 256;
        const float* pa = attn + h * 256;
        float acc = 0.0f;
        for (int f8 = 0; f8 < 32; ++f8) {
            bf16x8 vs = *(const bf16x8*)(ps + f8 * 8);
            bf16x8 vd = *(const bf16x8*)(pd + f8 * 8);
            float4 a0 = *(const float4*)(pa + f8 * 8);
            float4 a1 = *(const float4*)(pa + f8 * 8 + 4);
            float av[8] = {a0.x, a0.y, a0.z, a0.w, a1.x, a1.y, a1.z, a1.w};
#pragma unroll
            for (int e = 0; e < 8; ++e) {
                float v = (float)vs[e] + (float)vd[e];
                v = v > 0.0f ? v : 0.2f * v;
                acc += v * av[e];
            }
        }
        sal[trip] = acc;
    }
    __syncthreads();
    if (tid < 128) {                          // softmax over j != i
        int i = tid >> 3, h = tid & 7;
        float m = -1e30f;
#pragma unroll
        for (int j = 0; j < 16; ++j)
            if (j != i) m = fmaxf(m, sal[(i * 16 + j) * 8 + h]);
        float ex[16], den = 0.0f;
#pragma unroll
        for (int j = 0; j < 16; ++j) {
            ex[j] = (j == i) ? 0.0f : __expf(sal[(i * 16 + j) * 8 + h] - m);
            den += ex[j];
        }
        float rd = 1.0f / den;
#pragma unroll
        for (int j = 0; j < 16; ++j) sal[(i * 16 + j) * 8 + h] = ex[j] * rd;
    }
    __syncthreads();
    {
        int i = tid >> 4, fb = tid & 15;
        for (int it = 0; it < 16; ++it) {
            int f = fb + it * 16;
            float acc = 0.0f;
            for (int j = 0; j < 16; ++j) {
                const bf16* ps = sb + j * 2048 + f;
#pragma unroll
                for (int h = 0; h < 8; ++h)
                    acc += sal[(i * 16 + j) * 8 + h] * (float)ps[h * 256];
            }
            r1[((size_t)b * 16 + i) * 256 + f] = (bf16)(acc * 0.125f);
        }
    }
}

// ---------------------------------------------------------------------------
// 4. GATv2 layer 2 (1 head) fused with node-mean + d_out row writes.
// ---------------------------------------------------------------------------
__global__ __launch_bounds__(256, 1) void gat2_kernel(
    const bf16* __restrict__ src2,   // (2048,256)
    const bf16* __restrict__ dst2,
    const float* __restrict__ attn2, // (256) f32
    const float* __restrict__ hideout,   // (128,2) f32
    const float* __restrict__ timestep,  // (128,1) f32
    float* __restrict__ out,             // (128,259)+loss f32
    float* __restrict__ ac_ws)           // (128,256) f32
{
    __shared__ float sal[256];
    __shared__ float wj[16];
    const int tid = threadIdx.x, b = blockIdx.x;
    const bf16* sb = src2 + (size_t)b * 4096;
    const bf16* db = dst2 + (size_t)b * 4096;
    {
        int i = tid >> 4, j = tid & 15;
        const bf16* ps = sb + j * 256;
        const bf16* pd = db + i * 256;
        float acc = 0.0f;
        for (int g8 = 0; g8 < 32; ++g8) {
            bf16x8 vs = *(const bf16x8*)(ps + g8 * 8);
            bf16x8 vd = *(const bf16x8*)(pd + g8 * 8);
            float4 a0 = *(const float4*)(attn2 + g8 * 8);
            float4 a1 = *(const float4*)(attn2 + g8 * 8 + 4);
            float av[8] = {a0.x, a0.y, a0.z, a0.w, a1.x, a1.y, a1.z, a1.w};
#pragma unroll
            for (int e = 0; e < 8; ++e) {
                float v = (float)vs[e] + (float)vd[e];
                v = v > 0.0f ? v : 0.2f * v;
                acc += v * av[e];
            }
        }
        sal[tid] = acc;
    }
    __syncthreads();
    if (tid < 16) {
        int i = tid;
        float m = -1e30f;
#pragma unroll
        for (int j = 0; j < 16; ++j)
            if (j != i) m = fmaxf(m, sal[i * 16 + j]);
        float ex[16], den = 0.0f;
#pragma unroll
        for (int j = 0; j < 16; ++j) {
            ex[j] = (j == i) ? 0.0f : __expf(sal[i * 16 + j] - m);
            den += ex[j];
        }
        float rd = 1.0f / den;
#pragma unroll
        for (int j = 0; j < 16; ++j) sal[i * 16 + j] = ex[j] * rd;
    }
    __syncthreads();
    if (tid < 16) {
        float a = 0.0f;
#pragma unroll
        for (int i = 0; i < 16; ++i) a += sal[i * 16 + tid];
        wj[tid] = a * (1.0f / 16.0f);
    }
    __syncthreads();
    {
        int g = tid;
        float acc = 0.0f;
#pragma unroll
        for (int j = 0; j < 16; ++j) acc += wj[j] * (float)sb[j * 256 + g];
        ac_ws[b * 256 + g] = acc;
        out[(size_t)b * 259 + g] = acc;
    }
    if (tid < 2) out[(size_t)b * 259 + 256 + tid] = hideout[b * 2 + tid];
    if (tid == 0) out[(size_t)b * 259 + 258] = timestep[b];
}

// ---------------------------------------------------------------------------
// 5. CPC: one WG per t. pred/proj -> l2norm -> logits -> log-softmax diag.
// ---------------------------------------------------------------------------
__global__ __launch_bounds__(256, 1) void cpc_kernel(
    const float* __restrict__ ac,      // (128,256) f32
    const float* __restrict__ future,  // (128,12,2) f32
    const float* __restrict__ Wk,      // (12,16,256) f32
    const float* __restrict__ bk,      // (12,16) f32
    const float* __restrict__ Wl,      // (16,2) f32
    const float* __restrict__ bl,      // (16) f32
    float* __restrict__ loss_part)     // (12) f32
{
    __shared__ float pred[128][17];
    __shared__ float proj[128][17];
    __shared__ float red[4];
    const int tid = threadIdx.x, t = blockIdx.x;

    for (int ii = 0; ii < 8; ++ii) {
        int idx = tid + ii * 256;
        int b = idx >> 4, l = idx & 15;
        const float* wrow = Wk + ((size_t)t * 16 + l) * 256;
        const float* arow = ac + b * 256;
        float acc = bk[t * 16 + l];
        for (int g = 0; g < 256; g += 4) {
            float4 w = *(const float4*)(wrow + g);
            float4 a = *(const float4*)(arow + g);
            acc += w.x * a.x + w.y * a.y + w.z * a.z + w.w * a.w;
        }
        pred[b][l] = acc;
        float f0 = future[(b * 12 + t) * 2 + 0];
        float f1 = future[(b * 12 + t) * 2 + 1];
        proj[b][l] = f0 * Wl[l * 2 + 0] + f1 * Wl[l * 2 + 1] + bl[l];
    }
    __syncthreads();
    {
        float* row = (tid < 128) ? pred[tid] : proj[tid - 128];
        float ss = 0.0f;
#pragma unroll
        for (int l = 0; l < 16; ++l) ss += row[l] * row[l];
        float inv = 1.0f / fmaxf(sqrtf(ss), 1e-12f);
#pragma unroll
        for (int l = 0; l < 16; ++l) row[l] *= inv;
    }
    __syncthreads();
    float lsbb = 0.0f;
    if (tid < 128) {
        int b = tid;
        float tf[16];
#pragma unroll
        for (int l = 0; l < 16; ++l) tf[l] = proj[b][l];
        float mx = -1e30f, dbb = 0.0f;
        for (int cc = 0; cc < 128; ++cc) {
            float d = 0.0f;
#pragma unroll
            for (int l = 0; l < 16; ++l) d += tf[l] * pred[cc][l];
            mx = fmaxf(mx, d);
            if (cc == b) dbb = d;
        }
        float den = 0.0f;
        for (int cc = 0; cc < 128; ++cc) {
            float d = 0.0f;
#pragma unroll
            for (int l = 0; l < 16; ++l) d += tf[l] * pred[cc][l];
            den += __expf(d - mx);
        }
        lsbb = dbb - mx - __logf(den);
    }
#pragma unroll
    for (int o = 32; o > 0; o >>= 1) lsbb += __shfl_down(lsbb, o);
    if ((tid & 63) == 0) red[tid >> 6] = lsbb;
    __syncthreads();
    if (tid == 0) loss_part[t] = red[0] + red[1] + red[2] + red[3];
}

__global__ void final_kernel(const float* __restrict__ loss_part,
                             float* __restrict__ out)
{
    if (threadIdx.x == 0) {
        float s = 0.0f;
        for (int t = 0; t < 12; ++t) s += loss_part[t];
        out[33152] = -s / 1536.0f;
    }
}

// ---------------------------------------------------------------------------
extern "C" void kernel_launch(void* const* d_in, const int* in_sizes, int n_in,
                              void* d_out, int out_size, void* d_ws, size_t ws_size,
                              hipStream_t stream)
{
    const float* agent_obs = (const float*)d_in[0];
    const float* future    = (const float*)d_in[1];
    const float* hideout   = (const float*)d_in[2];
    const float* timestep  = (const float*)d_in[3];
    // d_in[4] = num_agents (int, ==16)
    const float* W_ih  = (const float*)d_in[5];
    const float* W_hh  = (const float*)d_in[6];
    const float* b_ih  = (const float*)d_in[7];
    const float* b_hh  = (const float*)d_in[8];
    const float* Wsrc1 = (const float*)d_in[9];
    const float* bsrc1 = (const float*)d_in[10];
    const float* Wdst1 = (const float*)d_in[11];
    const float* bdst1 = (const float*)d_in[12];
    const float* attn1 = (const float*)d_in[13];
    const float* Wsrc2 = (const float*)d_in[14];
    const float* bsrc2 = (const float*)d_in[15];
    const float* Wdst2 = (const float*)d_in[16];
    const float* bdst2 = (const float*)d_in[17];
    const float* attn2 = (const float*)d_in[18];
    const float* Wk    = (const float*)d_in[19];
    const float* bk    = (const float*)d_in[20];
    const float* Wl    = (const float*)d_in[21];
    const float* bl    = (const float*)d_in[22];
    float* out = (float*)d_out;

    char* ws = (char*)d_ws;
    const size_t KB = 1024;
    bf16*  wihb  = (bf16*)(ws);                  // 32 KB  (1024x16)
    bf16*  whh4  = (bf16*)(ws + 32 * KB);        // 512 KB (16,16,1024) slices
    bf16*  ws1b  = (bf16*)(ws + 544 * KB);       // 1 MB   (2048x256)
    bf16*  wd1b  = (bf16*)(ws + 1568 * KB);      // 1 MB
    bf16*  ws2b  = (bf16*)(ws + 2592 * KB);      // 128 KB (256x256)
    bf16*  wd2b  = (bf16*)(ws + 2720 * KB);      // 128 KB
    bf16*  hn    = (bf16*)(ws + 2848 * KB);      // 1 MB   (2048x256)
    bf16*  src1  = (bf16*)(ws + 3872 * KB);      // 8 MB   (2048x2048)
    bf16*  dst1  = (bf16*)(ws + 12064 * KB);     // 8 MB
    bf16*  r1    = (bf16*)(ws + 20256 * KB);     // 1 MB   (2048x256)
    bf16*  src2  = (bf16*)(ws + 21280 * KB);     // 1 MB
    bf16*  dst2  = (bf16*)(ws + 22304 * KB);     // 1 MB
    float* acf   = (float*)(ws + 23328 * KB);    // 128 KB (128x256 f32)
    float* lossp = (float*)(ws + 23456 * KB);    // 48 B

    cvt6<<<1424, 256, 0, stream>>>(W_ih, W_hh, Wsrc1, Wdst1, Wsrc2, Wdst2,
                                   wihb, whh4, ws1b, wd1b, ws2b, wd2b);
    lstm_kernel<<<128, 1024, 0, stream>>>(agent_obs, wihb, whh4, b_ih, b_hh, hn);
    gemm_bias<<<dim3(32, 32), 256, 0, stream>>>(hn, ws1b, bsrc1, src1, 2048, 2048);
    gemm_bias<<<dim3(32, 32), 256, 0, stream>>>(hn, wd1b, bdst1, dst1, 2048, 2048);
    gat1_kernel<<<128, 256, 0, stream>>>(src1, dst1, attn1, r1);
    gemm_bias<<<dim3(4, 32), 256, 0, stream>>>(r1, ws2b, bsrc2, src2, 2048, 256);
    gemm_bias<<<dim3(4, 32), 256, 0, stream>>>(r1, wd2b, bdst2, dst2, 2048, 256);
    gat2_kernel<<<128, 256, 0, stream>>>(src2, dst2, attn2, hideout, timestep, out, acf);
    cpc_kernel<<<12, 256, 0, stream>>>(acf, future, Wk, bk, Wl, bl, lossp);
    final_kernel<<<1, 64, 0, stream>>>(lossp, out);
}

// Round 11
// 843.918 us; speedup vs baseline: 3.1692x; 1.5420x over previous
//
#include <hip/hip_runtime.h>
#include <hip/hip_fp8.h>

// CPCGNN: LSTM(2048 x 128 steps, F=16, H=256) -> GATv2 x2 (16-node graphs) ->
// mean pool -> CPC loss. Inputs/outputs FLOAT32.
//
// Round 11: LSTM recurrent matmul in FP8 (OCP e4m3): W_hh and h stored fp8,
// mfma_f32_16x16x32_fp8_fp8, halving the per-step W stream (512->256 KB/CU)
// that rounds 2-10 proved to be at the ~29 B/cy/CU per-CU ingest roofline.
// x-path (W_ih, agent_obs) stays bf16; c stays f32 in registers.
// Stream: round-10 per-wave global_load_lds pipelines (1 KB/chunk/wave,
// 3-chunk lookahead, counted vmcnt, zero chunk barriers).

typedef __bf16 bf16;
typedef bf16 bf16x4 __attribute__((ext_vector_type(4)));
typedef bf16 bf16x8 __attribute__((ext_vector_type(8)));
typedef float f32x4 __attribute__((ext_vector_type(4)));

__device__ __forceinline__ float fast_sigmoid(float x) {
    return __builtin_amdgcn_rcpf(1.0f + __expf(-x));
}
__device__ __forceinline__ float fast_tanh(float x) {
    return 2.0f * __builtin_amdgcn_rcpf(1.0f + __expf(-2.0f * x)) - 1.0f;
}
__device__ __forceinline__ bf16x8 zero8() {
    bf16x8 z;
#pragma unroll
    for (int i = 0; i < 8; ++i) z[i] = (bf16)0.0f;
    return z;
}
__device__ __forceinline__ bf16x8 load8_bf(const float* p) {
    float4 a = *(const float4*)p;
    float4 b = *(const float4*)(p + 4);
    bf16x8 r;
    r[0] = (bf16)a.x; r[1] = (bf16)a.y; r[2] = (bf16)a.z; r[3] = (bf16)a.w;
    r[4] = (bf16)b.x; r[5] = (bf16)b.y; r[6] = (bf16)b.z; r[7] = (bf16)b.w;
    return r;
}
__device__ __forceinline__ unsigned char to_fp8(float v) {
    __hip_fp8_e4m3 q(v);
    return (unsigned char)q.__x;
}

// ---------------------------------------------------------------------------
// 0. Weight conversions. W_hh -> fp8 per-(chunk,wave) slices, lane-linear:
//    chunk ic = kc*2 + (G>>1); byte dst = ic*16384 + w*1024 + (G&1)*512
//    + (grp*16+col)*8 + (k&7). Others -> bf16 row-major.
// ---------------------------------------------------------------------------
__global__ __launch_bounds__(256, 1) void cvt6(
    const float* __restrict__ s0, const float* __restrict__ s1,
    const float* __restrict__ s2, const float* __restrict__ s3,
    const float* __restrict__ s4, const float* __restrict__ s5,
    bf16* __restrict__ d0, unsigned char* __restrict__ d1fp8,
    bf16* __restrict__ d2, bf16* __restrict__ d3, bf16* __restrict__ d4,
    bf16* __restrict__ d5)
{
    const int n0 = 16384, n1 = 262144, n2 = 524288, n3 = 524288, n4 = 65536;
    int loc = (blockIdx.x * 256 + threadIdx.x) * 4;
    if (loc >= n0 && loc < n0 + n1) {             // W_hh -> fp8
        int l = loc - n0;
        int n = l >> 8, k = l & 255;
        int G = n >> 8, w_ = (n >> 4) & 15, col = n & 15;
        int kc = k >> 5, grp = (k >> 3) & 3, k8 = k & 7;   // k8 in {0,4}
        int dst = (kc * 2 + (G >> 1)) * 16384 + w_ * 1024 + (G & 1) * 512
                  + (grp * 16 + col) * 8 + k8;
        float4 v = *(const float4*)(s1 + l);
        unsigned int pack = (unsigned int)to_fp8(v.x)
                          | ((unsigned int)to_fp8(v.y) << 8)
                          | ((unsigned int)to_fp8(v.z) << 16)
                          | ((unsigned int)to_fp8(v.w) << 24);
        *(unsigned int*)(d1fp8 + dst) = pack;
        return;
    }
    const float* s; bf16* d; int dst;
    if (loc < n0)                   { s = s0; d = d0; dst = loc; }
    else if ((loc -= n0 + n1) < n2) { s = s2; d = d2; dst = loc; }
    else if ((loc -= n2) < n3)      { s = s3; d = d3; dst = loc; }
    else if ((loc -= n3) < n4)      { s = s4; d = d4; dst = loc; }
    else                            { loc -= n4; s = s5; d = d5; dst = loc; }
    float4 v = *(const float4*)(s + loc);
    bf16x4 o;
    o[0] = (bf16)v.x; o[1] = (bf16)v.y; o[2] = (bf16)v.z; o[3] = (bf16)v.w;
    *(bf16x4*)(d + dst) = o;
}

// ---------------------------------------------------------------------------
// 1. LSTM. WG b = graph b. Wave w owns tau=w (gate-cols n = G*256+w*16+col).
//    Chunk cc = s*16+ic, (kc=ic>>1, gh=ic&1): 1 KB/wave fp8 staged via one
//    global_load_lds; own-wave vmcnt(5 @ic<3, 3 @ic>=3); lgkmcnt(0) guards
//    slot reuse; NO chunk barriers. Recurrent MFMA fp8_fp8; input MFMA bf16.
//    One lgkmcnt-only s_barrier per step for the fp8 h exchange.
// ---------------------------------------------------------------------------
__global__ __launch_bounds__(1024) void lstm_kernel(
    const float* __restrict__ agent_obs,       // (128,128,16,16) f32
    const bf16* __restrict__ W_ih,             // (1024,16) bf16
    const unsigned char* __restrict__ whh8,    // (16,16384) fp8 slices
    const float* __restrict__ b_ih,
    const float* __restrict__ b_hh,
    bf16* __restrict__ hn)                     // (2048,256) bf16
{
    __shared__ unsigned char wring[4][16][1024];   // 64 KB ring
    __shared__ unsigned char hbuf8[2][16][272];    // fp8 h, +16 pad
    const int tid  = threadIdx.x;
    const int lane = tid & 63;
    const int w    = tid >> 6;            // wave id = tau
    const int col  = lane & 15;
    const int grp  = lane >> 4;
    const int b    = blockIdx.x;

    for (int i = tid; i < 2 * 16 * 272; i += 1024) (&hbuf8[0][0][0])[i] = 0;

    float bias[4];
    bf16x8 wih[4];
#pragma unroll
    for (int G = 0; G < 4; ++G) {
        int n = G * 256 + w * 16 + col;
        bias[G] = b_ih[n] + b_hh[n];
        wih[G] = (grp < 2) ? *(const bf16x8*)&W_ih[n * 16 + grp * 8] : zero8();
    }
    f32x4 c = (f32x4){0.0f, 0.0f, 0.0f, 0.0f};
    const float* xb = agent_obs + (size_t)b * 32768;
    const unsigned char* wsrc = whh8 + w * 1024 + lane * 16;

    auto stage = [&](int cc) {
        const unsigned char* gs = wsrc + (size_t)(cc & 15) * 16384;
        unsigned char* ls = &wring[cc & 3][w][0];
        __builtin_amdgcn_global_load_lds((const void*)gs, (void*)ls, 16, 0, 0);
    };

    bf16x8 ax = (grp < 2) ? load8_bf(xb + col * 16 + grp * 8) : zero8();
    __syncthreads();                      // hbuf zeros visible
    stage(0); stage(1); stage(2);

    for (int s = 0; s < 128; ++s) {
        const int pr = s & 1, pw = pr ^ 1;
        f32x4 acc[4];
#pragma unroll
        for (int G = 0; G < 4; ++G) {
            float bs_ = bias[G];
            acc[G] = (f32x4){bs_, bs_, bs_, bs_};
        }
        long ah8 = 0;
        bf16x8 axn = zero8();
#pragma unroll
        for (int ic = 0; ic < 16; ++ic) {
            const int cc = s * 16 + ic;
            const int kc = ic >> 1, gh = ic & 1, sl = ic & 3;
            // own-wave: prior ds_reads of the slot being overwritten are done
            asm volatile("s_waitcnt lgkmcnt(0)" ::: "memory");
            stage(cc + 3);
            // age-exact counted waits (ax issued at iter 15 of prev step):
            if (ic < 3) asm volatile("s_waitcnt vmcnt(5)" ::: "memory");
            else        asm volatile("s_waitcnt vmcnt(3)" ::: "memory");
            if (gh == 0)
                ah8 = *(const long*)&hbuf8[pr][col][kc * 32 + grp * 8];
#pragma unroll
            for (int gl = 0; gl < 2; ++gl) {
                long bw = *(const long*)&wring[sl][w][gl * 512 + lane * 8];
                acc[gh * 2 + gl] = __builtin_amdgcn_mfma_f32_16x16x32_fp8_fp8(
                    ah8, bw, acc[gh * 2 + gl], 0, 0, 0);
            }
            if (ic == 15 && s < 127)      // fixed-point x prefetch (age-known)
                axn = (grp < 2) ? load8_bf(xb + (s + 1) * 256 + col * 16 + grp * 8)
                                : zero8();
        }
        // input contribution (bf16 path)
#pragma unroll
        for (int G = 0; G < 4; ++G)
            acc[G] = __builtin_amdgcn_mfma_f32_16x16x32_bf16(ax, wih[G], acc[G], 0, 0, 0);
        // gates: lane holds rows m=grp*4+r, col j=w*16+col
#pragma unroll
        for (int r = 0; r < 4; ++r) {
            float iv = fast_sigmoid(acc[0][r]);
            float fv = fast_sigmoid(acc[1][r]);
            float gv = fast_tanh(acc[2][r]);
            float ov = fast_sigmoid(acc[3][r]);
            float cn = fv * c[r] + iv * gv;
            c[r] = cn;
            float hv = ov * fast_tanh(cn);
            int m = grp * 4 + r, j = w * 16 + col;
            if (s == 127) hn[((size_t)b * 16 + m) * 256 + j] = (bf16)hv;
            else          hbuf8[pw][m][j] = to_fp8(hv);
        }
        ax = axn;
        // h exchange: drain LDS ops only — W vmcnt stream keeps flowing
        asm volatile("s_waitcnt lgkmcnt(0)" ::: "memory");
        __builtin_amdgcn_s_barrier();
    }
}

// ---------------------------------------------------------------------------
// 2. GEMM: C[M,N] = A[M,256] @ W[N,256]^T + bias. A,W,C bf16; bias f32.
// ---------------------------------------------------------------------------
__global__ __launch_bounds__(256, 1) void gemm_bias(
    const bf16* __restrict__ A, const bf16* __restrict__ W,
    const float* __restrict__ bias, bf16* __restrict__ C, int M, int N)
{
    const int tid = threadIdx.x, lane = tid & 63, wv = tid >> 6;
    const int col = lane & 15, grp = lane >> 4;
    const int n = blockIdx.x * 64 + wv * 16 + col;
    const int bm = blockIdx.y * 64;
    float bs = bias[n];
    f32x4 acc[4];
#pragma unroll
    for (int mt = 0; mt < 4; ++mt) acc[mt] = (f32x4){bs, bs, bs, bs};
#pragma unroll
    for (int kc = 0; kc < 8; ++kc) {
        bf16x8 bw = *(const bf16x8*)&W[(size_t)n * 256 + kc * 32 + grp * 8];
#pragma unroll
        for (int mt = 0; mt < 4; ++mt) {
            bf16x8 aa = *(const bf16x8*)
                &A[(size_t)(bm + mt * 16 + col) * 256 + kc * 32 + grp * 8];
            acc[mt] = __builtin_amdgcn_mfma_f32_16x16x32_bf16(aa, bw, acc[mt], 0, 0, 0);
        }
    }
#pragma unroll
    for (int mt = 0; mt < 4; ++mt)
#pragma unroll
        for (int r = 0; r < 4; ++r)
            C[(size_t)(bm + mt * 16 + grp * 4 + r) * N + n] = (bf16)acc[mt][r];
}

// ---------------------------------------------------------------------------
// 3. GATv2 layer 1: scores + edge softmax (no self) + head-mean aggregation.
// ---------------------------------------------------------------------------
__global__ __launch_bounds__(256, 1) void gat1_kernel(
    const bf16* __restrict__ src,    // (2048, 2048) = (b*16+n, h*256+f)
    const bf16* __restrict__ dst,
    const float* __restrict__ attn,  // (8,256) f32
    bf16* __restrict__ r1)           // (2048, 256)
{
    __shared__ float sal[2048];      // (i*16+j)*8+h
    const int tid = threadIdx.x, b = blockIdx.x;
    const bf16* sb = src + (size_t)b * 32768;
    const bf16* db = dst + (size_t)b * 32768;

    for (int ii = 0; ii < 8; ++ii) {
        int trip = tid + ii * 256;            // i*128 + j*8 + h
        int i = trip >> 7, j = (trip >> 3) & 15, h = trip & 7;
        const bf16* ps = sb + j * 2048 + h * 256;
        const bf16* pd = db + i * 2048 + h * 256;
        const float* pa = attn + h * 256;
        float acc = 0.0f;
        for (int f8 = 0; f8 < 32; ++f8) {
            bf16x8 vs = *(const bf16x8*)(ps + f8 * 8);
            bf16x8 vd = *(const bf16x8*)(pd + f8 * 8);
            float4 a0 = *(const float4*)(pa + f8 * 8);
            float4 a1 = *(const float4*)(pa + f8 * 8 + 4);
            float av[8] = {a0.x, a0.y, a0.z, a0.w, a1.x, a1.y, a1.z, a1.w};
#pragma unroll
            for (int e = 0; e < 8; ++e) {
                float v = (float)vs[e] + (float)vd[e];
                v = v > 0.0f ? v : 0.2f * v;
                acc += v * av[e];
            }
        }
        sal[trip] = acc;
    }
    __syncthreads();
    if (tid < 128) {                          // softmax over j != i
        int i = tid >> 3, h = tid & 7;
        float m = -1e30f;
#pragma unroll
        for (int j = 0; j < 16; ++j)
            if (j != i) m = fmaxf(m, sal[(i * 16 + j) * 8 + h]);
        float ex[16], den = 0.0f;
#pragma unroll
        for (int j = 0; j < 16; ++j) {
            ex[j] = (j == i) ? 0.0f : __expf(sal[(i * 16 + j) * 8 + h] - m);
            den += ex[j];
        }
        float rd = 1.0f / den;
#pragma unroll
        for (int j = 0; j < 16; ++j) sal[(i * 16 + j) * 8 + h] = ex[j] * rd;
    }
    __syncthreads();
    {
        int i = tid >> 4, fb = tid & 15;
        for (int it = 0; it < 16; ++it) {
            int f = fb + it * 16;
            float acc = 0.0f;
            for (int j = 0; j < 16; ++j) {
                const bf16* ps = sb + j * 2048 + f;
#pragma unroll
                for (int h = 0; h < 8; ++h)
                    acc += sal[(i * 16 + j) * 8 + h] * (float)ps[h * 256];
            }
            r1[((size_t)b * 16 + i) * 256 + f] = (bf16)(acc * 0.125f);
        }
    }
}

// ---------------------------------------------------------------------------
// 4. GATv2 layer 2 (1 head) fused with node-mean + d_out row writes.
// ---------------------------------------------------------------------------
__global__ __launch_bounds__(256, 1) void gat2_kernel(
    const bf16* __restrict__ src2,   // (2048,256)
    const bf16* __restrict__ dst2,
    const float* __restrict__ attn2, // (256) f32
    const float* __restrict__ hideout,   // (128,2) f32
    const float* __restrict__ timestep,  // (128,1) f32
    float* __restrict__ out,             // (128,259)+loss f32
    float* __restrict__ ac_ws)           // (128,256) f32
{
    __shared__ float sal[256];
    __shared__ float wj[16];
    const int tid = threadIdx.x, b = blockIdx.x;
    const bf16* sb = src2 + (size_t)b * 4096;
    const bf16* db = dst2 + (size_t)b * 4096;
    {
        int i = tid >> 4, j = tid & 15;
        const bf16* ps = sb + j * 256;
        const bf16* pd = db + i * 256;
        float acc = 0.0f;
        for (int g8 = 0; g8 < 32; ++g8) {
            bf16x8 vs = *(const bf16x8*)(ps + g8 * 8);
            bf16x8 vd = *(const bf16x8*)(pd + g8 * 8);
            float4 a0 = *(const float4*)(attn2 + g8 * 8);
            float4 a1 = *(const float4*)(attn2 + g8 * 8 + 4);
            float av[8] = {a0.x, a0.y, a0.z, a0.w, a1.x, a1.y, a1.z, a1.w};
#pragma unroll
            for (int e = 0; e < 8; ++e) {
                float v = (float)vs[e] + (float)vd[e];
                v = v > 0.0f ? v : 0.2f * v;
                acc += v * av[e];
            }
        }
        sal[tid] = acc;
    }
    __syncthreads();
    if (tid < 16) {
        int i = tid;
        float m = -1e30f;
#pragma unroll
        for (int j = 0; j < 16; ++j)
            if (j != i) m = fmaxf(m, sal[i * 16 + j]);
        float ex[16], den = 0.0f;
#pragma unroll
        for (int j = 0; j < 16; ++j) {
            ex[j] = (j == i) ? 0.0f : __expf(sal[i * 16 + j] - m);
            den += ex[j];
        }
        float rd = 1.0f / den;
#pragma unroll
        for (int j = 0; j < 16; ++j) sal[i * 16 + j] = ex[j] * rd;
    }
    __syncthreads();
    if (tid < 16) {
        float a = 0.0f;
#pragma unroll
        for (int i = 0; i < 16; ++i) a += sal[i * 16 + tid];
        wj[tid] = a * (1.0f / 16.0f);
    }
    __syncthreads();
    {
        int g = tid;
        float acc = 0.0f;
#pragma unroll
        for (int j = 0; j < 16; ++j) acc += wj[j] * (float)sb[j * 256 + g];
        ac_ws[b * 256 + g] = acc;
        out[(size_t)b * 259 + g] = acc;
    }
    if (tid < 2) out[(size_t)b * 259 + 256 + tid] = hideout[b * 2 + tid];
    if (tid == 0) out[(size_t)b * 259 + 258] = timestep[b];
}

// ---------------------------------------------------------------------------
// 5. CPC: one WG per t. pred/proj -> l2norm -> logits -> log-softmax diag.
// ---------------------------------------------------------------------------
__global__ __launch_bounds__(256, 1) void cpc_kernel(
    const float* __restrict__ ac,      // (128,256) f32
    const float* __restrict__ future,  // (128,12,2) f32
    const float* __restrict__ Wk,      // (12,16,256) f32
    const float* __restrict__ bk,      // (12,16) f32
    const float* __restrict__ Wl,      // (16,2) f32
    const float* __restrict__ bl,      // (16) f32
    float* __restrict__ loss_part)     // (12) f32
{
    __shared__ float pred[128][17];
    __shared__ float proj[128][17];
    __shared__ float red[4];
    const int tid = threadIdx.x, t = blockIdx.x;

    for (int ii = 0; ii < 8; ++ii) {
        int idx = tid + ii * 256;
        int b = idx >> 4, l = idx & 15;
        const float* wrow = Wk + ((size_t)t * 16 + l) * 256;
        const float* arow = ac + b * 256;
        float acc = bk[t * 16 + l];
        for (int g = 0; g < 256; g += 4) {
            float4 w = *(const float4*)(wrow + g);
            float4 a = *(const float4*)(arow + g);
            acc += w.x * a.x + w.y * a.y + w.z * a.z + w.w * a.w;
        }
        pred[b][l] = acc;
        float f0 = future[(b * 12 + t) * 2 + 0];
        float f1 = future[(b * 12 + t) * 2 + 1];
        proj[b][l] = f0 * Wl[l * 2 + 0] + f1 * Wl[l * 2 + 1] + bl[l];
    }
    __syncthreads();
    {
        float* row = (tid < 128) ? pred[tid] : proj[tid - 128];
        float ss = 0.0f;
#pragma unroll
        for (int l = 0; l < 16; ++l) ss += row[l] * row[l];
        float inv = 1.0f / fmaxf(sqrtf(ss), 1e-12f);
#pragma unroll
        for (int l = 0; l < 16; ++l) row[l] *= inv;
    }
    __syncthreads();
    float lsbb = 0.0f;
    if (tid < 128) {
        int b = tid;
        float tf[16];
#pragma unroll
        for (int l = 0; l < 16; ++l) tf[l] = proj[b][l];
        float mx = -1e30f, dbb = 0.0f;
        for (int cc = 0; cc < 128; ++cc) {
            float d = 0.0f;
#pragma unroll
            for (int l = 0; l < 16; ++l) d += tf[l] * pred[cc][l];
            mx = fmaxf(mx, d);
            if (cc == b) dbb = d;
        }
        float den = 0.0f;
        for (int cc = 0; cc < 128; ++cc) {
            float d = 0.0f;
#pragma unroll
            for (int l = 0; l < 16; ++l) d += tf[l] * pred[cc][l];
            den += __expf(d - mx);
        }
        lsbb = dbb - mx - __logf(den);
    }
#pragma unroll
    for (int o = 32; o > 0; o >>= 1) lsbb += __shfl_down(lsbb, o);
    if ((tid & 63) == 0) red[tid >> 6] = lsbb;
    __syncthreads();
    if (tid == 0) loss_part[t] = red[0] + red[1] + red[2] + red[3];
}

__global__ void final_kernel(const float* __restrict__ loss_part,
                             float* __restrict__ out)
{
    if (threadIdx.x == 0) {
        float s = 0.0f;
        for (int t = 0; t < 12; ++t) s += loss_part[t];
        out[33152] = -s / 1536.0f;
    }
}

// ---------------------------------------------------------------------------
extern "C" void kernel_launch(void* const* d_in, const int* in_sizes, int n_in,
                              void* d_out, int out_size, void* d_ws, size_t ws_size,
                              hipStream_t stream)
{
    const float* agent_obs = (const float*)d_in[0];
    const float* future    = (const float*)d_in[1];
    const float* hideout   = (const float*)d_in[2];
    const float* timestep  = (const float*)d_in[3];
    // d_in[4] = num_agents (int, ==16)
    const float* W_ih  = (const float*)d_in[5];
    const float* W_hh  = (const float*)d_in[6];
    const float* b_ih  = (const float*)d_in[7];
    const float* b_hh  = (const float*)d_in[8];
    const float* Wsrc1 = (const float*)d_in[9];
    const float* bsrc1 = (const float*)d_in[10];
    const float* Wdst1 = (const float*)d_in[11];
    const float* bdst1 = (const float*)d_in[12];
    const float* attn1 = (const float*)d_in[13];
    const float* Wsrc2 = (const float*)d_in[14];
    const float* bsrc2 = (const float*)d_in[15];
    const float* Wdst2 = (const float*)d_in[16];
    const float* bdst2 = (const float*)d_in[17];
    const float* attn2 = (const float*)d_in[18];
    const float* Wk    = (const float*)d_in[19];
    const float* bk    = (const float*)d_in[20];
    const float* Wl    = (const float*)d_in[21];
    const float* bl    = (const float*)d_in[22];
    float* out = (float*)d_out;

    char* ws = (char*)d_ws;
    const size_t KB = 1024;
    bf16*  wihb  = (bf16*)(ws);                  // 32 KB  (1024x16)
    unsigned char* whh8 = (unsigned char*)(ws + 32 * KB);  // 256 KB fp8
    bf16*  ws1b  = (bf16*)(ws + 544 * KB);       // 1 MB   (2048x256)
    bf16*  wd1b  = (bf16*)(ws + 1568 * KB);      // 1 MB
    bf16*  ws2b  = (bf16*)(ws + 2592 * KB);      // 128 KB (256x256)
    bf16*  wd2b  = (bf16*)(ws + 2720 * KB);      // 128 KB
    bf16*  hn    = (bf16*)(ws + 2848 * KB);      // 1 MB   (2048x256)
    bf16*  src1  = (bf16*)(ws + 3872 * KB);      // 8 MB   (2048x2048)
    bf16*  dst1  = (bf16*)(ws + 12064 * KB);     // 8 MB
    bf16*  r1    = (bf16*)(ws + 20256 * KB);     // 1 MB   (2048x256)
    bf16*  src2  = (bf16*)(ws + 21280 * KB);     // 1 MB
    bf16*  dst2  = (bf16*)(ws + 22304 * KB);     // 1 MB
    float* acf   = (float*)(ws + 23328 * KB);    // 128 KB (128x256 f32)
    float* lossp = (float*)(ws + 23456 * KB);    // 48 B

    cvt6<<<1424, 256, 0, stream>>>(W_ih, W_hh, Wsrc1, Wdst1, Wsrc2, Wdst2,
                                   wihb, whh8, ws1b, wd1b, ws2b, wd2b);
    lstm_kernel<<<128, 1024, 0, stream>>>(agent_obs, wihb, whh8, b_ih, b_hh, hn);
    gemm_bias<<<dim3(32, 32), 256, 0, stream>>>(hn, ws1b, bsrc1, src1, 2048, 2048);
    gemm_bias<<<dim3(32, 32), 256, 0, stream>>>(hn, wd1b, bdst1, dst1, 2048, 2048);
    gat1_kernel<<<128, 256, 0, stream>>>(src1, dst1, attn1, r1);
    gemm_bias<<<dim3(4, 32), 256, 0, stream>>>(r1, ws2b, bsrc2, src2, 2048, 256);
    gemm_bias<<<dim3(4, 32), 256, 0, stream>>>(r1, wd2b, bdst2, dst2, 2048, 256);
    gat2_kernel<<<128, 256, 0, stream>>>(src2, dst2, attn2, hideout, timestep, out, acf);
    cpc_kernel<<<12, 256, 0, stream>>>(acf, future, Wk, bk, Wl, bl, lossp);
    final_kernel<<<1, 64, 0, stream>>>(lossp, out);
}

// Round 12
// 782.079 us; speedup vs baseline: 3.4198x; 1.0791x over previous
//
#include <hip/hip_runtime.h>
#include <hip/hip_fp8.h>

// CPCGNN: LSTM(2048 x 128 steps, F=16, H=256) -> GATv2 x2 (16-node graphs) ->
// mean pool -> CPC loss. Inputs/outputs FLOAT32.
//
// Round 12: 3-tier W_hh residency (fp8, 16 chunks x 16 KB):
//   chunks 0-3  : VGPR-resident (16 VGPRs/lane, loaded once)
//   chunks 4-10 : LDS-resident (112 KB, staged once via global_load_lds)
//   chunks 11-15: streamed per step (80 KB) via per-wave gload_lds pipelines,
//                 2-slot ring, age-exact counted vmcnt, no chunk barriers.
// Streamed bytes/step: 256 KB (r11) -> 80 KB. The ~28.5 B/cy/CU ingest wall
// (measured r2-r11) now applies to 80 KB -> ~1.4 us/step.

typedef __bf16 bf16;
typedef bf16 bf16x4 __attribute__((ext_vector_type(4)));
typedef bf16 bf16x8 __attribute__((ext_vector_type(8)));
typedef float f32x4 __attribute__((ext_vector_type(4)));

#define MFMA8(A, B, C) __builtin_amdgcn_mfma_f32_16x16x32_fp8_fp8((A), (B), (C), 0, 0, 0)

__device__ __forceinline__ float fast_sigmoid(float x) {
    return __builtin_amdgcn_rcpf(1.0f + __expf(-x));
}
__device__ __forceinline__ float fast_tanh(float x) {
    return 2.0f * __builtin_amdgcn_rcpf(1.0f + __expf(-2.0f * x)) - 1.0f;
}
__device__ __forceinline__ bf16x8 zero8() {
    bf16x8 z;
#pragma unroll
    for (int i = 0; i < 8; ++i) z[i] = (bf16)0.0f;
    return z;
}
__device__ __forceinline__ bf16x8 load8_bf(const float* p) {
    float4 a = *(const float4*)p;
    float4 b = *(const float4*)(p + 4);
    bf16x8 r;
    r[0] = (bf16)a.x; r[1] = (bf16)a.y; r[2] = (bf16)a.z; r[3] = (bf16)a.w;
    r[4] = (bf16)b.x; r[5] = (bf16)b.y; r[6] = (bf16)b.z; r[7] = (bf16)b.w;
    return r;
}
__device__ __forceinline__ unsigned char to_fp8(float v) {
    __hip_fp8_e4m3 q(v);
    return (unsigned char)q.__x;
}

// ---------------------------------------------------------------------------
// 0. Weight conversions (unchanged from r11). W_hh -> fp8 per-(chunk,wave)
//    slices: chunk ic = kc*2+(G>>1); byte dst = ic*16384 + w*1024 + (G&1)*512
//    + lane*8 + (k&7). Others -> bf16 row-major.
// ---------------------------------------------------------------------------
__global__ __launch_bounds__(256, 1) void cvt6(
    const float* __restrict__ s0, const float* __restrict__ s1,
    const float* __restrict__ s2, const float* __restrict__ s3,
    const float* __restrict__ s4, const float* __restrict__ s5,
    bf16* __restrict__ d0, unsigned char* __restrict__ d1fp8,
    bf16* __restrict__ d2, bf16* __restrict__ d3, bf16* __restrict__ d4,
    bf16* __restrict__ d5)
{
    const int n0 = 16384, n1 = 262144, n2 = 524288, n3 = 524288, n4 = 65536;
    int loc = (blockIdx.x * 256 + threadIdx.x) * 4;
    if (loc >= n0 && loc < n0 + n1) {             // W_hh -> fp8
        int l = loc - n0;
        int n = l >> 8, k = l & 255;
        int G = n >> 8, w_ = (n >> 4) & 15, col = n & 15;
        int kc = k >> 5, grp = (k >> 3) & 3, k8 = k & 7;   // k8 in {0,4}
        int dst = (kc * 2 + (G >> 1)) * 16384 + w_ * 1024 + (G & 1) * 512
                  + (grp * 16 + col) * 8 + k8;
        float4 v = *(const float4*)(s1 + l);
        unsigned int pack = (unsigned int)to_fp8(v.x)
                          | ((unsigned int)to_fp8(v.y) << 8)
                          | ((unsigned int)to_fp8(v.z) << 16)
                          | ((unsigned int)to_fp8(v.w) << 24);
        *(unsigned int*)(d1fp8 + dst) = pack;
        return;
    }
    const float* s; bf16* d; int dst;
    if (loc < n0)                   { s = s0; d = d0; dst = loc; }
    else if ((loc -= n0 + n1) < n2) { s = s2; d = d2; dst = loc; }
    else if ((loc -= n2) < n3)      { s = s3; d = d3; dst = loc; }
    else if ((loc -= n3) < n4)      { s = s4; d = d4; dst = loc; }
    else                            { loc -= n4; s = s5; d = d5; dst = loc; }
    float4 v = *(const float4*)(s + loc);
    bf16x4 o;
    o[0] = (bf16)v.x; o[1] = (bf16)v.y; o[2] = (bf16)v.z; o[3] = (bf16)v.w;
    *(bf16x4*)(d + dst) = o;
}

// ---------------------------------------------------------------------------
// 1. LSTM. WG b = graph b, 16 waves, wave w owns tau=w. Per step:
//    A: 8 MFMA from VGPR-resident chunks (kc 0-1)
//    B: 7 LDS-res chunks (kc 2-5 first half), ds_read_b64 + MFMA
//    C: 5 streamed chunks (kc 5-7): {vmcnt(age); ds_read; 2 MFMA; lgkm0;
//       restage}. vm queue/step: [st11,st12,xa,xb,st13,st14,st15] ->
//       waits 3,3,1,1,0 (x clamped-loaded every step for uniform ages).
//    Then bf16 input MFMA, gates, fp8 h write, lgkm0 + s_barrier.
// ---------------------------------------------------------------------------
__global__ __launch_bounds__(1024)
__attribute__((amdgpu_waves_per_eu(4, 4)))
void lstm_kernel(
    const float* __restrict__ agent_obs,       // (128,128,16,16) f32
    const bf16* __restrict__ W_ih,             // (1024,16) bf16
    const unsigned char* __restrict__ whh8,    // (16,16384) fp8 chunks
    const float* __restrict__ b_ih,
    const float* __restrict__ b_hh,
    bf16* __restrict__ hn)                     // (2048,256) bf16
{
    __shared__ unsigned char wres[7][16][1024];    // 112 KB: chunks 4..10
    __shared__ unsigned char wring[2][16][1024];   // 32 KB ring: chunks 11..15
    __shared__ unsigned char hbuf8[2][16][272];    // 8.5 KB fp8 h (+16 pad)
    const int tid  = threadIdx.x;
    const int lane = tid & 63;
    const int w    = tid >> 6;            // wave id = tau
    const int col  = lane & 15;
    const int grp  = lane >> 4;
    const int b    = blockIdx.x;

    for (int i = tid; i < 2 * 16 * 272; i += 1024) (&hbuf8[0][0][0])[i] = 0;

    float bias[4];
    bf16x8 wih[4];
#pragma unroll
    for (int G = 0; G < 4; ++G) {
        int n = G * 256 + w * 16 + col;
        bias[G] = b_ih[n] + b_hh[n];
        wih[G] = (grp < 2) ? *(const bf16x8*)&W_ih[n * 16 + grp * 8] : zero8();
    }
    // VGPR-resident chunks 0..3 (2 longs each = 16 VGPRs total)
    long wvr[4][2];
#pragma unroll
    for (int ic = 0; ic < 4; ++ic)
#pragma unroll
        for (int gl = 0; gl < 2; ++gl)
            wvr[ic][gl] = *(const long*)(whh8 + ic * 16384 + w * 1024
                                         + gl * 512 + lane * 8);
    // LDS-resident chunks 4..10: one 1KB/wave gload_lds each
    const unsigned char* wsrc16 = whh8 + w * 1024 + lane * 16;
#pragma unroll
    for (int ic = 4; ic < 11; ++ic)
        __builtin_amdgcn_global_load_lds((const void*)(wsrc16 + ic * 16384),
                                         (void*)&wres[ic - 4][w][0], 16, 0, 0);
    f32x4 c = (f32x4){0.0f, 0.0f, 0.0f, 0.0f};
    const float* xb = agent_obs + (size_t)b * 32768;
    bf16x8 ax = (grp < 2) ? load8_bf(xb + col * 16 + grp * 8) : zero8();

    asm volatile("s_waitcnt vmcnt(0)" ::: "memory");   // wres + wvr + ax ready
    __syncthreads();                                    // hbuf zeros visible

    for (int s = 0; s < 128; ++s) {
        const int pr = s & 1, pw = pr ^ 1;
        const unsigned char* hb = &hbuf8[pr][0][0];
        f32x4 acc[4];
#pragma unroll
        for (int G = 0; G < 4; ++G) {
            float bs_ = bias[G];
            acc[G] = (f32x4){bs_, bs_, bs_, bs_};
        }
        // ---- A: VGPR chunks 0..3 (kc 0,1)
        long ah = *(const long*)(hb + col * 272 + 0 * 32 + grp * 8);
        acc[0] = MFMA8(ah, wvr[0][0], acc[0]);
        acc[1] = MFMA8(ah, wvr[0][1], acc[1]);
        acc[2] = MFMA8(ah, wvr[1][0], acc[2]);
        acc[3] = MFMA8(ah, wvr[1][1], acc[3]);
        ah = *(const long*)(hb + col * 272 + 1 * 32 + grp * 8);
        acc[0] = MFMA8(ah, wvr[2][0], acc[0]);
        acc[1] = MFMA8(ah, wvr[2][1], acc[1]);
        acc[2] = MFMA8(ah, wvr[3][0], acc[2]);
        acc[3] = MFMA8(ah, wvr[3][1], acc[3]);
        // ---- B: LDS-resident chunks 4..10 (kc 2..5-first-half)
#pragma unroll
        for (int ic = 4; ic < 11; ++ic) {
            const int kc = ic >> 1, gh = ic & 1;
            if (gh == 0)
                ah = *(const long*)(hb + col * 272 + kc * 32 + grp * 8);
            long bw0 = *(const long*)&wres[ic - 4][w][lane * 8];
            long bw1 = *(const long*)&wres[ic - 4][w][512 + lane * 8];
            acc[gh * 2 + 0] = MFMA8(ah, bw0, acc[gh * 2 + 0]);
            acc[gh * 2 + 1] = MFMA8(ah, bw1, acc[gh * 2 + 1]);
        }
        // ah holds kc=5 (read at ic=10)
        // ---- C: streamed chunks 11..15 (kc 5..7), 2-slot ring
        asm volatile("s_waitcnt lgkmcnt(0)" ::: "memory");  // prev-step ring reads done
        __builtin_amdgcn_global_load_lds((const void*)(wsrc16 + 11 * 16384),
                                         (void*)&wring[1][w][0], 16, 0, 0);
        __builtin_amdgcn_global_load_lds((const void*)(wsrc16 + 12 * 16384),
                                         (void*)&wring[0][w][0], 16, 0, 0);
        const int sn = (s < 127) ? s + 1 : 127;   // clamp: uniform vm ages
        bf16x8 axn = (grp < 2) ? load8_bf(xb + sn * 256 + col * 16 + grp * 8)
                               : zero8();
        // chunk 11 (kc5, gh1) slot1 — queue [11,12,xa,xb]
        asm volatile("s_waitcnt vmcnt(3)" ::: "memory");
        {
            long bw0 = *(const long*)&wring[1][w][lane * 8];
            long bw1 = *(const long*)&wring[1][w][512 + lane * 8];
            acc[2] = MFMA8(ah, bw0, acc[2]);
            acc[3] = MFMA8(ah, bw1, acc[3]);
        }
        asm volatile("s_waitcnt lgkmcnt(0)" ::: "memory");
        __builtin_amdgcn_global_load_lds((const void*)(wsrc16 + 13 * 16384),
                                         (void*)&wring[1][w][0], 16, 0, 0);
        // chunk 12 (kc6, gh0) slot0 — queue [12,xa,xb,13]
        asm volatile("s_waitcnt vmcnt(3)" ::: "memory");
        ah = *(const long*)(hb + col * 272 + 6 * 32 + grp * 8);
        {
            long bw0 = *(const long*)&wring[0][w][lane * 8];
            long bw1 = *(const long*)&wring[0][w][512 + lane * 8];
            acc[0] = MFMA8(ah, bw0, acc[0]);
            acc[1] = MFMA8(ah, bw1, acc[1]);
        }
        asm volatile("s_waitcnt lgkmcnt(0)" ::: "memory");
        __builtin_amdgcn_global_load_lds((const void*)(wsrc16 + 14 * 16384),
                                         (void*)&wring[0][w][0], 16, 0, 0);
        // chunk 13 (kc6, gh1) slot1 — queue [xa,xb,13,14]
        asm volatile("s_waitcnt vmcnt(1)" ::: "memory");
        {
            long bw0 = *(const long*)&wring[1][w][lane * 8];
            long bw1 = *(const long*)&wring[1][w][512 + lane * 8];
            acc[2] = MFMA8(ah, bw0, acc[2]);
            acc[3] = MFMA8(ah, bw1, acc[3]);
        }
        asm volatile("s_waitcnt lgkmcnt(0)" ::: "memory");
        __builtin_amdgcn_global_load_lds((const void*)(wsrc16 + 15 * 16384),
                                         (void*)&wring[1][w][0], 16, 0, 0);
        // chunk 14 (kc7, gh0) slot0 — queue [14,15]
        asm volatile("s_waitcnt vmcnt(1)" ::: "memory");
        ah = *(const long*)(hb + col * 272 + 7 * 32 + grp * 8);
        {
            long bw0 = *(const long*)&wring[0][w][lane * 8];
            long bw1 = *(const long*)&wring[0][w][512 + lane * 8];
            acc[0] = MFMA8(ah, bw0, acc[0]);
            acc[1] = MFMA8(ah, bw1, acc[1]);
        }
        // chunk 15 (kc7, gh1) slot1 — queue [15]
        asm volatile("s_waitcnt vmcnt(0)" ::: "memory");
        {
            long bw0 = *(const long*)&wring[1][w][lane * 8];
            long bw1 = *(const long*)&wring[1][w][512 + lane * 8];
            acc[2] = MFMA8(ah, bw0, acc[2]);
            acc[3] = MFMA8(ah, bw1, acc[3]);
        }
        // ---- input contribution (bf16 path)
#pragma unroll
        for (int G = 0; G < 4; ++G)
            acc[G] = __builtin_amdgcn_mfma_f32_16x16x32_bf16(ax, wih[G], acc[G], 0, 0, 0);
        // ---- gates: lane holds rows m=grp*4+r, col j=w*16+col
#pragma unroll
        for (int r = 0; r < 4; ++r) {
            float iv = fast_sigmoid(acc[0][r]);
            float fv = fast_sigmoid(acc[1][r]);
            float gv = fast_tanh(acc[2][r]);
            float ov = fast_sigmoid(acc[3][r]);
            float cn = fv * c[r] + iv * gv;
            c[r] = cn;
            float hv = ov * fast_tanh(cn);
            int m = grp * 4 + r, j = w * 16 + col;
            if (s == 127) hn[((size_t)b * 16 + m) * 256 + j] = (bf16)hv;
            else          hbuf8[pw][m][j] = to_fp8(hv);
        }
        ax = axn;
        // h exchange: drain LDS ops only — vm stream unaffected
        asm volatile("s_waitcnt lgkmcnt(0)" ::: "memory");
        __builtin_amdgcn_s_barrier();
    }
}

// ---------------------------------------------------------------------------
// 2. GEMM: C[M,N] = A[M,256] @ W[N,256]^T + bias. A,W,C bf16; bias f32.
// ---------------------------------------------------------------------------
__global__ __launch_bounds__(256, 1) void gemm_bias(
    const bf16* __restrict__ A, const bf16* __restrict__ W,
    const float* __restrict__ bias, bf16* __restrict__ C, int M, int N)
{
    const int tid = threadIdx.x, lane = tid & 63, wv = tid >> 6;
    const int col = lane & 15, grp = lane >> 4;
    const int n = blockIdx.x * 64 + wv * 16 + col;
    const int bm = blockIdx.y * 64;
    float bs = bias[n];
    f32x4 acc[4];
#pragma unroll
    for (int mt = 0; mt < 4; ++mt) acc[mt] = (f32x4){bs, bs, bs, bs};
#pragma unroll
    for (int kc = 0; kc < 8; ++kc) {
        bf16x8 bw = *(const bf16x8*)&W[(size_t)n * 256 + kc * 32 + grp * 8];
#pragma unroll
        for (int mt = 0; mt < 4; ++mt) {
            bf16x8 aa = *(const bf16x8*)
                &A[(size_t)(bm + mt * 16 + col) * 256 + kc * 32 + grp * 8];
            acc[mt] = __builtin_amdgcn_mfma_f32_16x16x32_bf16(aa, bw, acc[mt], 0, 0, 0);
        }
    }
#pragma unroll
    for (int mt = 0; mt < 4; ++mt)
#pragma unroll
        for (int r = 0; r < 4; ++r)
            C[(size_t)(bm + mt * 16 + grp * 4 + r) * N + n] = (bf16)acc[mt][r];
}

// ---------------------------------------------------------------------------
// 3. GATv2 layer 1: scores + edge softmax (no self) + head-mean aggregation.
// ---------------------------------------------------------------------------
__global__ __launch_bounds__(256, 1) void gat1_kernel(
    const bf16* __restrict__ src,    // (2048, 2048) = (b*16+n, h*256+f)
    const bf16* __restrict__ dst,
    const float* __restrict__ attn,  // (8,256) f32
    bf16* __restrict__ r1)           // (2048, 256)
{
    __shared__ float sal[2048];      // (i*16+j)*8+h
    const int tid = threadIdx.x, b = blockIdx.x;
    const bf16* sb = src + (size_t)b * 32768;
    const bf16* db = dst + (size_t)b * 32768;

    for (int ii = 0; ii < 8; ++ii) {
        int trip = tid + ii * 256;            // i*128 + j*8 + h
        int i = trip >> 7, j = (trip >> 3) & 15, h = trip & 7;
        const bf16* ps = sb + j * 2048 + h * 256;
        const bf16* pd = db + i * 2048 + h * 256;
        const float* pa = attn + h * 256;
        float acc = 0.0f;
        for (int f8 = 0; f8 < 32; ++f8) {
            bf16x8 vs = *(const bf16x8*)(ps + f8 * 8);
            bf16x8 vd = *(const bf16x8*)(pd + f8 * 8);
            float4 a0 = *(const float4*)(pa + f8 * 8);
            float4 a1 = *(const float4*)(pa + f8 * 8 + 4);
            float av[8] = {a0.x, a0.y, a0.z, a0.w, a1.x, a1.y, a1.z, a1.w};
#pragma unroll
            for (int e = 0; e < 8; ++e) {
                float v = (float)vs[e] + (float)vd[e];
                v = v > 0.0f ? v : 0.2f * v;
                acc += v * av[e];
            }
        }
        sal[trip] = acc;
    }
    __syncthreads();
    if (tid < 128) {                          // softmax over j != i
        int i = tid >> 3, h = tid & 7;
        float m = -1e30f;
#pragma unroll
        for (int j = 0; j < 16; ++j)
            if (j != i) m = fmaxf(m, sal[(i * 16 + j) * 8 + h]);
        float ex[16], den = 0.0f;
#pragma unroll
        for (int j = 0; j < 16; ++j) {
            ex[j] = (j == i) ? 0.0f : __expf(sal[(i * 16 + j) * 8 + h] - m);
            den += ex[j];
        }
        float rd = 1.0f / den;
#pragma unroll
        for (int j = 0; j < 16; ++j) sal[(i * 16 + j) * 8 + h] = ex[j] * rd;
    }
    __syncthreads();
    {
        int i = tid >> 4, fb = tid & 15;
        for (int it = 0; it < 16; ++it) {
            int f = fb + it * 16;
            float acc = 0.0f;
            for (int j = 0; j < 16; ++j) {
                const bf16* ps = sb + j * 2048 + f;
#pragma unroll
                for (int h = 0; h < 8; ++h)
                    acc += sal[(i * 16 + j) * 8 + h] * (float)ps[h * 256];
            }
            r1[((size_t)b * 16 + i) * 256 + f] = (bf16)(acc * 0.125f);
        }
    }
}

// ---------------------------------------------------------------------------
// 4. GATv2 layer 2 (1 head) fused with node-mean + d_out row writes.
// ---------------------------------------------------------------------------
__global__ __launch_bounds__(256, 1) void gat2_kernel(
    const bf16* __restrict__ src2,   // (2048,256)
    const bf16* __restrict__ dst2,
    const float* __restrict__ attn2, // (256) f32
    const float* __restrict__ hideout,   // (128,2) f32
    const float* __restrict__ timestep,  // (128,1) f32
    float* __restrict__ out,             // (128,259)+loss f32
    float* __restrict__ ac_ws)           // (128,256) f32
{
    __shared__ float sal[256];
    __shared__ float wj[16];
    const int tid = threadIdx.x, b = blockIdx.x;
    const bf16* sb = src2 + (size_t)b * 4096;
    const bf16* db = dst2 + (size_t)b * 4096;
    {
        int i = tid >> 4, j = tid & 15;
        const bf16* ps = sb + j * 256;
        const bf16* pd = db + i * 256;
        float acc = 0.0f;
        for (int g8 = 0; g8 < 32; ++g8) {
            bf16x8 vs = *(const bf16x8*)(ps + g8 * 8);
            bf16x8 vd = *(const bf16x8*)(pd + g8 * 8);
            float4 a0 = *(const float4*)(attn2 + g8 * 8);
            float4 a1 = *(const float4*)(attn2 + g8 * 8 + 4);
            float av[8] = {a0.x, a0.y, a0.z, a0.w, a1.x, a1.y, a1.z, a1.w};
#pragma unroll
            for (int e = 0; e < 8; ++e) {
                float v = (float)vs[e] + (float)vd[e];
                v = v > 0.0f ? v : 0.2f * v;
                acc += v * av[e];
            }
        }
        sal[tid] = acc;
    }
    __syncthreads();
    if (tid < 16) {
        int i = tid;
        float m = -1e30f;
#pragma unroll
        for (int j = 0; j < 16; ++j)
            if (j != i) m = fmaxf(m, sal[i * 16 + j]);
        float ex[16], den = 0.0f;
#pragma unroll
        for (int j = 0; j < 16; ++j) {
            ex[j] = (j == i) ? 0.0f : __expf(sal[i * 16 + j] - m);
            den += ex[j];
        }
        float rd = 1.0f / den;
#pragma unroll
        for (int j = 0; j < 16; ++j) sal[i * 16 + j] = ex[j] * rd;
    }
    __syncthreads();
    if (tid < 16) {
        float a = 0.0f;
#pragma unroll
        for (int i = 0; i < 16; ++i) a += sal[i * 16 + tid];
        wj[tid] = a * (1.0f / 16.0f);
    }
    __syncthreads();
    {
        int g = tid;
        float acc = 0.0f;
#pragma unroll
        for (int j = 0; j < 16; ++j) acc += wj[j] * (float)sb[j * 256 + g];
        ac_ws[b * 256 + g] = acc;
        out[(size_t)b * 259 + g] = acc;
    }
    if (tid < 2) out[(size_t)b * 259 + 256 + tid] = hideout[b * 2 + tid];
    if (tid == 0) out[(size_t)b * 259 + 258] = timestep[b];
}

// ---------------------------------------------------------------------------
// 5. CPC: one WG per t. pred/proj -> l2norm -> logits -> log-softmax diag.
// ---------------------------------------------------------------------------
__global__ __launch_bounds__(256, 1) void cpc_kernel(
    const float* __restrict__ ac,      // (128,256) f32
    const float* __restrict__ future,  // (128,12,2) f32
    const float* __restrict__ Wk,      // (12,16,256) f32
    const float* __restrict__ bk,      // (12,16) f32
    const float* __restrict__ Wl,      // (16,2) f32
    const float* __restrict__ bl,      // (16) f32
    float* __restrict__ loss_part)     // (12) f32
{
    __shared__ float pred[128][17];
    __shared__ float proj[128][17];
    __shared__ float red[4];
    const int tid = threadIdx.x, t = blockIdx.x;

    for (int ii = 0; ii < 8; ++ii) {
        int idx = tid + ii * 256;
        int b = idx >> 4, l = idx & 15;
        const float* wrow = Wk + ((size_t)t * 16 + l) * 256;
        const float* arow = ac + b * 256;
        float acc = bk[t * 16 + l];
        for (int g = 0; g < 256; g += 4) {
            float4 w = *(const float4*)(wrow + g);
            float4 a = *(const float4*)(arow + g);
            acc += w.x * a.x + w.y * a.y + w.z * a.z + w.w * a.w;
        }
        pred[b][l] = acc;
        float f0 = future[(b * 12 + t) * 2 + 0];
        float f1 = future[(b * 12 + t) * 2 + 1];
        proj[b][l] = f0 * Wl[l * 2 + 0] + f1 * Wl[l * 2 + 1] + bl[l];
    }
    __syncthreads();
    {
        float* row = (tid < 128) ? pred[tid] : proj[tid - 128];
        float ss = 0.0f;
#pragma unroll
        for (int l = 0; l < 16; ++l) ss += row[l] * row[l];
        float inv = 1.0f / fmaxf(sqrtf(ss), 1e-12f);
#pragma unroll
        for (int l = 0; l < 16; ++l) row[l] *= inv;
    }
    __syncthreads();
    float lsbb = 0.0f;
    if (tid < 128) {
        int b = tid;
        float tf[16];
#pragma unroll
        for (int l = 0; l < 16; ++l) tf[l] = proj[b][l];
        float mx = -1e30f, dbb = 0.0f;
        for (int cc = 0; cc < 128; ++cc) {
            float d = 0.0f;
#pragma unroll
            for (int l = 0; l < 16; ++l) d += tf[l] * pred[cc][l];
            mx = fmaxf(mx, d);
            if (cc == b) dbb = d;
        }
        float den = 0.0f;
        for (int cc = 0; cc < 128; ++cc) {
            float d = 0.0f;
#pragma unroll
            for (int l = 0; l < 16; ++l) d += tf[l] * pred[cc][l];
            den += __expf(d - mx);
        }
        lsbb = dbb - mx - __logf(den);
    }
#pragma unroll
    for (int o = 32; o > 0; o >>= 1) lsbb += __shfl_down(lsbb, o);
    if ((tid & 63) == 0) red[tid >> 6] = lsbb;
    __syncthreads();
    if (tid == 0) loss_part[t] = red[0] + red[1] + red[2] + red[3];
}

__global__ void final_kernel(const float* __restrict__ loss_part,
                             float* __restrict__ out)
{
    if (threadIdx.x == 0) {
        float s = 0.0f;
        for (int t = 0; t < 12; ++t) s += loss_part[t];
        out[33152] = -s / 1536.0f;
    }
}

// ---------------------------------------------------------------------------
extern "C" void kernel_launch(void* const* d_in, const int* in_sizes, int n_in,
                              void* d_out, int out_size, void* d_ws, size_t ws_size,
                              hipStream_t stream)
{
    const float* agent_obs = (const float*)d_in[0];
    const float* future    = (const float*)d_in[1];
    const float* hideout   = (const float*)d_in[2];
    const float* timestep  = (const float*)d_in[3];
    // d_in[4] = num_agents (int, ==16)
    const float* W_ih  = (const float*)d_in[5];
    const float* W_hh  = (const float*)d_in[6];
    const float* b_ih  = (const float*)d_in[7];
    const float* b_hh  = (const float*)d_in[8];
    const float* Wsrc1 = (const float*)d_in[9];
    const float* bsrc1 = (const float*)d_in[10];
    const float* Wdst1 = (const float*)d_in[11];
    const float* bdst1 = (const float*)d_in[12];
    const float* attn1 = (const float*)d_in[13];
    const float* Wsrc2 = (const float*)d_in[14];
    const float* bsrc2 = (const float*)d_in[15];
    const float* Wdst2 = (const float*)d_in[16];
    const float* bdst2 = (const float*)d_in[17];
    const float* attn2 = (const float*)d_in[18];
    const float* Wk    = (const float*)d_in[19];
    const float* bk    = (const float*)d_in[20];
    const float* Wl    = (const float*)d_in[21];
    const float* bl    = (const float*)d_in[22];
    float* out = (float*)d_out;

    char* ws = (char*)d_ws;
    const size_t KB = 1024;
    bf16*  wihb  = (bf16*)(ws);                  // 32 KB  (1024x16)
    unsigned char* whh8 = (unsigned char*)(ws + 32 * KB);  // 256 KB fp8
    bf16*  ws1b  = (bf16*)(ws + 544 * KB);       // 1 MB   (2048x256)
    bf16*  wd1b  = (bf16*)(ws + 1568 * KB);      // 1 MB
    bf16*  ws2b  = (bf16*)(ws + 2592 * KB);      // 128 KB (256x256)
    bf16*  wd2b  = (bf16*)(ws + 2720 * KB);      // 128 KB
    bf16*  hn    = (bf16*)(ws + 2848 * KB);      // 1 MB   (2048x256)
    bf16*  src1  = (bf16*)(ws + 3872 * KB);      // 8 MB   (2048x2048)
    bf16*  dst1  = (bf16*)(ws + 12064 * KB);     // 8 MB
    bf16*  r1    = (bf16*)(ws + 20256 * KB);     // 1 MB   (2048x256)
    bf16*  src2  = (bf16*)(ws + 21280 * KB);     // 1 MB
    bf16*  dst2  = (bf16*)(ws + 22304 * KB);     // 1 MB
    float* acf   = (float*)(ws + 23328 * KB);    // 128 KB (128x256 f32)
    float* lossp = (float*)(ws + 23456 * KB);    // 48 B

    cvt6<<<1424, 256, 0, stream>>>(W_ih, W_hh, Wsrc1, Wdst1, Wsrc2, Wdst2,
                                   wihb, whh8, ws1b, wd1b, ws2b, wd2b);
    lstm_kernel<<<128, 1024, 0, stream>>>(agent_obs, wihb, whh8, b_ih, b_hh, hn);
    gemm_bias<<<dim3(32, 32), 256, 0, stream>>>(hn, ws1b, bsrc1, src1, 2048, 2048);
    gemm_bias<<<dim3(32, 32), 256, 0, stream>>>(hn, wd1b, bdst1, dst1, 2048, 2048);
    gat1_kernel<<<128, 256, 0, stream>>>(src1, dst1, attn1, r1);
    gemm_bias<<<dim3(4, 32), 256, 0, stream>>>(r1, ws2b, bsrc2, src2, 2048, 256);
    gemm_bias<<<dim3(4, 32), 256, 0, stream>>>(r1, wd2b, bdst2, dst2, 2048, 256);
    gat2_kernel<<<128, 256, 0, stream>>>(src2, dst2, attn2, hideout, timestep, out, acf);
    cpc_kernel<<<12, 256, 0, stream>>>(acf, future, Wk, bk, Wl, bl, lossp);
    final_kernel<<<1, 64, 0, stream>>>(lossp, out);
}

// Round 13
// 724.312 us; speedup vs baseline: 3.6925x; 1.0798x over previous
//
#include <hip/hip_runtime.h>
#include <hip/hip_fp8.h>

// CPCGNN: LSTM(2048 x 128 steps, F=16, H=256) -> GATv2 x2 (16-node graphs) ->
// mean pool -> CPC loss. Inputs/outputs FLOAT32.
//
// Round 13: fully resident W_hh (fp8, 16 chunks x 16 KB):
//   chunks 0-11 : VGPR-resident (48 VGPRs/lane, loaded once)
//   chunks 12-15: LDS-resident (64 KB, staged once via global_load_lds)
// NO per-step W traffic, no vmcnt machinery. Per step: 8 h ds_reads,
// 32 fp8 MFMA + 4 bf16 MFMA, gates, fp8 h write, lgkm0+barrier.
// Accumulation order identical to r12 (kc ascending) -> same numerics.

typedef __bf16 bf16;
typedef bf16 bf16x4 __attribute__((ext_vector_type(4)));
typedef bf16 bf16x8 __attribute__((ext_vector_type(8)));
typedef float f32x4 __attribute__((ext_vector_type(4)));

#define MFMA8(A, B, C) __builtin_amdgcn_mfma_f32_16x16x32_fp8_fp8((A), (B), (C), 0, 0, 0)

__device__ __forceinline__ float fast_sigmoid(float x) {
    return __builtin_amdgcn_rcpf(1.0f + __expf(-x));
}
__device__ __forceinline__ float fast_tanh(float x) {
    return 2.0f * __builtin_amdgcn_rcpf(1.0f + __expf(-2.0f * x)) - 1.0f;
}
__device__ __forceinline__ bf16x8 zero8() {
    bf16x8 z;
#pragma unroll
    for (int i = 0; i < 8; ++i) z[i] = (bf16)0.0f;
    return z;
}
__device__ __forceinline__ bf16x8 load8_bf(const float* p) {
    float4 a = *(const float4*)p;
    float4 b = *(const float4*)(p + 4);
    bf16x8 r;
    r[0] = (bf16)a.x; r[1] = (bf16)a.y; r[2] = (bf16)a.z; r[3] = (bf16)a.w;
    r[4] = (bf16)b.x; r[5] = (bf16)b.y; r[6] = (bf16)b.z; r[7] = (bf16)b.w;
    return r;
}
__device__ __forceinline__ unsigned char to_fp8(float v) {
    __hip_fp8_e4m3 q(v);
    return (unsigned char)q.__x;
}

// ---------------------------------------------------------------------------
// 0. Weight conversions (unchanged from r11/r12). W_hh -> fp8 per-(chunk,wave)
//    slices: chunk ic = kc*2+(G>>1); byte dst = ic*16384 + w*1024 + (G&1)*512
//    + lane*8 + (k&7). Others -> bf16 row-major.
// ---------------------------------------------------------------------------
__global__ __launch_bounds__(256, 1) void cvt6(
    const float* __restrict__ s0, const float* __restrict__ s1,
    const float* __restrict__ s2, const float* __restrict__ s3,
    const float* __restrict__ s4, const float* __restrict__ s5,
    bf16* __restrict__ d0, unsigned char* __restrict__ d1fp8,
    bf16* __restrict__ d2, bf16* __restrict__ d3, bf16* __restrict__ d4,
    bf16* __restrict__ d5)
{
    const int n0 = 16384, n1 = 262144, n2 = 524288, n3 = 524288, n4 = 65536;
    int loc = (blockIdx.x * 256 + threadIdx.x) * 4;
    if (loc >= n0 && loc < n0 + n1) {             // W_hh -> fp8
        int l = loc - n0;
        int n = l >> 8, k = l & 255;
        int G = n >> 8, w_ = (n >> 4) & 15, col = n & 15;
        int kc = k >> 5, grp = (k >> 3) & 3, k8 = k & 7;   // k8 in {0,4}
        int dst = (kc * 2 + (G >> 1)) * 16384 + w_ * 1024 + (G & 1) * 512
                  + (grp * 16 + col) * 8 + k8;
        float4 v = *(const float4*)(s1 + l);
        unsigned int pack = (unsigned int)to_fp8(v.x)
                          | ((unsigned int)to_fp8(v.y) << 8)
                          | ((unsigned int)to_fp8(v.z) << 16)
                          | ((unsigned int)to_fp8(v.w) << 24);
        *(unsigned int*)(d1fp8 + dst) = pack;
        return;
    }
    const float* s; bf16* d; int dst;
    if (loc < n0)                   { s = s0; d = d0; dst = loc; }
    else if ((loc -= n0 + n1) < n2) { s = s2; d = d2; dst = loc; }
    else if ((loc -= n2) < n3)      { s = s3; d = d3; dst = loc; }
    else if ((loc -= n3) < n4)      { s = s4; d = d4; dst = loc; }
    else                            { loc -= n4; s = s5; d = d5; dst = loc; }
    float4 v = *(const float4*)(s + loc);
    bf16x4 o;
    o[0] = (bf16)v.x; o[1] = (bf16)v.y; o[2] = (bf16)v.z; o[3] = (bf16)v.w;
    *(bf16x4*)(d + dst) = o;
}

// ---------------------------------------------------------------------------
// 1. LSTM. WG b = graph b, 16 waves, wave w owns tau=w (gate-cols
//    n = G*256 + w*16 + col, G=0..3). W fully resident:
//    wvr[12][2] VGPR chunks (kc 0..5), wres[4] LDS chunks (kc 6..7).
//    Per step: ds_read h (8 x b64) -> 32 fp8 MFMA -> 4 bf16 input MFMA ->
//    gates -> fp8 h write -> lgkm0 + s_barrier. No global W traffic.
// ---------------------------------------------------------------------------
__global__ __launch_bounds__(1024)
__attribute__((amdgpu_waves_per_eu(4, 4)))
void lstm_kernel(
    const float* __restrict__ agent_obs,       // (128,128,16,16) f32
    const bf16* __restrict__ W_ih,             // (1024,16) bf16
    const unsigned char* __restrict__ whh8,    // (16,16384) fp8 chunks
    const float* __restrict__ b_ih,
    const float* __restrict__ b_hh,
    bf16* __restrict__ hn)                     // (2048,256) bf16
{
    __shared__ unsigned char wres[4][16][1024];    // 64 KB: chunks 12..15
    __shared__ unsigned char hbuf8[2][16][272];    // 8.5 KB fp8 h (+16 pad)
    const int tid  = threadIdx.x;
    const int lane = tid & 63;
    const int w    = tid >> 6;            // wave id = tau
    const int col  = lane & 15;
    const int grp  = lane >> 4;
    const int b    = blockIdx.x;

    for (int i = tid; i < 2 * 16 * 272; i += 1024) (&hbuf8[0][0][0])[i] = 0;

    float bias[4];
    bf16x8 wih[4];
#pragma unroll
    for (int G = 0; G < 4; ++G) {
        int n = G * 256 + w * 16 + col;
        bias[G] = b_ih[n] + b_hh[n];
        wih[G] = (grp < 2) ? *(const bf16x8*)&W_ih[n * 16 + grp * 8] : zero8();
    }
    // VGPR-resident chunks 0..11 (2 longs each = 48 VGPRs total)
    long wvr[12][2];
#pragma unroll
    for (int ic = 0; ic < 12; ++ic)
#pragma unroll
        for (int gl = 0; gl < 2; ++gl)
            wvr[ic][gl] = *(const long*)(whh8 + ic * 16384 + w * 1024
                                         + gl * 512 + lane * 8);
    // LDS-resident chunks 12..15: one 1KB/wave gload_lds each
    const unsigned char* wsrc16 = whh8 + w * 1024 + lane * 16;
#pragma unroll
    for (int ic = 12; ic < 16; ++ic)
        __builtin_amdgcn_global_load_lds((const void*)(wsrc16 + ic * 16384),
                                         (void*)&wres[ic - 12][w][0], 16, 0, 0);
    f32x4 c = (f32x4){0.0f, 0.0f, 0.0f, 0.0f};
    const float* xb = agent_obs + (size_t)b * 32768;

    asm volatile("s_waitcnt vmcnt(0)" ::: "memory");   // wres + wvr ready
    __syncthreads();                                    // hbuf zeros visible

    for (int s = 0; s < 128; ++s) {
        const int pr = s & 1, pw = pr ^ 1;
        const unsigned char* hb = &hbuf8[pr][0][0];
        // x load issued at top; consumed after 32 MFMAs (latency hidden)
        bf16x8 ax = (grp < 2) ? load8_bf(xb + s * 256 + col * 16 + grp * 8)
                              : zero8();
        f32x4 acc[4];
#pragma unroll
        for (int G = 0; G < 4; ++G) {
            float bs_ = bias[G];
            acc[G] = (f32x4){bs_, bs_, bs_, bs_};
        }
        // ---- kc 0..5 from VGPR-resident chunks
        long ah;
#pragma unroll
        for (int ic = 0; ic < 12; ++ic) {
            const int kc = ic >> 1, gh = ic & 1;
            if (gh == 0)
                ah = *(const long*)(hb + col * 272 + kc * 32 + grp * 8);
            acc[gh * 2 + 0] = MFMA8(ah, wvr[ic][0], acc[gh * 2 + 0]);
            acc[gh * 2 + 1] = MFMA8(ah, wvr[ic][1], acc[gh * 2 + 1]);
        }
        // ---- kc 6..7 from LDS-resident chunks
#pragma unroll
        for (int ic = 12; ic < 16; ++ic) {
            const int kc = ic >> 1, gh = ic & 1;
            if (gh == 0)
                ah = *(const long*)(hb + col * 272 + kc * 32 + grp * 8);
            long bw0 = *(const long*)&wres[ic - 12][w][lane * 8];
            long bw1 = *(const long*)&wres[ic - 12][w][512 + lane * 8];
            acc[gh * 2 + 0] = MFMA8(ah, bw0, acc[gh * 2 + 0]);
            acc[gh * 2 + 1] = MFMA8(ah, bw1, acc[gh * 2 + 1]);
        }
        // ---- input contribution (bf16 path)
#pragma unroll
        for (int G = 0; G < 4; ++G)
            acc[G] = __builtin_amdgcn_mfma_f32_16x16x32_bf16(ax, wih[G], acc[G], 0, 0, 0);
        // ---- gates: lane holds rows m=grp*4+r, col j=w*16+col
#pragma unroll
        for (int r = 0; r < 4; ++r) {
            float iv = fast_sigmoid(acc[0][r]);
            float fv = fast_sigmoid(acc[1][r]);
            float gv = fast_tanh(acc[2][r]);
            float ov = fast_sigmoid(acc[3][r]);
            float cn = fv * c[r] + iv * gv;
            c[r] = cn;
            float hv = ov * fast_tanh(cn);
            int m = grp * 4 + r, j = w * 16 + col;
            if (s == 127) hn[((size_t)b * 16 + m) * 256 + j] = (bf16)hv;
            else          hbuf8[pw][m][j] = to_fp8(hv);
        }
        // h exchange: drain LDS ops, then barrier
        asm volatile("s_waitcnt lgkmcnt(0)" ::: "memory");
        __builtin_amdgcn_s_barrier();
    }
}

// ---------------------------------------------------------------------------
// 2. GEMM: C[M,N] = A[M,256] @ W[N,256]^T + bias. A,W,C bf16; bias f32.
// ---------------------------------------------------------------------------
__global__ __launch_bounds__(256, 1) void gemm_bias(
    const bf16* __restrict__ A, const bf16* __restrict__ W,
    const float* __restrict__ bias, bf16* __restrict__ C, int M, int N)
{
    const int tid = threadIdx.x, lane = tid & 63, wv = tid >> 6;
    const int col = lane & 15, grp = lane >> 4;
    const int n = blockIdx.x * 64 + wv * 16 + col;
    const int bm = blockIdx.y * 64;
    float bs = bias[n];
    f32x4 acc[4];
#pragma unroll
    for (int mt = 0; mt < 4; ++mt) acc[mt] = (f32x4){bs, bs, bs, bs};
#pragma unroll
    for (int kc = 0; kc < 8; ++kc) {
        bf16x8 bw = *(const bf16x8*)&W[(size_t)n * 256 + kc * 32 + grp * 8];
#pragma unroll
        for (int mt = 0; mt < 4; ++mt) {
            bf16x8 aa = *(const bf16x8*)
                &A[(size_t)(bm + mt * 16 + col) * 256 + kc * 32 + grp * 8];
            acc[mt] = __builtin_amdgcn_mfma_f32_16x16x32_bf16(aa, bw, acc[mt], 0, 0, 0);
        }
    }
#pragma unroll
    for (int mt = 0; mt < 4; ++mt)
#pragma unroll
        for (int r = 0; r < 4; ++r)
            C[(size_t)(bm + mt * 16 + grp * 4 + r) * N + n] = (bf16)acc[mt][r];
}

// ---------------------------------------------------------------------------
// 3. GATv2 layer 1: scores + edge softmax (no self) + head-mean aggregation.
// ---------------------------------------------------------------------------
__global__ __launch_bounds__(256, 1) void gat1_kernel(
    const bf16* __restrict__ src,    // (2048, 2048) = (b*16+n, h*256+f)
    const bf16* __restrict__ dst,
    const float* __restrict__ attn,  // (8,256) f32
    bf16* __restrict__ r1)           // (2048, 256)
{
    __shared__ float sal[2048];      // (i*16+j)*8+h
    const int tid = threadIdx.x, b = blockIdx.x;
    const bf16* sb = src + (size_t)b * 32768;
    const bf16* db = dst + (size_t)b * 32768;

    for (int ii = 0; ii < 8; ++ii) {
        int trip = tid + ii * 256;            // i*128 + j*8 + h
        int i = trip >> 7, j = (trip >> 3) & 15, h = trip & 7;
        const bf16* ps = sb + j * 2048 + h * 256;
        const bf16* pd = db + i * 2048 + h * 256;
        const float* pa = attn + h * 256;
        float acc = 0.0f;
        for (int f8 = 0; f8 < 32; ++f8) {
            bf16x8 vs = *(const bf16x8*)(ps + f8 * 8);
            bf16x8 vd = *(const bf16x8*)(pd + f8 * 8);
            float4 a0 = *(const float4*)(pa + f8 * 8);
            float4 a1 = *(const float4*)(pa + f8 * 8 + 4);
            float av[8] = {a0.x, a0.y, a0.z, a0.w, a1.x, a1.y, a1.z, a1.w};
#pragma unroll
            for (int e = 0; e < 8; ++e) {
                float v = (float)vs[e] + (float)vd[e];
                v = v > 0.0f ? v : 0.2f * v;
                acc += v * av[e];
            }
        }
        sal[trip] = acc;
    }
    __syncthreads();
    if (tid < 128) {                          // softmax over j != i
        int i = tid >> 3, h = tid & 7;
        float m = -1e30f;
#pragma unroll
        for (int j = 0; j < 16; ++j)
            if (j != i) m = fmaxf(m, sal[(i * 16 + j) * 8 + h]);
        float ex[16], den = 0.0f;
#pragma unroll
        for (int j = 0; j < 16; ++j) {
            ex[j] = (j == i) ? 0.0f : __expf(sal[(i * 16 + j) * 8 + h] - m);
            den += ex[j];
        }
        float rd = 1.0f / den;
#pragma unroll
        for (int j = 0; j < 16; ++j) sal[(i * 16 + j) * 8 + h] = ex[j] * rd;
    }
    __syncthreads();
    {
        int i = tid >> 4, fb = tid & 15;
        for (int it = 0; it < 16; ++it) {
            int f = fb + it * 16;
            float acc = 0.0f;
            for (int j = 0; j < 16; ++j) {
                const bf16* ps = sb + j * 2048 + f;
#pragma unroll
                for (int h = 0; h < 8; ++h)
                    acc += sal[(i * 16 + j) * 8 + h] * (float)ps[h * 256];
            }
            r1[((size_t)b * 16 + i) * 256 + f] = (bf16)(acc * 0.125f);
        }
    }
}

// ---------------------------------------------------------------------------
// 4. GATv2 layer 2 (1 head) fused with node-mean + d_out row writes.
// ---------------------------------------------------------------------------
__global__ __launch_bounds__(256, 1) void gat2_kernel(
    const bf16* __restrict__ src2,   // (2048,256)
    const bf16* __restrict__ dst2,
    const float* __restrict__ attn2, // (256) f32
    const float* __restrict__ hideout,   // (128,2) f32
    const float* __restrict__ timestep,  // (128,1) f32
    float* __restrict__ out,             // (128,259)+loss f32
    float* __restrict__ ac_ws)           // (128,256) f32
{
    __shared__ float sal[256];
    __shared__ float wj[16];
    const int tid = threadIdx.x, b = blockIdx.x;
    const bf16* sb = src2 + (size_t)b * 4096;
    const bf16* db = dst2 + (size_t)b * 4096;
    {
        int i = tid >> 4, j = tid & 15;
        const bf16* ps = sb + j * 256;
        const bf16* pd = db + i * 256;
        float acc = 0.0f;
        for (int g8 = 0; g8 < 32; ++g8) {
            bf16x8 vs = *(const bf16x8*)(ps + g8 * 8);
            bf16x8 vd = *(const bf16x8*)(pd + g8 * 8);
            float4 a0 = *(const float4*)(attn2 + g8 * 8);
            float4 a1 = *(const float4*)(attn2 + g8 * 8 + 4);
            float av[8] = {a0.x, a0.y, a0.z, a0.w, a1.x, a1.y, a1.z, a1.w};
#pragma unroll
            for (int e = 0; e < 8; ++e) {
                float v = (float)vs[e] + (float)vd[e];
                v = v > 0.0f ? v : 0.2f * v;
                acc += v * av[e];
            }
        }
        sal[tid] = acc;
    }
    __syncthreads();
    if (tid < 16) {
        int i = tid;
        float m = -1e30f;
#pragma unroll
        for (int j = 0; j < 16; ++j)
            if (j != i) m = fmaxf(m, sal[i * 16 + j]);
        float ex[16], den = 0.0f;
#pragma unroll
        for (int j = 0; j < 16; ++j) {
            ex[j] = (j == i) ? 0.0f : __expf(sal[i * 16 + j] - m);
            den += ex[j];
        }
        float rd = 1.0f / den;
#pragma unroll
        for (int j = 0; j < 16; ++j) sal[i * 16 + j] = ex[j] * rd;
    }
    __syncthreads();
    if (tid < 16) {
        float a = 0.0f;
#pragma unroll
        for (int i = 0; i < 16; ++i) a += sal[i * 16 + tid];
        wj[tid] = a * (1.0f / 16.0f);
    }
    __syncthreads();
    {
        int g = tid;
        float acc = 0.0f;
#pragma unroll
        for (int j = 0; j < 16; ++j) acc += wj[j] * (float)sb[j * 256 + g];
        ac_ws[b * 256 + g] = acc;
        out[(size_t)b * 259 + g] = acc;
    }
    if (tid < 2) out[(size_t)b * 259 + 256 + tid] = hideout[b * 2 + tid];
    if (tid == 0) out[(size_t)b * 259 + 258] = timestep[b];
}

// ---------------------------------------------------------------------------
// 5. CPC: one WG per t. pred/proj -> l2norm -> logits -> log-softmax diag.
// ---------------------------------------------------------------------------
__global__ __launch_bounds__(256, 1) void cpc_kernel(
    const float* __restrict__ ac,      // (128,256) f32
    const float* __restrict__ future,  // (128,12,2) f32
    const float* __restrict__ Wk,      // (12,16,256) f32
    const float* __restrict__ bk,      // (12,16) f32
    const float* __restrict__ Wl,      // (16,2) f32
    const float* __restrict__ bl,      // (16) f32
    float* __restrict__ loss_part)     // (12) f32
{
    __shared__ float pred[128][17];
    __shared__ float proj[128][17];
    __shared__ float red[4];
    const int tid = threadIdx.x, t = blockIdx.x;

    for (int ii = 0; ii < 8; ++ii) {
        int idx = tid + ii * 256;
        int b = idx >> 4, l = idx & 15;
        const float* wrow = Wk + ((size_t)t * 16 + l) * 256;
        const float* arow = ac + b * 256;
        float acc = bk[t * 16 + l];
        for (int g = 0; g < 256; g += 4) {
            float4 w = *(const float4*)(wrow + g);
            float4 a = *(const float4*)(arow + g);
            acc += w.x * a.x + w.y * a.y + w.z * a.z + w.w * a.w;
        }
        pred[b][l] = acc;
        float f0 = future[(b * 12 + t) * 2 + 0];
        float f1 = future[(b * 12 + t) * 2 + 1];
        proj[b][l] = f0 * Wl[l * 2 + 0] + f1 * Wl[l * 2 + 1] + bl[l];
    }
    __syncthreads();
    {
        float* row = (tid < 128) ? pred[tid] : proj[tid - 128];
        float ss = 0.0f;
#pragma unroll
        for (int l = 0; l < 16; ++l) ss += row[l] * row[l];
        float inv = 1.0f / fmaxf(sqrtf(ss), 1e-12f);
#pragma unroll
        for (int l = 0; l < 16; ++l) row[l] *= inv;
    }
    __syncthreads();
    float lsbb = 0.0f;
    if (tid < 128) {
        int b = tid;
        float tf[16];
#pragma unroll
        for (int l = 0; l < 16; ++l) tf[l] = proj[b][l];
        float mx = -1e30f, dbb = 0.0f;
        for (int cc = 0; cc < 128; ++cc) {
            float d = 0.0f;
#pragma unroll
            for (int l = 0; l < 16; ++l) d += tf[l] * pred[cc][l];
            mx = fmaxf(mx, d);
            if (cc == b) dbb = d;
        }
        float den = 0.0f;
        for (int cc = 0; cc < 128; ++cc) {
            float d = 0.0f;
#pragma unroll
            for (int l = 0; l < 16; ++l) d += tf[l] * pred[cc][l];
            den += __expf(d - mx);
        }
        lsbb = dbb - mx - __logf(den);
    }
#pragma unroll
    for (int o = 32; o > 0; o >>= 1) lsbb += __shfl_down(lsbb, o);
    if ((tid & 63) == 0) red[tid >> 6] = lsbb;
    __syncthreads();
    if (tid == 0) loss_part[t] = red[0] + red[1] + red[2] + red[3];
}

__global__ void final_kernel(const float* __restrict__ loss_part,
                             float* __restrict__ out)
{
    if (threadIdx.x == 0) {
        float s = 0.0f;
        for (int t = 0; t < 12; ++t) s += loss_part[t];
        out[33152] = -s / 1536.0f;
    }
}

// ---------------------------------------------------------------------------
extern "C" void kernel_launch(void* const* d_in, const int* in_sizes, int n_in,
                              void* d_out, int out_size, void* d_ws, size_t ws_size,
                              hipStream_t stream)
{
    const float* agent_obs = (const float*)d_in[0];
    const float* future    = (const float*)d_in[1];
    const float* hideout   = (const float*)d_in[2];
    const float* timestep  = (const float*)d_in[3];
    // d_in[4] = num_agents (int, ==16)
    const float* W_ih  = (const float*)d_in[5];
    const float* W_hh  = (const float*)d_in[6];
    const float* b_ih  = (const float*)d_in[7];
    const float* b_hh  = (const float*)d_in[8];
    const float* Wsrc1 = (const float*)d_in[9];
    const float* bsrc1 = (const float*)d_in[10];
    const float* Wdst1 = (const float*)d_in[11];
    const float* bdst1 = (const float*)d_in[12];
    const float* attn1 = (const float*)d_in[13];
    const float* Wsrc2 = (const float*)d_in[14];
    const float* bsrc2 = (const float*)d_in[15];
    const float* Wdst2 = (const float*)d_in[16];
    const float* bdst2 = (const float*)d_in[17];
    const float* attn2 = (const float*)d_in[18];
    const float* Wk    = (const float*)d_in[19];
    const float* bk    = (const float*)d_in[20];
    const float* Wl    = (const float*)d_in[21];
    const float* bl    = (const float*)d_in[22];
    float* out = (float*)d_out;

    char* ws = (char*)d_ws;
    const size_t KB = 1024;
    bf16*  wihb  = (bf16*)(ws);                  // 32 KB  (1024x16)
    unsigned char* whh8 = (unsigned char*)(ws + 32 * KB);  // 256 KB fp8
    bf16*  ws1b  = (bf16*)(ws + 544 * KB);       // 1 MB   (2048x256)
    bf16*  wd1b  = (bf16*)(ws + 1568 * KB);      // 1 MB
    bf16*  ws2b  = (bf16*)(ws + 2592 * KB);      // 128 KB (256x256)
    bf16*  wd2b  = (bf16*)(ws + 2720 * KB);      // 128 KB
    bf16*  hn    = (bf16*)(ws + 2848 * KB);      // 1 MB   (2048x256)
    bf16*  src1  = (bf16*)(ws + 3872 * KB);      // 8 MB   (2048x2048)
    bf16*  dst1  = (bf16*)(ws + 12064 * KB);     // 8 MB
    bf16*  r1    = (bf16*)(ws + 20256 * KB);     // 1 MB   (2048x256)
    bf16*  src2  = (bf16*)(ws + 21280 * KB);     // 1 MB
    bf16*  dst2  = (bf16*)(ws + 22304 * KB);     // 1 MB
    float* acf   = (float*)(ws + 23328 * KB);    // 128 KB (128x256 f32)
    float* lossp = (float*)(ws + 23456 * KB);    // 48 B

    cvt6<<<1424, 256, 0, stream>>>(W_ih, W_hh, Wsrc1, Wdst1, Wsrc2, Wdst2,
                                   wihb, whh8, ws1b, wd1b, ws2b, wd2b);
    lstm_kernel<<<128, 1024, 0, stream>>>(agent_obs, wihb, whh8, b_ih, b_hh, hn);
    gemm_bias<<<dim3(32, 32), 256, 0, stream>>>(hn, ws1b, bsrc1, src1, 2048, 2048);
    gemm_bias<<<dim3(32, 32), 256, 0, stream>>>(hn, wd1b, bdst1, dst1, 2048, 2048);
    gat1_kernel<<<128, 256, 0, stream>>>(src1, dst1, attn1, r1);
    gemm_bias<<<dim3(4, 32), 256, 0, stream>>>(r1, ws2b, bsrc2, src2, 2048, 256);
    gemm_bias<<<dim3(4, 32), 256, 0, stream>>>(r1, wd2b, bdst2, dst2, 2048, 256);
    gat2_kernel<<<128, 256, 0, stream>>>(src2, dst2, attn2, hideout, timestep, out, acf);
    cpc_kernel<<<12, 256, 0, stream>>>(acf, future, Wk, bk, Wl, bl, lossp);
    final_kernel<<<1, 64, 0, stream>>>(lossp, out);
}

// Round 15
// 637.389 us; speedup vs baseline: 4.1961x; 1.1364x over previous
//
#include <hip/hip_runtime.h>
#include <hip/hip_fp8.h>

// CPCGNN: LSTM(2048 x 128 steps, F=16, H=256) -> GATv2 x2 (16-node graphs) ->
// mean pool -> CPC loss. Inputs/outputs FLOAT32.
//
// Round 15: round-14 design with the cvt6 pointer bug fixed (s += loc no-op
// line removed). Fragment-major GEMM operands; vectorized gat1 aggregation;
// chain-split LSTM accumulators.

typedef __bf16 bf16;
typedef bf16 bf16x4 __attribute__((ext_vector_type(4)));
typedef bf16 bf16x8 __attribute__((ext_vector_type(8)));
typedef float f32x4 __attribute__((ext_vector_type(4)));

#define MFMA8(A, B, C) __builtin_amdgcn_mfma_f32_16x16x32_fp8_fp8((A), (B), (C), 0, 0, 0)

__device__ __forceinline__ float fast_sigmoid(float x) {
    return __builtin_amdgcn_rcpf(1.0f + __expf(-x));
}
__device__ __forceinline__ float fast_tanh(float x) {
    return 2.0f * __builtin_amdgcn_rcpf(1.0f + __expf(-2.0f * x)) - 1.0f;
}
__device__ __forceinline__ bf16x8 zero8() {
    bf16x8 z;
#pragma unroll
    for (int i = 0; i < 8; ++i) z[i] = (bf16)0.0f;
    return z;
}
__device__ __forceinline__ bf16x8 load8_bf(const float* p) {
    float4 a = *(const float4*)p;
    float4 b = *(const float4*)(p + 4);
    bf16x8 r;
    r[0] = (bf16)a.x; r[1] = (bf16)a.y; r[2] = (bf16)a.z; r[3] = (bf16)a.w;
    r[4] = (bf16)b.x; r[5] = (bf16)b.y; r[6] = (bf16)b.z; r[7] = (bf16)b.w;
    return r;
}
__device__ __forceinline__ unsigned char to_fp8(float v) {
    __hip_fp8_e4m3 q(v);
    return (unsigned char)q.__x;
}

// ---------------------------------------------------------------------------
// 0. Weight conversions. W_ih -> bf16 row-major. W_hh -> fp8 per-(chunk,wave)
//    slices (r13 formula). Wsrc1/Wdst1/Wsrc2/Wdst2 -> bf16 FRAGMENT-MAJOR:
//    dst = ((n>>4)*8 + (k>>5))*512 + ((k>>3)&3)*128 + (n&15)*8 + (k&7).
// ---------------------------------------------------------------------------
__global__ __launch_bounds__(256, 1) void cvt6(
    const float* __restrict__ s0, const float* __restrict__ s1,
    const float* __restrict__ s2, const float* __restrict__ s3,
    const float* __restrict__ s4, const float* __restrict__ s5,
    bf16* __restrict__ d0, unsigned char* __restrict__ d1fp8,
    bf16* __restrict__ d2, bf16* __restrict__ d3, bf16* __restrict__ d4,
    bf16* __restrict__ d5)
{
    const int n0 = 16384, n1 = 262144, n2 = 524288, n3 = 524288, n4 = 65536;
    int loc = (blockIdx.x * 256 + threadIdx.x) * 4;
    if (loc >= n0 && loc < n0 + n1) {             // W_hh -> fp8 (r13 layout)
        int l = loc - n0;
        int n = l >> 8, k = l & 255;
        int G = n >> 8, w_ = (n >> 4) & 15, col = n & 15;
        int kc = k >> 5, grp = (k >> 3) & 3, k8 = k & 7;   // k8 in {0,4}
        int dst = (kc * 2 + (G >> 1)) * 16384 + w_ * 1024 + (G & 1) * 512
                  + (grp * 16 + col) * 8 + k8;
        float4 v = *(const float4*)(s1 + l);
        unsigned int pack = (unsigned int)to_fp8(v.x)
                          | ((unsigned int)to_fp8(v.y) << 8)
                          | ((unsigned int)to_fp8(v.z) << 16)
                          | ((unsigned int)to_fp8(v.w) << 24);
        *(unsigned int*)(d1fp8 + dst) = pack;
        return;
    }
    if (loc < n0) {                               // W_ih row-major
        float4 v = *(const float4*)(s0 + loc);
        bf16x4 o;
        o[0] = (bf16)v.x; o[1] = (bf16)v.y; o[2] = (bf16)v.z; o[3] = (bf16)v.w;
        *(bf16x4*)(d0 + loc) = o;
        return;
    }
    // GAT weights -> fragment-major
    int l = loc - n0 - n1;
    const float* s; bf16* d;
    if (l < n2)              { s = s2; d = d2; }
    else if ((l -= n2) < n3) { s = s3; d = d3; }
    else if ((l -= n3) < n4) { s = s4; d = d4; }
    else                     { l -= n4; s = s5; d = d5; }
    int n = l >> 8, k = l & 255;
    int dst = ((n >> 4) * 8 + (k >> 5)) * 512 + ((k >> 3) & 3) * 128
              + (n & 15) * 8 + (k & 7);
    float4 v = *(const float4*)(s + l);
    bf16x4 o;
    o[0] = (bf16)v.x; o[1] = (bf16)v.y; o[2] = (bf16)v.z; o[3] = (bf16)v.w;
    *(bf16x4*)(d + dst) = o;
}

// ---------------------------------------------------------------------------
// 1. LSTM (r13 structure; + chain-split accumulators, + fragment-major hn).
// ---------------------------------------------------------------------------
__global__ __launch_bounds__(1024)
__attribute__((amdgpu_waves_per_eu(4, 4)))
void lstm_kernel(
    const float* __restrict__ agent_obs,       // (128,128,16,16) f32
    const bf16* __restrict__ W_ih,             // (1024,16) bf16
    const unsigned char* __restrict__ whh8,    // (16,16384) fp8 chunks
    const float* __restrict__ b_ih,
    const float* __restrict__ b_hh,
    bf16* __restrict__ hn)                     // fragment-major (2048x256)
{
    __shared__ unsigned char wres[4][16][1024];    // 64 KB: chunks 12..15
    __shared__ unsigned char hbuf8[2][16][272];    // 8.5 KB fp8 h (+16 pad)
    const int tid  = threadIdx.x;
    const int lane = tid & 63;
    const int w    = tid >> 6;            // wave id = tau
    const int col  = lane & 15;
    const int grp  = lane >> 4;
    const int b    = blockIdx.x;

    for (int i = tid; i < 2 * 16 * 272; i += 1024) (&hbuf8[0][0][0])[i] = 0;

    float bias[4];
    bf16x8 wih[4];
#pragma unroll
    for (int G = 0; G < 4; ++G) {
        int n = G * 256 + w * 16 + col;
        bias[G] = b_ih[n] + b_hh[n];
        wih[G] = (grp < 2) ? *(const bf16x8*)&W_ih[n * 16 + grp * 8] : zero8();
    }
    // VGPR-resident chunks 0..11
    long wvr[12][2];
#pragma unroll
    for (int ic = 0; ic < 12; ++ic)
#pragma unroll
        for (int gl = 0; gl < 2; ++gl)
            wvr[ic][gl] = *(const long*)(whh8 + ic * 16384 + w * 1024
                                         + gl * 512 + lane * 8);
    // LDS-resident chunks 12..15
    const unsigned char* wsrc16 = whh8 + w * 1024 + lane * 16;
#pragma unroll
    for (int ic = 12; ic < 16; ++ic)
        __builtin_amdgcn_global_load_lds((const void*)(wsrc16 + ic * 16384),
                                         (void*)&wres[ic - 12][w][0], 16, 0, 0);
    f32x4 c = (f32x4){0.0f, 0.0f, 0.0f, 0.0f};
    const float* xb = agent_obs + (size_t)b * 32768;
    // fragment-major hn base for this lane (row-blk b, k = w*16+col):
    const int hnbase = b * 4096 + (w >> 1) * 512
                     + ((w & 1) * 2 + (col >> 3)) * 128 + (col & 7);

    asm volatile("s_waitcnt vmcnt(0)" ::: "memory");
    __syncthreads();

    for (int s = 0; s < 128; ++s) {
        const int pr = s & 1, pw = pr ^ 1;
        const unsigned char* hb = &hbuf8[pr][0][0];
        bf16x8 ax = (grp < 2) ? load8_bf(xb + s * 256 + col * 16 + grp * 8)
                              : zero8();
        f32x4 acc[4], acc2[4];
#pragma unroll
        for (int G = 0; G < 4; ++G) {
            float bs_ = bias[G];
            acc[G]  = (f32x4){bs_, bs_, bs_, bs_};
            acc2[G] = (f32x4){0.0f, 0.0f, 0.0f, 0.0f};
        }
        long ah;
        // kc 0..5 from VGPR chunks; chain split at ic=8
#pragma unroll
        for (int ic = 0; ic < 12; ++ic) {
            const int kc = ic >> 1, gh = ic & 1;
            if (gh == 0)
                ah = *(const long*)(hb + col * 272 + kc * 32 + grp * 8);
            if (ic < 8) {
                acc[gh * 2 + 0] = MFMA8(ah, wvr[ic][0], acc[gh * 2 + 0]);
                acc[gh * 2 + 1] = MFMA8(ah, wvr[ic][1], acc[gh * 2 + 1]);
            } else {
                acc2[gh * 2 + 0] = MFMA8(ah, wvr[ic][0], acc2[gh * 2 + 0]);
                acc2[gh * 2 + 1] = MFMA8(ah, wvr[ic][1], acc2[gh * 2 + 1]);
            }
        }
        // kc 6..7 from LDS chunks -> acc2
#pragma unroll
        for (int ic = 12; ic < 16; ++ic) {
            const int kc = ic >> 1, gh = ic & 1;
            if (gh == 0)
                ah = *(const long*)(hb + col * 272 + kc * 32 + grp * 8);
            long bw0 = *(const long*)&wres[ic - 12][w][lane * 8];
            long bw1 = *(const long*)&wres[ic - 12][w][512 + lane * 8];
            acc2[gh * 2 + 0] = MFMA8(ah, bw0, acc2[gh * 2 + 0]);
            acc2[gh * 2 + 1] = MFMA8(ah, bw1, acc2[gh * 2 + 1]);
        }
        // input contribution (bf16 path) into acc
#pragma unroll
        for (int G = 0; G < 4; ++G)
            acc[G] = __builtin_amdgcn_mfma_f32_16x16x32_bf16(ax, wih[G], acc[G], 0, 0, 0);
        // gates
#pragma unroll
        for (int r = 0; r < 4; ++r) {
            float iv = fast_sigmoid(acc[0][r] + acc2[0][r]);
            float fv = fast_sigmoid(acc[1][r] + acc2[1][r]);
            float gv = fast_tanh(acc[2][r] + acc2[2][r]);
            float ov = fast_sigmoid(acc[3][r] + acc2[3][r]);
            float cn = fv * c[r] + iv * gv;
            c[r] = cn;
            float hv = ov * fast_tanh(cn);
            int m = grp * 4 + r;
            if (s == 127) hn[hnbase + m * 8] = (bf16)hv;
            else          hbuf8[pw][m][w * 16 + col] = to_fp8(hv);
        }
        asm volatile("s_waitcnt lgkmcnt(0)" ::: "memory");
        __builtin_amdgcn_s_barrier();
    }
}

// ---------------------------------------------------------------------------
// 2. GEMM: C[M,N] = A @ W^T + bias. A,W FRAGMENT-MAJOR bf16 (1KB/wave loads);
//    C row-major bf16; bias f32.
// ---------------------------------------------------------------------------
__global__ __launch_bounds__(256, 1) void gemm_bias(
    const bf16* __restrict__ Af, const bf16* __restrict__ Wf,
    const float* __restrict__ bias, bf16* __restrict__ C, int N)
{
    const int tid = threadIdx.x, lane = tid & 63, wv = tid >> 6;
    const int col = lane & 15, grp = lane >> 4;
    const int n = blockIdx.x * 64 + wv * 16 + col;
    const int wt = blockIdx.x * 4 + wv;
    const int bm = blockIdx.y * 64;
    float bs = bias[n];
    f32x4 acc[4];
#pragma unroll
    for (int mt = 0; mt < 4; ++mt) acc[mt] = (f32x4){bs, bs, bs, bs};
#pragma unroll
    for (int kc = 0; kc < 8; ++kc) {
        bf16x8 bw = *(const bf16x8*)&Wf[((size_t)wt * 8 + kc) * 512 + lane * 8];
#pragma unroll
        for (int mt = 0; mt < 4; ++mt) {
            bf16x8 aa = *(const bf16x8*)
                &Af[((size_t)(blockIdx.y * 4 + mt) * 8 + kc) * 512 + lane * 8];
            acc[mt] = __builtin_amdgcn_mfma_f32_16x16x32_bf16(aa, bw, acc[mt], 0, 0, 0);
        }
    }
#pragma unroll
    for (int mt = 0; mt < 4; ++mt)
#pragma unroll
        for (int r = 0; r < 4; ++r)
            C[(size_t)(bm + mt * 16 + grp * 4 + r) * N + n] = (bf16)acc[mt][r];
}

// ---------------------------------------------------------------------------
// 3. GATv2 layer 1: scores + edge softmax + head-mean aggregation.
//    Aggregation: thread (i, fv) register-accumulates 16 f over (j,h) with
//    vector loads. r1 written FRAGMENT-MAJOR for the small gemms.
// ---------------------------------------------------------------------------
__global__ __launch_bounds__(256, 1) void gat1_kernel(
    const bf16* __restrict__ src,    // (2048, 2048) row-major
    const bf16* __restrict__ dst,
    const float* __restrict__ attn,  // (8,256) f32
    bf16* __restrict__ r1f)          // fragment-major (2048x256)
{
    __shared__ float sal[2048];      // (i*16+j)*8+h
    const int tid = threadIdx.x, b = blockIdx.x;
    const bf16* sb = src + (size_t)b * 32768;
    const bf16* db = dst + (size_t)b * 32768;

    for (int ii = 0; ii < 8; ++ii) {
        int trip = tid + ii * 256;            // i*128 + j*8 + h
        int i = trip >> 7, j = (trip >> 3) & 15, h = trip & 7;
        const bf16* ps = sb + j * 2048 + h * 256;
        const bf16* pd = db + i * 2048 + h * 256;
        const float* pa = attn + h * 256;
        float acc = 0.0f;
        for (int f8 = 0; f8 < 32; ++f8) {
            bf16x8 vs = *(const bf16x8*)(ps + f8 * 8);
            bf16x8 vd = *(const bf16x8*)(pd + f8 * 8);
            float4 a0 = *(const float4*)(pa + f8 * 8);
            float4 a1 = *(const float4*)(pa + f8 * 8 + 4);
            float av[8] = {a0.x, a0.y, a0.z, a0.w, a1.x, a1.y, a1.z, a1.w};
#pragma unroll
            for (int e = 0; e < 8; ++e) {
                float v = (float)vs[e] + (float)vd[e];
                v = v > 0.0f ? v : 0.2f * v;
                acc += v * av[e];
            }
        }
        sal[trip] = acc;
    }
    __syncthreads();
    if (tid < 128) {                          // softmax over j != i
        int i = tid >> 3, h = tid & 7;
        float m = -1e30f;
#pragma unroll
        for (int j = 0; j < 16; ++j)
            if (j != i) m = fmaxf(m, sal[(i * 16 + j) * 8 + h]);
        float ex[16], den = 0.0f;
#pragma unroll
        for (int j = 0; j < 16; ++j) {
            ex[j] = (j == i) ? 0.0f : __expf(sal[(i * 16 + j) * 8 + h] - m);
            den += ex[j];
        }
        float rd = 1.0f / den;
#pragma unroll
        for (int j = 0; j < 16; ++j) sal[(i * 16 + j) * 8 + h] = ex[j] * rd;
    }
    __syncthreads();
    {   // aggregation: i = tid>>4 (node), fv = tid&15 (16-wide f block)
        const int i = tid >> 4, fv = tid & 15;
        float acc[16];
#pragma unroll
        for (int e = 0; e < 16; ++e) acc[e] = 0.0f;
        for (int j = 0; j < 16; ++j) {
#pragma unroll
            for (int h = 0; h < 8; ++h) {
                float wgt = sal[(i * 16 + j) * 8 + h];
                const bf16* ps = sb + j * 2048 + h * 256 + fv * 16;
                bf16x8 v0 = *(const bf16x8*)(ps);
                bf16x8 v1 = *(const bf16x8*)(ps + 8);
#pragma unroll
                for (int e = 0; e < 8; ++e) {
                    acc[e]     += wgt * (float)v0[e];
                    acc[e + 8] += wgt * (float)v1[e];
                }
            }
        }
#pragma unroll
        for (int e = 0; e < 16; ++e) {
            int f = fv * 16 + e;
            int dsti = b * 4096 + (f >> 5) * 512 + ((f >> 3) & 3) * 128
                     + i * 8 + (f & 7);
            r1f[dsti] = (bf16)(acc[e] * 0.125f);
        }
    }
}

// ---------------------------------------------------------------------------
// 4. GATv2 layer 2 (1 head) fused with node-mean + d_out row writes.
// ---------------------------------------------------------------------------
__global__ __launch_bounds__(256, 1) void gat2_kernel(
    const bf16* __restrict__ src2,   // (2048,256) row-major
    const bf16* __restrict__ dst2,
    const float* __restrict__ attn2, // (256) f32
    const float* __restrict__ hideout,   // (128,2) f32
    const float* __restrict__ timestep,  // (128,1) f32
    float* __restrict__ out,             // (128,259)+loss f32
    float* __restrict__ ac_ws)           // (128,256) f32
{
    __shared__ float sal[256];
    __shared__ float wj[16];
    const int tid = threadIdx.x, b = blockIdx.x;
    const bf16* sb = src2 + (size_t)b * 4096;
    const bf16* db = dst2 + (size_t)b * 4096;
    {
        int i = tid >> 4, j = tid & 15;
        const bf16* ps = sb + j * 256;
        const bf16* pd = db + i * 256;
        float acc = 0.0f;
        for (int g8 = 0; g8 < 32; ++g8) {
            bf16x8 vs = *(const bf16x8*)(ps + g8 * 8);
            bf16x8 vd = *(const bf16x8*)(pd + g8 * 8);
            float4 a0 = *(const float4*)(attn2 + g8 * 8);
            float4 a1 = *(const float4*)(attn2 + g8 * 8 + 4);
            float av[8] = {a0.x, a0.y, a0.z, a0.w, a1.x, a1.y, a1.z, a1.w};
#pragma unroll
            for (int e = 0; e < 8; ++e) {
                float v = (float)vs[e] + (float)vd[e];
                v = v > 0.0f ? v : 0.2f * v;
                acc += v * av[e];
            }
        }
        sal[tid] = acc;
    }
    __syncthreads();
    if (tid < 16) {
        int i = tid;
        float m = -1e30f;
#pragma unroll
        for (int j = 0; j < 16; ++j)
            if (j != i) m = fmaxf(m, sal[i * 16 + j]);
        float ex[16], den = 0.0f;
#pragma unroll
        for (int j = 0; j < 16; ++j) {
            ex[j] = (j == i) ? 0.0f : __expf(sal[i * 16 + j] - m);
            den += ex[j];
        }
        float rd = 1.0f / den;
#pragma unroll
        for (int j = 0; j < 16; ++j) sal[i * 16 + j] = ex[j] * rd;
    }
    __syncthreads();
    if (tid < 16) {
        float a = 0.0f;
#pragma unroll
        for (int i = 0; i < 16; ++i) a += sal[i * 16 + tid];
        wj[tid] = a * (1.0f / 16.0f);
    }
    __syncthreads();
    {
        int g = tid;
        float acc = 0.0f;
#pragma unroll
        for (int j = 0; j < 16; ++j) acc += wj[j] * (float)sb[j * 256 + g];
        ac_ws[b * 256 + g] = acc;
        out[(size_t)b * 259 + g] = acc;
    }
    if (tid < 2) out[(size_t)b * 259 + 256 + tid] = hideout[b * 2 + tid];
    if (tid == 0) out[(size_t)b * 259 + 258] = timestep[b];
}

// ---------------------------------------------------------------------------
// 5. CPC: one WG per t. pred/proj -> l2norm -> logits -> log-softmax diag.
// ---------------------------------------------------------------------------
__global__ __launch_bounds__(256, 1) void cpc_kernel(
    const float* __restrict__ ac,      // (128,256) f32
    const float* __restrict__ future,  // (128,12,2) f32
    const float* __restrict__ Wk,      // (12,16,256) f32
    const float* __restrict__ bk,      // (12,16) f32
    const float* __restrict__ Wl,      // (16,2) f32
    const float* __restrict__ bl,      // (16) f32
    float* __restrict__ loss_part)     // (12) f32
{
    __shared__ float pred[128][17];
    __shared__ float proj[128][17];
    __shared__ float red[4];
    const int tid = threadIdx.x, t = blockIdx.x;

    for (int ii = 0; ii < 8; ++ii) {
        int idx = tid + ii * 256;
        int b = idx >> 4, l = idx & 15;
        const float* wrow = Wk + ((size_t)t * 16 + l) * 256;
        const float* arow = ac + b * 256;
        float acc = bk[t * 16 + l];
        for (int g = 0; g < 256; g += 4) {
            float4 w = *(const float4*)(wrow + g);
            float4 a = *(const float4*)(arow + g);
            acc += w.x * a.x + w.y * a.y + w.z * a.z + w.w * a.w;
        }
        pred[b][l] = acc;
        float f0 = future[(b * 12 + t) * 2 + 0];
        float f1 = future[(b * 12 + t) * 2 + 1];
        proj[b][l] = f0 * Wl[l * 2 + 0] + f1 * Wl[l * 2 + 1] + bl[l];
    }
    __syncthreads();
    {
        float* row = (tid < 128) ? pred[tid] : proj[tid - 128];
        float ss = 0.0f;
#pragma unroll
        for (int l = 0; l < 16; ++l) ss += row[l] * row[l];
        float inv = 1.0f / fmaxf(sqrtf(ss), 1e-12f);
#pragma unroll
        for (int l = 0; l < 16; ++l) row[l] *= inv;
    }
    __syncthreads();
    float lsbb = 0.0f;
    if (tid < 128) {
        int b = tid;
        float tf[16];
#pragma unroll
        for (int l = 0; l < 16; ++l) tf[l] = proj[b][l];
        float mx = -1e30f, dbb = 0.0f;
        for (int cc = 0; cc < 128; ++cc) {
            float d = 0.0f;
#pragma unroll
            for (int l = 0; l < 16; ++l) d += tf[l] * pred[cc][l];
            mx = fmaxf(mx, d);
            if (cc == b) dbb = d;
        }
        float den = 0.0f;
        for (int cc = 0; cc < 128; ++cc) {
            float d = 0.0f;
#pragma unroll
            for (int l = 0; l < 16; ++l) d += tf[l] * pred[cc][l];
            den += __expf(d - mx);
        }
        lsbb = dbb - mx - __logf(den);
    }
#pragma unroll
    for (int o = 32; o > 0; o >>= 1) lsbb += __shfl_down(lsbb, o);
    if ((tid & 63) == 0) red[tid >> 6] = lsbb;
    __syncthreads();
    if (tid == 0) loss_part[t] = red[0] + red[1] + red[2] + red[3];
}

__global__ void final_kernel(const float* __restrict__ loss_part,
                             float* __restrict__ out)
{
    if (threadIdx.x == 0) {
        float s = 0.0f;
        for (int t = 0; t < 12; ++t) s += loss_part[t];
        out[33152] = -s / 1536.0f;
    }
}

// ---------------------------------------------------------------------------
extern "C" void kernel_launch(void* const* d_in, const int* in_sizes, int n_in,
                              void* d_out, int out_size, void* d_ws, size_t ws_size,
                              hipStream_t stream)
{
    const float* agent_obs = (const float*)d_in[0];
    const float* future    = (const float*)d_in[1];
    const float* hideout   = (const float*)d_in[2];
    const float* timestep  = (const float*)d_in[3];
    // d_in[4] = num_agents (int, ==16)
    const float* W_ih  = (const float*)d_in[5];
    const float* W_hh  = (const float*)d_in[6];
    const float* b_ih  = (const float*)d_in[7];
    const float* b_hh  = (const float*)d_in[8];
    const float* Wsrc1 = (const float*)d_in[9];
    const float* bsrc1 = (const float*)d_in[10];
    const float* Wdst1 = (const float*)d_in[11];
    const float* bdst1 = (const float*)d_in[12];
    const float* attn1 = (const float*)d_in[13];
    const float* Wsrc2 = (const float*)d_in[14];
    const float* bsrc2 = (const float*)d_in[15];
    const float* Wdst2 = (const float*)d_in[16];
    const float* bdst2 = (const float*)d_in[17];
    const float* attn2 = (const float*)d_in[18];
    const float* Wk    = (const float*)d_in[19];
    const float* bk    = (const float*)d_in[20];
    const float* Wl    = (const float*)d_in[21];
    const float* bl    = (const float*)d_in[22];
    float* out = (float*)d_out;

    char* ws = (char*)d_ws;
    const size_t KB = 1024;
    bf16*  wihb  = (bf16*)(ws);                  // 32 KB  (1024x16)
    unsigned char* whh8 = (unsigned char*)(ws + 32 * KB);  // 256 KB fp8
    bf16*  ws1b  = (bf16*)(ws + 544 * KB);       // 1 MB   frag (2048x256)
    bf16*  wd1b  = (bf16*)(ws + 1568 * KB);      // 1 MB   frag
    bf16*  ws2b  = (bf16*)(ws + 2592 * KB);      // 128 KB frag (256x256)
    bf16*  wd2b  = (bf16*)(ws + 2720 * KB);      // 128 KB frag
    bf16*  hn    = (bf16*)(ws + 2848 * KB);      // 1 MB   frag (2048x256)
    bf16*  src1  = (bf16*)(ws + 3872 * KB);      // 8 MB   (2048x2048)
    bf16*  dst1  = (bf16*)(ws + 12064 * KB);     // 8 MB
    bf16*  r1f   = (bf16*)(ws + 20256 * KB);     // 1 MB   frag (2048x256)
    bf16*  src2  = (bf16*)(ws + 21280 * KB);     // 1 MB   (2048x256)
    bf16*  dst2  = (bf16*)(ws + 22304 * KB);     // 1 MB
    float* acf   = (float*)(ws + 23328 * KB);    // 128 KB (128x256 f32)
    float* lossp = (float*)(ws + 23456 * KB);    // 48 B

    cvt6<<<1424, 256, 0, stream>>>(W_ih, W_hh, Wsrc1, Wdst1, Wsrc2, Wdst2,
                                   wihb, whh8, ws1b, wd1b, ws2b, wd2b);
    lstm_kernel<<<128, 1024, 0, stream>>>(agent_obs, wihb, whh8, b_ih, b_hh, hn);
    gemm_bias<<<dim3(32, 32), 256, 0, stream>>>(hn, ws1b, bsrc1, src1, 2048);
    gemm_bias<<<dim3(32, 32), 256, 0, stream>>>(hn, wd1b, bdst1, dst1, 2048);
    gat1_kernel<<<128, 256, 0, stream>>>(src1, dst1, attn1, r1f);
    gemm_bias<<<dim3(4, 32), 256, 0, stream>>>(r1f, ws2b, bsrc2, src2, 256);
    gemm_bias<<<dim3(4, 32), 256, 0, stream>>>(r1f, wd2b, bdst2, dst2, 256);
    gat2_kernel<<<128, 256, 0, stream>>>(src2, dst2, attn2, hideout, timestep, out, acf);
    cpc_kernel<<<12, 256, 0, stream>>>(acf, future, Wk, bk, Wl, bl, lossp);
    final_kernel<<<1, 64, 0, stream>>>(lossp, out);
}

// Round 16
// 582.491 us; speedup vs baseline: 4.5915x; 1.0942x over previous
//
#include <hip/hip_runtime.h>
#include <hip/hip_fp8.h>

// CPCGNN: LSTM(2048 x 128 steps, F=16, H=256) -> GATv2 x2 (16-node graphs) ->
// mean pool -> CPC loss. Inputs/outputs FLOAT32.
//
// Round 16: r15 minus the LSTM chain-split regression (back to r13 single-acc
// body, keeping the fragment-major hn epilogue), plus FUSED gemm pairs:
// one kernel computes {src1,dst1} (shared A = hn) and one computes
// {src2,dst2} (shared A = r1f) — A fragments loaded once for both outputs.

typedef __bf16 bf16;
typedef bf16 bf16x4 __attribute__((ext_vector_type(4)));
typedef bf16 bf16x8 __attribute__((ext_vector_type(8)));
typedef float f32x4 __attribute__((ext_vector_type(4)));

#define MFMA8(A, B, C) __builtin_amdgcn_mfma_f32_16x16x32_fp8_fp8((A), (B), (C), 0, 0, 0)

__device__ __forceinline__ float fast_sigmoid(float x) {
    return __builtin_amdgcn_rcpf(1.0f + __expf(-x));
}
__device__ __forceinline__ float fast_tanh(float x) {
    return 2.0f * __builtin_amdgcn_rcpf(1.0f + __expf(-2.0f * x)) - 1.0f;
}
__device__ __forceinline__ bf16x8 zero8() {
    bf16x8 z;
#pragma unroll
    for (int i = 0; i < 8; ++i) z[i] = (bf16)0.0f;
    return z;
}
__device__ __forceinline__ bf16x8 load8_bf(const float* p) {
    float4 a = *(const float4*)p;
    float4 b = *(const float4*)(p + 4);
    bf16x8 r;
    r[0] = (bf16)a.x; r[1] = (bf16)a.y; r[2] = (bf16)a.z; r[3] = (bf16)a.w;
    r[4] = (bf16)b.x; r[5] = (bf16)b.y; r[6] = (bf16)b.z; r[7] = (bf16)b.w;
    return r;
}
__device__ __forceinline__ unsigned char to_fp8(float v) {
    __hip_fp8_e4m3 q(v);
    return (unsigned char)q.__x;
}

// ---------------------------------------------------------------------------
// 0. Weight conversions. W_ih -> bf16 row-major. W_hh -> fp8 per-(chunk,wave)
//    slices (r13 formula). Wsrc1/Wdst1/Wsrc2/Wdst2 -> bf16 FRAGMENT-MAJOR:
//    dst = ((n>>4)*8 + (k>>5))*512 + ((k>>3)&3)*128 + (n&15)*8 + (k&7).
// ---------------------------------------------------------------------------
__global__ __launch_bounds__(256, 1) void cvt6(
    const float* __restrict__ s0, const float* __restrict__ s1,
    const float* __restrict__ s2, const float* __restrict__ s3,
    const float* __restrict__ s4, const float* __restrict__ s5,
    bf16* __restrict__ d0, unsigned char* __restrict__ d1fp8,
    bf16* __restrict__ d2, bf16* __restrict__ d3, bf16* __restrict__ d4,
    bf16* __restrict__ d5)
{
    const int n0 = 16384, n1 = 262144, n2 = 524288, n3 = 524288, n4 = 65536;
    int loc = (blockIdx.x * 256 + threadIdx.x) * 4;
    if (loc >= n0 && loc < n0 + n1) {             // W_hh -> fp8 (r13 layout)
        int l = loc - n0;
        int n = l >> 8, k = l & 255;
        int G = n >> 8, w_ = (n >> 4) & 15, col = n & 15;
        int kc = k >> 5, grp = (k >> 3) & 3, k8 = k & 7;   // k8 in {0,4}
        int dst = (kc * 2 + (G >> 1)) * 16384 + w_ * 1024 + (G & 1) * 512
                  + (grp * 16 + col) * 8 + k8;
        float4 v = *(const float4*)(s1 + l);
        unsigned int pack = (unsigned int)to_fp8(v.x)
                          | ((unsigned int)to_fp8(v.y) << 8)
                          | ((unsigned int)to_fp8(v.z) << 16)
                          | ((unsigned int)to_fp8(v.w) << 24);
        *(unsigned int*)(d1fp8 + dst) = pack;
        return;
    }
    if (loc < n0) {                               // W_ih row-major
        float4 v = *(const float4*)(s0 + loc);
        bf16x4 o;
        o[0] = (bf16)v.x; o[1] = (bf16)v.y; o[2] = (bf16)v.z; o[3] = (bf16)v.w;
        *(bf16x4*)(d0 + loc) = o;
        return;
    }
    // GAT weights -> fragment-major
    int l = loc - n0 - n1;
    const float* s; bf16* d;
    if (l < n2)              { s = s2; d = d2; }
    else if ((l -= n2) < n3) { s = s3; d = d3; }
    else if ((l -= n3) < n4) { s = s4; d = d4; }
    else                     { l -= n4; s = s5; d = d5; }
    int n = l >> 8, k = l & 255;
    int dst = ((n >> 4) * 8 + (k >> 5)) * 512 + ((k >> 3) & 3) * 128
              + (n & 15) * 8 + (k & 7);
    float4 v = *(const float4*)(s + l);
    bf16x4 o;
    o[0] = (bf16)v.x; o[1] = (bf16)v.y; o[2] = (bf16)v.z; o[3] = (bf16)v.w;
    *(bf16x4*)(d + dst) = o;
}

// ---------------------------------------------------------------------------
// 1. LSTM (r13 single-acc body + fragment-major hn epilogue).
// ---------------------------------------------------------------------------
__global__ __launch_bounds__(1024)
__attribute__((amdgpu_waves_per_eu(4, 4)))
void lstm_kernel(
    const float* __restrict__ agent_obs,       // (128,128,16,16) f32
    const bf16* __restrict__ W_ih,             // (1024,16) bf16
    const unsigned char* __restrict__ whh8,    // (16,16384) fp8 chunks
    const float* __restrict__ b_ih,
    const float* __restrict__ b_hh,
    bf16* __restrict__ hn)                     // fragment-major (2048x256)
{
    __shared__ unsigned char wres[4][16][1024];    // 64 KB: chunks 12..15
    __shared__ unsigned char hbuf8[2][16][272];    // 8.5 KB fp8 h (+16 pad)
    const int tid  = threadIdx.x;
    const int lane = tid & 63;
    const int w    = tid >> 6;            // wave id = tau
    const int col  = lane & 15;
    const int grp  = lane >> 4;
    const int b    = blockIdx.x;

    for (int i = tid; i < 2 * 16 * 272; i += 1024) (&hbuf8[0][0][0])[i] = 0;

    float bias[4];
    bf16x8 wih[4];
#pragma unroll
    for (int G = 0; G < 4; ++G) {
        int n = G * 256 + w * 16 + col;
        bias[G] = b_ih[n] + b_hh[n];
        wih[G] = (grp < 2) ? *(const bf16x8*)&W_ih[n * 16 + grp * 8] : zero8();
    }
    // VGPR-resident chunks 0..11
    long wvr[12][2];
#pragma unroll
    for (int ic = 0; ic < 12; ++ic)
#pragma unroll
        for (int gl = 0; gl < 2; ++gl)
            wvr[ic][gl] = *(const long*)(whh8 + ic * 16384 + w * 1024
                                         + gl * 512 + lane * 8);
    // LDS-resident chunks 12..15
    const unsigned char* wsrc16 = whh8 + w * 1024 + lane * 16;
#pragma unroll
    for (int ic = 12; ic < 16; ++ic)
        __builtin_amdgcn_global_load_lds((const void*)(wsrc16 + ic * 16384),
                                         (void*)&wres[ic - 12][w][0], 16, 0, 0);
    f32x4 c = (f32x4){0.0f, 0.0f, 0.0f, 0.0f};
    const float* xb = agent_obs + (size_t)b * 32768;
    // fragment-major hn base (row = b*16+m, k = w*16+col)
    const int hnbase = b * 4096 + (w >> 1) * 512
                     + ((w & 1) * 2 + (col >> 3)) * 128 + (col & 7);

    asm volatile("s_waitcnt vmcnt(0)" ::: "memory");
    __syncthreads();

    for (int s = 0; s < 128; ++s) {
        const int pr = s & 1, pw = pr ^ 1;
        const unsigned char* hb = &hbuf8[pr][0][0];
        bf16x8 ax = (grp < 2) ? load8_bf(xb + s * 256 + col * 16 + grp * 8)
                              : zero8();
        f32x4 acc[4];
#pragma unroll
        for (int G = 0; G < 4; ++G) {
            float bs_ = bias[G];
            acc[G] = (f32x4){bs_, bs_, bs_, bs_};
        }
        long ah;
        // kc 0..5 from VGPR-resident chunks
#pragma unroll
        for (int ic = 0; ic < 12; ++ic) {
            const int kc = ic >> 1, gh = ic & 1;
            if (gh == 0)
                ah = *(const long*)(hb + col * 272 + kc * 32 + grp * 8);
            acc[gh * 2 + 0] = MFMA8(ah, wvr[ic][0], acc[gh * 2 + 0]);
            acc[gh * 2 + 1] = MFMA8(ah, wvr[ic][1], acc[gh * 2 + 1]);
        }
        // kc 6..7 from LDS-resident chunks
#pragma unroll
        for (int ic = 12; ic < 16; ++ic) {
            const int kc = ic >> 1, gh = ic & 1;
            if (gh == 0)
                ah = *(const long*)(hb + col * 272 + kc * 32 + grp * 8);
            long bw0 = *(const long*)&wres[ic - 12][w][lane * 8];
            long bw1 = *(const long*)&wres[ic - 12][w][512 + lane * 8];
            acc[gh * 2 + 0] = MFMA8(ah, bw0, acc[gh * 2 + 0]);
            acc[gh * 2 + 1] = MFMA8(ah, bw1, acc[gh * 2 + 1]);
        }
        // input contribution (bf16 path)
#pragma unroll
        for (int G = 0; G < 4; ++G)
            acc[G] = __builtin_amdgcn_mfma_f32_16x16x32_bf16(ax, wih[G], acc[G], 0, 0, 0);
        // gates: lane holds rows m=grp*4+r, col j=w*16+col
#pragma unroll
        for (int r = 0; r < 4; ++r) {
            float iv = fast_sigmoid(acc[0][r]);
            float fv = fast_sigmoid(acc[1][r]);
            float gv = fast_tanh(acc[2][r]);
            float ov = fast_sigmoid(acc[3][r]);
            float cn = fv * c[r] + iv * gv;
            c[r] = cn;
            float hv = ov * fast_tanh(cn);
            int m = grp * 4 + r;
            if (s == 127) hn[hnbase + m * 8] = (bf16)hv;
            else          hbuf8[pw][m][w * 16 + col] = to_fp8(hv);
        }
        asm volatile("s_waitcnt lgkmcnt(0)" ::: "memory");
        __builtin_amdgcn_s_barrier();
    }
}

// ---------------------------------------------------------------------------
// 2. FUSED dual GEMM: C1 = A@W1^T+b1, C2 = A@W2^T+b2. A,W fragment-major;
//    A fragments loaded ONCE for both outputs. C row-major bf16.
// ---------------------------------------------------------------------------
__global__ __launch_bounds__(256, 1) void gemm_bias2(
    const bf16* __restrict__ Af,
    const bf16* __restrict__ Wf1, const bf16* __restrict__ Wf2,
    const float* __restrict__ bias1, const float* __restrict__ bias2,
    bf16* __restrict__ C1, bf16* __restrict__ C2, int N)
{
    const int tid = threadIdx.x, lane = tid & 63, wv = tid >> 6;
    const int col = lane & 15, grp = lane >> 4;
    const int n = blockIdx.x * 64 + wv * 16 + col;
    const int wt = blockIdx.x * 4 + wv;
    const int bm = blockIdx.y * 64;
    float bs1 = bias1[n], bs2 = bias2[n];
    f32x4 acc1[4], acc2[4];
#pragma unroll
    for (int mt = 0; mt < 4; ++mt) {
        acc1[mt] = (f32x4){bs1, bs1, bs1, bs1};
        acc2[mt] = (f32x4){bs2, bs2, bs2, bs2};
    }
#pragma unroll
    for (int kc = 0; kc < 8; ++kc) {
        bf16x8 bw1 = *(const bf16x8*)&Wf1[((size_t)wt * 8 + kc) * 512 + lane * 8];
        bf16x8 bw2 = *(const bf16x8*)&Wf2[((size_t)wt * 8 + kc) * 512 + lane * 8];
#pragma unroll
        for (int mt = 0; mt < 4; ++mt) {
            bf16x8 aa = *(const bf16x8*)
                &Af[((size_t)(blockIdx.y * 4 + mt) * 8 + kc) * 512 + lane * 8];
            acc1[mt] = __builtin_amdgcn_mfma_f32_16x16x32_bf16(aa, bw1, acc1[mt], 0, 0, 0);
            acc2[mt] = __builtin_amdgcn_mfma_f32_16x16x32_bf16(aa, bw2, acc2[mt], 0, 0, 0);
        }
    }
#pragma unroll
    for (int mt = 0; mt < 4; ++mt)
#pragma unroll
        for (int r = 0; r < 4; ++r) {
            size_t idx = (size_t)(bm + mt * 16 + grp * 4 + r) * N + n;
            C1[idx] = (bf16)acc1[mt][r];
            C2[idx] = (bf16)acc2[mt][r];
        }
}

// ---------------------------------------------------------------------------
// 3. GATv2 layer 1: scores + edge softmax + head-mean aggregation (r15).
// ---------------------------------------------------------------------------
__global__ __launch_bounds__(256, 1) void gat1_kernel(
    const bf16* __restrict__ src,    // (2048, 2048) row-major
    const bf16* __restrict__ dst,
    const float* __restrict__ attn,  // (8,256) f32
    bf16* __restrict__ r1f)          // fragment-major (2048x256)
{
    __shared__ float sal[2048];      // (i*16+j)*8+h
    const int tid = threadIdx.x, b = blockIdx.x;
    const bf16* sb = src + (size_t)b * 32768;
    const bf16* db = dst + (size_t)b * 32768;

    for (int ii = 0; ii < 8; ++ii) {
        int trip = tid + ii * 256;            // i*128 + j*8 + h
        int i = trip >> 7, j = (trip >> 3) & 15, h = trip & 7;
        const bf16* ps = sb + j * 2048 + h * 256;
        const bf16* pd = db + i * 2048 + h * 256;
        const float* pa = attn + h * 256;
        float acc = 0.0f;
        for (int f8 = 0; f8 < 32; ++f8) {
            bf16x8 vs = *(const bf16x8*)(ps + f8 * 8);
            bf16x8 vd = *(const bf16x8*)(pd + f8 * 8);
            float4 a0 = *(const float4*)(pa + f8 * 8);
            float4 a1 = *(const float4*)(pa + f8 * 8 + 4);
            float av[8] = {a0.x, a0.y, a0.z, a0.w, a1.x, a1.y, a1.z, a1.w};
#pragma unroll
            for (int e = 0; e < 8; ++e) {
                float v = (float)vs[e] + (float)vd[e];
                v = v > 0.0f ? v : 0.2f * v;
                acc += v * av[e];
            }
        }
        sal[trip] = acc;
    }
    __syncthreads();
    if (tid < 128) {                          // softmax over j != i
        int i = tid >> 3, h = tid & 7;
        float m = -1e30f;
#pragma unroll
        for (int j = 0; j < 16; ++j)
            if (j != i) m = fmaxf(m, sal[(i * 16 + j) * 8 + h]);
        float ex[16], den = 0.0f;
#pragma unroll
        for (int j = 0; j < 16; ++j) {
            ex[j] = (j == i) ? 0.0f : __expf(sal[(i * 16 + j) * 8 + h] - m);
            den += ex[j];
        }
        float rd = 1.0f / den;
#pragma unroll
        for (int j = 0; j < 16; ++j) sal[(i * 16 + j) * 8 + h] = ex[j] * rd;
    }
    __syncthreads();
    {   // aggregation: i = tid>>4 (node), fv = tid&15 (16-wide f block)
        const int i = tid >> 4, fv = tid & 15;
        float acc[16];
#pragma unroll
        for (int e = 0; e < 16; ++e) acc[e] = 0.0f;
        for (int j = 0; j < 16; ++j) {
#pragma unroll
            for (int h = 0; h < 8; ++h) {
                float wgt = sal[(i * 16 + j) * 8 + h];
                const bf16* ps = sb + j * 2048 + h * 256 + fv * 16;
                bf16x8 v0 = *(const bf16x8*)(ps);
                bf16x8 v1 = *(const bf16x8*)(ps + 8);
#pragma unroll
                for (int e = 0; e < 8; ++e) {
                    acc[e]     += wgt * (float)v0[e];
                    acc[e + 8] += wgt * (float)v1[e];
                }
            }
        }
#pragma unroll
        for (int e = 0; e < 16; ++e) {
            int f = fv * 16 + e;
            int dsti = b * 4096 + (f >> 5) * 512 + ((f >> 3) & 3) * 128
                     + i * 8 + (f & 7);
            r1f[dsti] = (bf16)(acc[e] * 0.125f);
        }
    }
}

// ---------------------------------------------------------------------------
// 4. GATv2 layer 2 (1 head) fused with node-mean + d_out row writes.
// ---------------------------------------------------------------------------
__global__ __launch_bounds__(256, 1) void gat2_kernel(
    const bf16* __restrict__ src2,   // (2048,256) row-major
    const bf16* __restrict__ dst2,
    const float* __restrict__ attn2, // (256) f32
    const float* __restrict__ hideout,   // (128,2) f32
    const float* __restrict__ timestep,  // (128,1) f32
    float* __restrict__ out,             // (128,259)+loss f32
    float* __restrict__ ac_ws)           // (128,256) f32
{
    __shared__ float sal[256];
    __shared__ float wj[16];
    const int tid = threadIdx.x, b = blockIdx.x;
    const bf16* sb = src2 + (size_t)b * 4096;
    const bf16* db = dst2 + (size_t)b * 4096;
    {
        int i = tid >> 4, j = tid & 15;
        const bf16* ps = sb + j * 256;
        const bf16* pd = db + i * 256;
        float acc = 0.0f;
        for (int g8 = 0; g8 < 32; ++g8) {
            bf16x8 vs = *(const bf16x8*)(ps + g8 * 8);
            bf16x8 vd = *(const bf16x8*)(pd + g8 * 8);
            float4 a0 = *(const float4*)(attn2 + g8 * 8);
            float4 a1 = *(const float4*)(attn2 + g8 * 8 + 4);
            float av[8] = {a0.x, a0.y, a0.z, a0.w, a1.x, a1.y, a1.z, a1.w};
#pragma unroll
            for (int e = 0; e < 8; ++e) {
                float v = (float)vs[e] + (float)vd[e];
                v = v > 0.0f ? v : 0.2f * v;
                acc += v * av[e];
            }
        }
        sal[tid] = acc;
    }
    __syncthreads();
    if (tid < 16) {
        int i = tid;
        float m = -1e30f;
#pragma unroll
        for (int j = 0; j < 16; ++j)
            if (j != i) m = fmaxf(m, sal[i * 16 + j]);
        float ex[16], den = 0.0f;
#pragma unroll
        for (int j = 0; j < 16; ++j) {
            ex[j] = (j == i) ? 0.0f : __expf(sal[i * 16 + j] - m);
            den += ex[j];
        }
        float rd = 1.0f / den;
#pragma unroll
        for (int j = 0; j < 16; ++j) sal[i * 16 + j] = ex[j] * rd;
    }
    __syncthreads();
    if (tid < 16) {
        float a = 0.0f;
#pragma unroll
        for (int i = 0; i < 16; ++i) a += sal[i * 16 + tid];
        wj[tid] = a * (1.0f / 16.0f);
    }
    __syncthreads();
    {
        int g = tid;
        float acc = 0.0f;
#pragma unroll
        for (int j = 0; j < 16; ++j) acc += wj[j] * (float)sb[j * 256 + g];
        ac_ws[b * 256 + g] = acc;
        out[(size_t)b * 259 + g] = acc;
    }
    if (tid < 2) out[(size_t)b * 259 + 256 + tid] = hideout[b * 2 + tid];
    if (tid == 0) out[(size_t)b * 259 + 258] = timestep[b];
}

// ---------------------------------------------------------------------------
// 5. CPC: one WG per t. pred/proj -> l2norm -> logits -> log-softmax diag.
// ---------------------------------------------------------------------------
__global__ __launch_bounds__(256, 1) void cpc_kernel(
    const float* __restrict__ ac,      // (128,256) f32
    const float* __restrict__ future,  // (128,12,2) f32
    const float* __restrict__ Wk,      // (12,16,256) f32
    const float* __restrict__ bk,      // (12,16) f32
    const float* __restrict__ Wl,      // (16,2) f32
    const float* __restrict__ bl,      // (16) f32
    float* __restrict__ loss_part)     // (12) f32
{
    __shared__ float pred[128][17];
    __shared__ float proj[128][17];
    __shared__ float red[4];
    const int tid = threadIdx.x, t = blockIdx.x;

    for (int ii = 0; ii < 8; ++ii) {
        int idx = tid + ii * 256;
        int b = idx >> 4, l = idx & 15;
        const float* wrow = Wk + ((size_t)t * 16 + l) * 256;
        const float* arow = ac + b * 256;
        float acc = bk[t * 16 + l];
        for (int g = 0; g < 256; g += 4) {
            float4 w = *(const float4*)(wrow + g);
            float4 a = *(const float4*)(arow + g);
            acc += w.x * a.x + w.y * a.y + w.z * a.z + w.w * a.w;
        }
        pred[b][l] = acc;
        float f0 = future[(b * 12 + t) * 2 + 0];
        float f1 = future[(b * 12 + t) * 2 + 1];
        proj[b][l] = f0 * Wl[l * 2 + 0] + f1 * Wl[l * 2 + 1] + bl[l];
    }
    __syncthreads();
    {
        float* row = (tid < 128) ? pred[tid] : proj[tid - 128];
        float ss = 0.0f;
#pragma unroll
        for (int l = 0; l < 16; ++l) ss += row[l] * row[l];
        float inv = 1.0f / fmaxf(sqrtf(ss), 1e-12f);
#pragma unroll
        for (int l = 0; l < 16; ++l) row[l] *= inv;
    }
    __syncthreads();
    float lsbb = 0.0f;
    if (tid < 128) {
        int b = tid;
        float tf[16];
#pragma unroll
        for (int l = 0; l < 16; ++l) tf[l] = proj[b][l];
        float mx = -1e30f, dbb = 0.0f;
        for (int cc = 0; cc < 128; ++cc) {
            float d = 0.0f;
#pragma unroll
            for (int l = 0; l < 16; ++l) d += tf[l] * pred[cc][l];
            mx = fmaxf(mx, d);
            if (cc == b) dbb = d;
        }
        float den = 0.0f;
        for (int cc = 0; cc < 128; ++cc) {
            float d = 0.0f;
#pragma unroll
            for (int l = 0; l < 16; ++l) d += tf[l] * pred[cc][l];
            den += __expf(d - mx);
        }
        lsbb = dbb - mx - __logf(den);
    }
#pragma unroll
    for (int o = 32; o > 0; o >>= 1) lsbb += __shfl_down(lsbb, o);
    if ((tid & 63) == 0) red[tid >> 6] = lsbb;
    __syncthreads();
    if (tid == 0) loss_part[t] = red[0] + red[1] + red[2] + red[3];
}

__global__ void final_kernel(const float* __restrict__ loss_part,
                             float* __restrict__ out)
{
    if (threadIdx.x == 0) {
        float s = 0.0f;
        for (int t = 0; t < 12; ++t) s += loss_part[t];
        out[33152] = -s / 1536.0f;
    }
}

// ---------------------------------------------------------------------------
extern "C" void kernel_launch(void* const* d_in, const int* in_sizes, int n_in,
                              void* d_out, int out_size, void* d_ws, size_t ws_size,
                              hipStream_t stream)
{
    const float* agent_obs = (const float*)d_in[0];
    const float* future    = (const float*)d_in[1];
    const float* hideout   = (const float*)d_in[2];
    const float* timestep  = (const float*)d_in[3];
    // d_in[4] = num_agents (int, ==16)
    const float* W_ih  = (const float*)d_in[5];
    const float* W_hh  = (const float*)d_in[6];
    const float* b_ih  = (const float*)d_in[7];
    const float* b_hh  = (const float*)d_in[8];
    const float* Wsrc1 = (const float*)d_in[9];
    const float* bsrc1 = (const float*)d_in[10];
    const float* Wdst1 = (const float*)d_in[11];
    const float* bdst1 = (const float*)d_in[12];
    const float* attn1 = (const float*)d_in[13];
    const float* Wsrc2 = (const float*)d_in[14];
    const float* bsrc2 = (const float*)d_in[15];
    const float* Wdst2 = (const float*)d_in[16];
    const float* bdst2 = (const float*)d_in[17];
    const float* attn2 = (const float*)d_in[18];
    const float* Wk    = (const float*)d_in[19];
    const float* bk    = (const float*)d_in[20];
    const float* Wl    = (const float*)d_in[21];
    const float* bl    = (const float*)d_in[22];
    float* out = (float*)d_out;

    char* ws = (char*)d_ws;
    const size_t KB = 1024;
    bf16*  wihb  = (bf16*)(ws);                  // 32 KB  (1024x16)
    unsigned char* whh8 = (unsigned char*)(ws + 32 * KB);  // 256 KB fp8
    bf16*  ws1b  = (bf16*)(ws + 544 * KB);       // 1 MB   frag (2048x256)
    bf16*  wd1b  = (bf16*)(ws + 1568 * KB);      // 1 MB   frag
    bf16*  ws2b  = (bf16*)(ws + 2592 * KB);      // 128 KB frag (256x256)
    bf16*  wd2b  = (bf16*)(ws + 2720 * KB);      // 128 KB frag
    bf16*  hn    = (bf16*)(ws + 2848 * KB);      // 1 MB   frag (2048x256)
    bf16*  src1  = (bf16*)(ws + 3872 * KB);      // 8 MB   (2048x2048)
    bf16*  dst1  = (bf16*)(ws + 12064 * KB);     // 8 MB
    bf16*  r1f   = (bf16*)(ws + 20256 * KB);     // 1 MB   frag (2048x256)
    bf16*  src2  = (bf16*)(ws + 21280 * KB);     // 1 MB   (2048x256)
    bf16*  dst2  = (bf16*)(ws + 22304 * KB);     // 1 MB
    float* acf   = (float*)(ws + 23328 * KB);    // 128 KB (128x256 f32)
    float* lossp = (float*)(ws + 23456 * KB);    // 48 B

    cvt6<<<1424, 256, 0, stream>>>(W_ih, W_hh, Wsrc1, Wdst1, Wsrc2, Wdst2,
                                   wihb, whh8, ws1b, wd1b, ws2b, wd2b);
    lstm_kernel<<<128, 1024, 0, stream>>>(agent_obs, wihb, whh8, b_ih, b_hh, hn);
    gemm_bias2<<<dim3(32, 32), 256, 0, stream>>>(hn, ws1b, wd1b, bsrc1, bdst1,
                                                 src1, dst1, 2048);
    gat1_kernel<<<128, 256, 0, stream>>>(src1, dst1, attn1, r1f);
    gemm_bias2<<<dim3(4, 32), 256, 0, stream>>>(r1f, ws2b, wd2b, bsrc2, bdst2,
                                                src2, dst2, 256);
    gat2_kernel<<<128, 256, 0, stream>>>(src2, dst2, attn2, hideout, timestep, out, acf);
    cpc_kernel<<<12, 256, 0, stream>>>(acf, future, Wk, bk, Wl, bl, lossp);
    final_kernel<<<1, 64, 0, stream>>>(lossp, out);
}

// Round 17
// 511.615 us; speedup vs baseline: 5.2276x; 1.1385x over previous
//
#include <hip/hip_runtime.h>
#include <hip/hip_fp8.h>

// CPCGNN: LSTM(2048 x 128 steps, F=16, H=256) -> GATv2 x2 (16-node graphs) ->
// mean pool -> CPC loss. Inputs/outputs FLOAT32.
//
// Round 17: r16 + two tail optimizations:
//  * cpc: logits are cosine sims (|d|<=1) -> drop the max pass (exactly
//    equivalent); float4 LDS reads (pred/proj stride 20 for 16B alignment).
//  * gat1: grid 128 -> 256 (each WG does 8 of a graph's 16 rows) — full-chip.

typedef __bf16 bf16;
typedef bf16 bf16x4 __attribute__((ext_vector_type(4)));
typedef bf16 bf16x8 __attribute__((ext_vector_type(8)));
typedef float f32x4 __attribute__((ext_vector_type(4)));

#define MFMA8(A, B, C) __builtin_amdgcn_mfma_f32_16x16x32_fp8_fp8((A), (B), (C), 0, 0, 0)

__device__ __forceinline__ float fast_sigmoid(float x) {
    return __builtin_amdgcn_rcpf(1.0f + __expf(-x));
}
__device__ __forceinline__ float fast_tanh(float x) {
    return 2.0f * __builtin_amdgcn_rcpf(1.0f + __expf(-2.0f * x)) - 1.0f;
}
__device__ __forceinline__ bf16x8 zero8() {
    bf16x8 z;
#pragma unroll
    for (int i = 0; i < 8; ++i) z[i] = (bf16)0.0f;
    return z;
}
__device__ __forceinline__ bf16x8 load8_bf(const float* p) {
    float4 a = *(const float4*)p;
    float4 b = *(const float4*)(p + 4);
    bf16x8 r;
    r[0] = (bf16)a.x; r[1] = (bf16)a.y; r[2] = (bf16)a.z; r[3] = (bf16)a.w;
    r[4] = (bf16)b.x; r[5] = (bf16)b.y; r[6] = (bf16)b.z; r[7] = (bf16)b.w;
    return r;
}
__device__ __forceinline__ unsigned char to_fp8(float v) {
    __hip_fp8_e4m3 q(v);
    return (unsigned char)q.__x;
}

// ---------------------------------------------------------------------------
// 0. Weight conversions (r16 unchanged). W_ih bf16 row-major; W_hh fp8
//    chunk/wave slices; GAT weights bf16 fragment-major.
// ---------------------------------------------------------------------------
__global__ __launch_bounds__(256, 1) void cvt6(
    const float* __restrict__ s0, const float* __restrict__ s1,
    const float* __restrict__ s2, const float* __restrict__ s3,
    const float* __restrict__ s4, const float* __restrict__ s5,
    bf16* __restrict__ d0, unsigned char* __restrict__ d1fp8,
    bf16* __restrict__ d2, bf16* __restrict__ d3, bf16* __restrict__ d4,
    bf16* __restrict__ d5)
{
    const int n0 = 16384, n1 = 262144, n2 = 524288, n3 = 524288, n4 = 65536;
    int loc = (blockIdx.x * 256 + threadIdx.x) * 4;
    if (loc >= n0 && loc < n0 + n1) {             // W_hh -> fp8 (r13 layout)
        int l = loc - n0;
        int n = l >> 8, k = l & 255;
        int G = n >> 8, w_ = (n >> 4) & 15, col = n & 15;
        int kc = k >> 5, grp = (k >> 3) & 3, k8 = k & 7;   // k8 in {0,4}
        int dst = (kc * 2 + (G >> 1)) * 16384 + w_ * 1024 + (G & 1) * 512
                  + (grp * 16 + col) * 8 + k8;
        float4 v = *(const float4*)(s1 + l);
        unsigned int pack = (unsigned int)to_fp8(v.x)
                          | ((unsigned int)to_fp8(v.y) << 8)
                          | ((unsigned int)to_fp8(v.z) << 16)
                          | ((unsigned int)to_fp8(v.w) << 24);
        *(unsigned int*)(d1fp8 + dst) = pack;
        return;
    }
    if (loc < n0) {                               // W_ih row-major
        float4 v = *(const float4*)(s0 + loc);
        bf16x4 o;
        o[0] = (bf16)v.x; o[1] = (bf16)v.y; o[2] = (bf16)v.z; o[3] = (bf16)v.w;
        *(bf16x4*)(d0 + loc) = o;
        return;
    }
    // GAT weights -> fragment-major
    int l = loc - n0 - n1;
    const float* s; bf16* d;
    if (l < n2)              { s = s2; d = d2; }
    else if ((l -= n2) < n3) { s = s3; d = d3; }
    else if ((l -= n3) < n4) { s = s4; d = d4; }
    else                     { l -= n4; s = s5; d = d5; }
    int n = l >> 8, k = l & 255;
    int dst = ((n >> 4) * 8 + (k >> 5)) * 512 + ((k >> 3) & 3) * 128
              + (n & 15) * 8 + (k & 7);
    float4 v = *(const float4*)(s + l);
    bf16x4 o;
    o[0] = (bf16)v.x; o[1] = (bf16)v.y; o[2] = (bf16)v.z; o[3] = (bf16)v.w;
    *(bf16x4*)(d + dst) = o;
}

// ---------------------------------------------------------------------------
// 1. LSTM (r16 unchanged: fully-resident fp8 W, single-acc body,
//    fragment-major hn epilogue).
// ---------------------------------------------------------------------------
__global__ __launch_bounds__(1024)
__attribute__((amdgpu_waves_per_eu(4, 4)))
void lstm_kernel(
    const float* __restrict__ agent_obs,       // (128,128,16,16) f32
    const bf16* __restrict__ W_ih,             // (1024,16) bf16
    const unsigned char* __restrict__ whh8,    // (16,16384) fp8 chunks
    const float* __restrict__ b_ih,
    const float* __restrict__ b_hh,
    bf16* __restrict__ hn)                     // fragment-major (2048x256)
{
    __shared__ unsigned char wres[4][16][1024];    // 64 KB: chunks 12..15
    __shared__ unsigned char hbuf8[2][16][272];    // 8.5 KB fp8 h (+16 pad)
    const int tid  = threadIdx.x;
    const int lane = tid & 63;
    const int w    = tid >> 6;            // wave id = tau
    const int col  = lane & 15;
    const int grp  = lane >> 4;
    const int b    = blockIdx.x;

    for (int i = tid; i < 2 * 16 * 272; i += 1024) (&hbuf8[0][0][0])[i] = 0;

    float bias[4];
    bf16x8 wih[4];
#pragma unroll
    for (int G = 0; G < 4; ++G) {
        int n = G * 256 + w * 16 + col;
        bias[G] = b_ih[n] + b_hh[n];
        wih[G] = (grp < 2) ? *(const bf16x8*)&W_ih[n * 16 + grp * 8] : zero8();
    }
    // VGPR-resident chunks 0..11
    long wvr[12][2];
#pragma unroll
    for (int ic = 0; ic < 12; ++ic)
#pragma unroll
        for (int gl = 0; gl < 2; ++gl)
            wvr[ic][gl] = *(const long*)(whh8 + ic * 16384 + w * 1024
                                         + gl * 512 + lane * 8);
    // LDS-resident chunks 12..15
    const unsigned char* wsrc16 = whh8 + w * 1024 + lane * 16;
#pragma unroll
    for (int ic = 12; ic < 16; ++ic)
        __builtin_amdgcn_global_load_lds((const void*)(wsrc16 + ic * 16384),
                                         (void*)&wres[ic - 12][w][0], 16, 0, 0);
    f32x4 c = (f32x4){0.0f, 0.0f, 0.0f, 0.0f};
    const float* xb = agent_obs + (size_t)b * 32768;
    const int hnbase = b * 4096 + (w >> 1) * 512
                     + ((w & 1) * 2 + (col >> 3)) * 128 + (col & 7);

    asm volatile("s_waitcnt vmcnt(0)" ::: "memory");
    __syncthreads();

    for (int s = 0; s < 128; ++s) {
        const int pr = s & 1, pw = pr ^ 1;
        const unsigned char* hb = &hbuf8[pr][0][0];
        bf16x8 ax = (grp < 2) ? load8_bf(xb + s * 256 + col * 16 + grp * 8)
                              : zero8();
        f32x4 acc[4];
#pragma unroll
        for (int G = 0; G < 4; ++G) {
            float bs_ = bias[G];
            acc[G] = (f32x4){bs_, bs_, bs_, bs_};
        }
        long ah;
#pragma unroll
        for (int ic = 0; ic < 12; ++ic) {
            const int kc = ic >> 1, gh = ic & 1;
            if (gh == 0)
                ah = *(const long*)(hb + col * 272 + kc * 32 + grp * 8);
            acc[gh * 2 + 0] = MFMA8(ah, wvr[ic][0], acc[gh * 2 + 0]);
            acc[gh * 2 + 1] = MFMA8(ah, wvr[ic][1], acc[gh * 2 + 1]);
        }
#pragma unroll
        for (int ic = 12; ic < 16; ++ic) {
            const int kc = ic >> 1, gh = ic & 1;
            if (gh == 0)
                ah = *(const long*)(hb + col * 272 + kc * 32 + grp * 8);
            long bw0 = *(const long*)&wres[ic - 12][w][lane * 8];
            long bw1 = *(const long*)&wres[ic - 12][w][512 + lane * 8];
            acc[gh * 2 + 0] = MFMA8(ah, bw0, acc[gh * 2 + 0]);
            acc[gh * 2 + 1] = MFMA8(ah, bw1, acc[gh * 2 + 1]);
        }
#pragma unroll
        for (int G = 0; G < 4; ++G)
            acc[G] = __builtin_amdgcn_mfma_f32_16x16x32_bf16(ax, wih[G], acc[G], 0, 0, 0);
#pragma unroll
        for (int r = 0; r < 4; ++r) {
            float iv = fast_sigmoid(acc[0][r]);
            float fv = fast_sigmoid(acc[1][r]);
            float gv = fast_tanh(acc[2][r]);
            float ov = fast_sigmoid(acc[3][r]);
            float cn = fv * c[r] + iv * gv;
            c[r] = cn;
            float hv = ov * fast_tanh(cn);
            int m = grp * 4 + r;
            if (s == 127) hn[hnbase + m * 8] = (bf16)hv;
            else          hbuf8[pw][m][w * 16 + col] = to_fp8(hv);
        }
        asm volatile("s_waitcnt lgkmcnt(0)" ::: "memory");
        __builtin_amdgcn_s_barrier();
    }
}

// ---------------------------------------------------------------------------
// 2. FUSED dual GEMM (r16 unchanged).
// ---------------------------------------------------------------------------
__global__ __launch_bounds__(256, 1) void gemm_bias2(
    const bf16* __restrict__ Af,
    const bf16* __restrict__ Wf1, const bf16* __restrict__ Wf2,
    const float* __restrict__ bias1, const float* __restrict__ bias2,
    bf16* __restrict__ C1, bf16* __restrict__ C2, int N)
{
    const int tid = threadIdx.x, lane = tid & 63, wv = tid >> 6;
    const int col = lane & 15, grp = lane >> 4;
    const int n = blockIdx.x * 64 + wv * 16 + col;
    const int wt = blockIdx.x * 4 + wv;
    const int bm = blockIdx.y * 64;
    float bs1 = bias1[n], bs2 = bias2[n];
    f32x4 acc1[4], acc2[4];
#pragma unroll
    for (int mt = 0; mt < 4; ++mt) {
        acc1[mt] = (f32x4){bs1, bs1, bs1, bs1};
        acc2[mt] = (f32x4){bs2, bs2, bs2, bs2};
    }
#pragma unroll
    for (int kc = 0; kc < 8; ++kc) {
        bf16x8 bw1 = *(const bf16x8*)&Wf1[((size_t)wt * 8 + kc) * 512 + lane * 8];
        bf16x8 bw2 = *(const bf16x8*)&Wf2[((size_t)wt * 8 + kc) * 512 + lane * 8];
#pragma unroll
        for (int mt = 0; mt < 4; ++mt) {
            bf16x8 aa = *(const bf16x8*)
                &Af[((size_t)(blockIdx.y * 4 + mt) * 8 + kc) * 512 + lane * 8];
            acc1[mt] = __builtin_amdgcn_mfma_f32_16x16x32_bf16(aa, bw1, acc1[mt], 0, 0, 0);
            acc2[mt] = __builtin_amdgcn_mfma_f32_16x16x32_bf16(aa, bw2, acc2[mt], 0, 0, 0);
        }
    }
#pragma unroll
    for (int mt = 0; mt < 4; ++mt)
#pragma unroll
        for (int r = 0; r < 4; ++r) {
            size_t idx = (size_t)(bm + mt * 16 + grp * 4 + r) * N + n;
            C1[idx] = (bf16)acc1[mt][r];
            C2[idx] = (bf16)acc2[mt][r];
        }
}

// ---------------------------------------------------------------------------
// 3. GATv2 layer 1 — grid 256: WG (b, half) handles rows i in [half*8,+8).
// ---------------------------------------------------------------------------
__global__ __launch_bounds__(256, 1) void gat1_kernel(
    const bf16* __restrict__ src,    // (2048, 2048) row-major
    const bf16* __restrict__ dst,
    const float* __restrict__ attn,  // (8,256) f32
    bf16* __restrict__ r1f)          // fragment-major (2048x256)
{
    __shared__ float sal[1024];      // (li*16+j)*8+h, li in [0,8)
    const int tid = threadIdx.x;
    const int b = blockIdx.x >> 1, h8 = (blockIdx.x & 1) * 8;
    const bf16* sb = src + (size_t)b * 32768;
    const bf16* db = dst + (size_t)b * 32768;

    for (int ii = 0; ii < 4; ++ii) {
        int t2 = tid + ii * 256;              // li*128 + j*8 + h
        int li = t2 >> 7, j = (t2 >> 3) & 15, h = t2 & 7;
        int i = h8 + li;
        const bf16* ps = sb + j * 2048 + h * 256;
        const bf16* pd = db + i * 2048 + h * 256;
        const float* pa = attn + h * 256;
        float acc = 0.0f;
        for (int f8 = 0; f8 < 32; ++f8) {
            bf16x8 vs = *(const bf16x8*)(ps + f8 * 8);
            bf16x8 vd = *(const bf16x8*)(pd + f8 * 8);
            float4 a0 = *(const float4*)(pa + f8 * 8);
            float4 a1 = *(const float4*)(pa + f8 * 8 + 4);
            float av[8] = {a0.x, a0.y, a0.z, a0.w, a1.x, a1.y, a1.z, a1.w};
#pragma unroll
            for (int e = 0; e < 8; ++e) {
                float v = (float)vs[e] + (float)vd[e];
                v = v > 0.0f ? v : 0.2f * v;
                acc += v * av[e];
            }
        }
        sal[t2] = acc;
    }
    __syncthreads();
    if (tid < 64) {                           // softmax over j != i
        int li = tid >> 3, h = tid & 7;
        int i = h8 + li;
        float m = -1e30f;
#pragma unroll
        for (int j = 0; j < 16; ++j)
            if (j != i) m = fmaxf(m, sal[(li * 16 + j) * 8 + h]);
        float ex[16], den = 0.0f;
#pragma unroll
        for (int j = 0; j < 16; ++j) {
            ex[j] = (j == i) ? 0.0f : __expf(sal[(li * 16 + j) * 8 + h] - m);
            den += ex[j];
        }
        float rd = 1.0f / den;
#pragma unroll
        for (int j = 0; j < 16; ++j) sal[(li * 16 + j) * 8 + h] = ex[j] * rd;
    }
    __syncthreads();
    {   // aggregation: li = tid>>5 (8 rows), fv = tid&31 (8-wide f blocks)
        const int li = tid >> 5, fv = tid & 31;
        const int i = h8 + li;
        float acc[8];
#pragma unroll
        for (int e = 0; e < 8; ++e) acc[e] = 0.0f;
        for (int j = 0; j < 16; ++j) {
#pragma unroll
            for (int h = 0; h < 8; ++h) {
                float wgt = sal[(li * 16 + j) * 8 + h];
                const bf16* ps = sb + j * 2048 + h * 256 + fv * 8;
                bf16x8 v0 = *(const bf16x8*)(ps);
#pragma unroll
                for (int e = 0; e < 8; ++e) acc[e] += wgt * (float)v0[e];
            }
        }
        // f = fv*8+e -> dsti = b*4096 + (fv>>2)*512 + (fv&3)*128 + i*8 + e
        bf16x8 o;
#pragma unroll
        for (int e = 0; e < 8; ++e) o[e] = (bf16)(acc[e] * 0.125f);
        *(bf16x8*)&r1f[b * 4096 + (fv >> 2) * 512 + (fv & 3) * 128 + i * 8] = o;
    }
}

// ---------------------------------------------------------------------------
// 4. GATv2 layer 2 (r16 unchanged).
// ---------------------------------------------------------------------------
__global__ __launch_bounds__(256, 1) void gat2_kernel(
    const bf16* __restrict__ src2,   // (2048,256) row-major
    const bf16* __restrict__ dst2,
    const float* __restrict__ attn2, // (256) f32
    const float* __restrict__ hideout,   // (128,2) f32
    const float* __restrict__ timestep,  // (128,1) f32
    float* __restrict__ out,             // (128,259)+loss f32
    float* __restrict__ ac_ws)           // (128,256) f32
{
    __shared__ float sal[256];
    __shared__ float wj[16];
    const int tid = threadIdx.x, b = blockIdx.x;
    const bf16* sb = src2 + (size_t)b * 4096;
    const bf16* db = dst2 + (size_t)b * 4096;
    {
        int i = tid >> 4, j = tid & 15;
        const bf16* ps = sb + j * 256;
        const bf16* pd = db + i * 256;
        float acc = 0.0f;
        for (int g8 = 0; g8 < 32; ++g8) {
            bf16x8 vs = *(const bf16x8*)(ps + g8 * 8);
            bf16x8 vd = *(const bf16x8*)(pd + g8 * 8);
            float4 a0 = *(const float4*)(attn2 + g8 * 8);
            float4 a1 = *(const float4*)(attn2 + g8 * 8 + 4);
            float av[8] = {a0.x, a0.y, a0.z, a0.w, a1.x, a1.y, a1.z, a1.w};
#pragma unroll
            for (int e = 0; e < 8; ++e) {
                float v = (float)vs[e] + (float)vd[e];
                v = v > 0.0f ? v : 0.2f * v;
                acc += v * av[e];
            }
        }
        sal[tid] = acc;
    }
    __syncthreads();
    if (tid < 16) {
        int i = tid;
        float m = -1e30f;
#pragma unroll
        for (int j = 0; j < 16; ++j)
            if (j != i) m = fmaxf(m, sal[i * 16 + j]);
        float ex[16], den = 0.0f;
#pragma unroll
        for (int j = 0; j < 16; ++j) {
            ex[j] = (j == i) ? 0.0f : __expf(sal[i * 16 + j] - m);
            den += ex[j];
        }
        float rd = 1.0f / den;
#pragma unroll
        for (int j = 0; j < 16; ++j) sal[i * 16 + j] = ex[j] * rd;
    }
    __syncthreads();
    if (tid < 16) {
        float a = 0.0f;
#pragma unroll
        for (int i = 0; i < 16; ++i) a += sal[i * 16 + tid];
        wj[tid] = a * (1.0f / 16.0f);
    }
    __syncthreads();
    {
        int g = tid;
        float acc = 0.0f;
#pragma unroll
        for (int j = 0; j < 16; ++j) acc += wj[j] * (float)sb[j * 256 + g];
        ac_ws[b * 256 + g] = acc;
        out[(size_t)b * 259 + g] = acc;
    }
    if (tid < 2) out[(size_t)b * 259 + 256 + tid] = hideout[b * 2 + tid];
    if (tid == 0) out[(size_t)b * 259 + 258] = timestep[b];
}

// ---------------------------------------------------------------------------
// 5. CPC: one WG per t. Logits are cosine sims (|d|<=1) -> single-pass
//    log-softmax (no max subtraction; exactly shift-equivalent). float4
//    LDS reads (stride 20 => 16B-aligned rows).
// ---------------------------------------------------------------------------
__global__ __launch_bounds__(256, 1) void cpc_kernel(
    const float* __restrict__ ac,      // (128,256) f32
    const float* __restrict__ future,  // (128,12,2) f32
    const float* __restrict__ Wk,      // (12,16,256) f32
    const float* __restrict__ bk,      // (12,16) f32
    const float* __restrict__ Wl,      // (16,2) f32
    const float* __restrict__ bl,      // (16) f32
    float* __restrict__ loss_part)     // (12) f32
{
    __shared__ float pred[128][20];
    __shared__ float proj[128][20];
    __shared__ float red[4];
    const int tid = threadIdx.x, t = blockIdx.x;

    for (int ii = 0; ii < 8; ++ii) {
        int idx = tid + ii * 256;
        int b = idx >> 4, l = idx & 15;
        const float* wrow = Wk + ((size_t)t * 16 + l) * 256;
        const float* arow = ac + b * 256;
        float acc = bk[t * 16 + l];
        for (int g = 0; g < 256; g += 4) {
            float4 w = *(const float4*)(wrow + g);
            float4 a = *(const float4*)(arow + g);
            acc += w.x * a.x + w.y * a.y + w.z * a.z + w.w * a.w;
        }
        pred[b][l] = acc;
        float f0 = future[(b * 12 + t) * 2 + 0];
        float f1 = future[(b * 12 + t) * 2 + 1];
        proj[b][l] = f0 * Wl[l * 2 + 0] + f1 * Wl[l * 2 + 1] + bl[l];
    }
    __syncthreads();
    {
        float* row = (tid < 128) ? pred[tid] : proj[tid - 128];
        float ss = 0.0f;
#pragma unroll
        for (int l = 0; l < 16; ++l) ss += row[l] * row[l];
        float inv = 1.0f / fmaxf(sqrtf(ss), 1e-12f);
#pragma unroll
        for (int l = 0; l < 16; ++l) row[l] *= inv;
    }
    __syncthreads();
    float lsbb = 0.0f;
    if (tid < 128) {
        int b = tid;
        float tf[16];
#pragma unroll
        for (int l = 0; l < 16; ++l) tf[l] = proj[b][l];
        float dbb = 0.0f, den = 0.0f;
        for (int cc = 0; cc < 128; ++cc) {
            float4 p0 = *(const float4*)&pred[cc][0];
            float4 p1 = *(const float4*)&pred[cc][4];
            float4 p2 = *(const float4*)&pred[cc][8];
            float4 p3 = *(const float4*)&pred[cc][12];
            float d = tf[0] * p0.x + tf[1] * p0.y + tf[2] * p0.z + tf[3] * p0.w
                    + tf[4] * p1.x + tf[5] * p1.y + tf[6] * p1.z + tf[7] * p1.w
                    + tf[8] * p2.x + tf[9] * p2.y + tf[10] * p2.z + tf[11] * p2.w
                    + tf[12] * p3.x + tf[13] * p3.y + tf[14] * p3.z + tf[15] * p3.w;
            den += __expf(d);
            if (cc == b) dbb = d;
        }
        lsbb = dbb - __logf(den);
    }
#pragma unroll
    for (int o = 32; o > 0; o >>= 1) lsbb += __shfl_down(lsbb, o);
    if ((tid & 63) == 0) red[tid >> 6] = lsbb;
    __syncthreads();
    if (tid == 0) loss_part[t] = red[0] + red[1] + red[2] + red[3];
}

__global__ void final_kernel(const float* __restrict__ loss_part,
                             float* __restrict__ out)
{
    if (threadIdx.x == 0) {
        float s = 0.0f;
        for (int t = 0; t < 12; ++t) s += loss_part[t];
        out[33152] = -s / 1536.0f;
    }
}

// ---------------------------------------------------------------------------
extern "C" void kernel_launch(void* const* d_in, const int* in_sizes, int n_in,
                              void* d_out, int out_size, void* d_ws, size_t ws_size,
                              hipStream_t stream)
{
    const float* agent_obs = (const float*)d_in[0];
    const float* future    = (const float*)d_in[1];
    const float* hideout   = (const float*)d_in[2];
    const float* timestep  = (const float*)d_in[3];
    // d_in[4] = num_agents (int, ==16)
    const float* W_ih  = (const float*)d_in[5];
    const float* W_hh  = (const float*)d_in[6];
    const float* b_ih  = (const float*)d_in[7];
    const float* b_hh  = (const float*)d_in[8];
    const float* Wsrc1 = (const float*)d_in[9];
    const float* bsrc1 = (const float*)d_in[10];
    const float* Wdst1 = (const float*)d_in[11];
    const float* bdst1 = (const float*)d_in[12];
    const float* attn1 = (const float*)d_in[13];
    const float* Wsrc2 = (const float*)d_in[14];
    const float* bsrc2 = (const float*)d_in[15];
    const float* Wdst2 = (const float*)d_in[16];
    const float* bdst2 = (const float*)d_in[17];
    const float* attn2 = (const float*)d_in[18];
    const float* Wk    = (const float*)d_in[19];
    const float* bk    = (const float*)d_in[20];
    const float* Wl    = (const float*)d_in[21];
    const float* bl    = (const float*)d_in[22];
    float* out = (float*)d_out;

    char* ws = (char*)d_ws;
    const size_t KB = 1024;
    bf16*  wihb  = (bf16*)(ws);                  // 32 KB  (1024x16)
    unsigned char* whh8 = (unsigned char*)(ws + 32 * KB);  // 256 KB fp8
    bf16*  ws1b  = (bf16*)(ws + 544 * KB);       // 1 MB   frag (2048x256)
    bf16*  wd1b  = (bf16*)(ws + 1568 * KB);      // 1 MB   frag
    bf16*  ws2b  = (bf16*)(ws + 2592 * KB);      // 128 KB frag (256x256)
    bf16*  wd2b  = (bf16*)(ws + 2720 * KB);      // 128 KB frag
    bf16*  hn    = (bf16*)(ws + 2848 * KB);      // 1 MB   frag (2048x256)
    bf16*  src1  = (bf16*)(ws + 3872 * KB);      // 8 MB   (2048x2048)
    bf16*  dst1  = (bf16*)(ws + 12064 * KB);     // 8 MB
    bf16*  r1f   = (bf16*)(ws + 20256 * KB);     // 1 MB   frag (2048x256)
    bf16*  src2  = (bf16*)(ws + 21280 * KB);     // 1 MB   (2048x256)
    bf16*  dst2  = (bf16*)(ws + 22304 * KB);     // 1 MB
    float* acf   = (float*)(ws + 23328 * KB);    // 128 KB (128x256 f32)
    float* lossp = (float*)(ws + 23456 * KB);    // 48 B

    cvt6<<<1424, 256, 0, stream>>>(W_ih, W_hh, Wsrc1, Wdst1, Wsrc2, Wdst2,
                                   wihb, whh8, ws1b, wd1b, ws2b, wd2b);
    lstm_kernel<<<128, 1024, 0, stream>>>(agent_obs, wihb, whh8, b_ih, b_hh, hn);
    gemm_bias2<<<dim3(32, 32), 256, 0, stream>>>(hn, ws1b, wd1b, bsrc1, bdst1,
                                                 src1, dst1, 2048);
    gat1_kernel<<<256, 256, 0, stream>>>(src1, dst1, attn1, r1f);
    gemm_bias2<<<dim3(4, 32), 256, 0, stream>>>(r1f, ws2b, wd2b, bsrc2, bdst2,
                                                src2, dst2, 256);
    gat2_kernel<<<128, 256, 0, stream>>>(src2, dst2, attn2, hideout, timestep, out, acf);
    cpc_kernel<<<12, 256, 0, stream>>>(acf, future, Wk, bk, Wl, bl, lossp);
    final_kernel<<<1, 64, 0, stream>>>(lossp, out);
}